// Round 9
// baseline (1156.016 us; speedup 1.0000x reference)
//
#include <hip/hip_runtime.h>
#include <hip/hip_bf16.h>
#include <cmath>

#define LAYERS 4
#define Bb 4
#define Ss 1024
#define Dd 1024
#define Ff 2048
#define Hh 8
#define DHd 128
#define Mm (Bb * Ss)   // 4096 rows
#define EPSf 1e-5f
#define LDQ 4096       // combined QKVG row stride

typedef __attribute__((ext_vector_type(8))) short short8v;
typedef __attribute__((ext_vector_type(4))) float f32x4;
typedef __attribute__((ext_vector_type(4))) unsigned int u32x4;

__device__ __forceinline__ float swish_f(float x) { return x / (1.f + expf(-x)); }
__device__ __forceinline__ float gelu_f(float x) {
  return 0.5f * x * (1.f + tanhf(0.7978845608028654f * (x + 0.044715f * x * x * x)));
}
__device__ __forceinline__ unsigned short f2bfu(float f) {
  __hip_bfloat16 h = __float2bfloat16(f);
  return __builtin_bit_cast(unsigned short, h);
}
__device__ __forceinline__ float bfu2f(unsigned short u) {
  unsigned v = ((unsigned)u) << 16;
  return __builtin_bit_cast(float, v);
}
__device__ __forceinline__ void gl_lds16(const void* g, void* l) {
  __builtin_amdgcn_global_load_lds((__attribute__((address_space(1))) void*)g,
                                   (__attribute__((address_space(3))) void*)l, 16, 0, 0);
}
__device__ __forceinline__ f32x4 mfma16(short8v a, short8v b, f32x4 c) {
  return __builtin_amdgcn_mfma_f32_16x16x32_bf16(a, b, c, 0, 0, 0);
}

// ---------------- LayerNorm fp32 -> bf16 ----------------
__global__ __launch_bounds__(256) void ln_bf16_kernel(const float* __restrict__ x,
                                                      short* __restrict__ outb,
                                                      const float* __restrict__ sc,
                                                      const float* __restrict__ bi) {
  const int row = blockIdx.x;
  const int t = threadIdx.x;
  const float4 v = *(const float4*)(x + (size_t)row * Dd + t * 4);
  float s = v.x + v.y + v.z + v.w;
  float s2 = v.x * v.x + v.y * v.y + v.z * v.z + v.w * v.w;
#pragma unroll
  for (int o = 32; o > 0; o >>= 1) { s += __shfl_down(s, o); s2 += __shfl_down(s2, o); }
  __shared__ float ps[4], ps2[4];
  if ((t & 63) == 0) { ps[t >> 6] = s; ps2[t >> 6] = s2; }
  __syncthreads();
  s = ps[0] + ps[1] + ps[2] + ps[3];
  s2 = ps2[0] + ps2[1] + ps2[2] + ps2[3];
  const float mu = s * (1.f / Dd);
  const float var = s2 * (1.f / Dd) - mu * mu;
  const float rstd = rsqrtf(var + EPSf);
  const float4 g = *(const float4*)(sc + t * 4);
  const float4 b = *(const float4*)(bi + t * 4);
  const float o0 = (v.x - mu) * rstd * g.x + b.x;
  const float o1 = (v.y - mu) * rstd * g.y + b.y;
  const float o2 = (v.z - mu) * rstd * g.z + b.z;
  const float o3 = (v.w - mu) * rstd * g.w + b.w;
  unsigned p0 = (unsigned)f2bfu(o0) | ((unsigned)f2bfu(o1) << 16);
  unsigned p1 = (unsigned)f2bfu(o2) | ((unsigned)f2bfu(o3) << 16);
  uint2 pk; pk.x = p0; pk.y = p1;
  *(uint2*)(outb + (size_t)row * Dd + t * 4) = pk;
}

// ---------------- RoPE tables ----------------
__global__ void rope_table_kernel(float* __restrict__ ct, float* __restrict__ st) {
  const int i = blockIdx.x * 256 + threadIdx.x;  // < Ss*64
  const int s = i >> 6, f = i & 63;
  const float inv = powf(10000.f, -(float)f / 64.f);
  const float a = (float)s * inv;
  ct[i] = cosf(a);
  st[i] = sinf(a);
}

// ---------------- RoPE in-place on combined bf16 QKVG buffer (Q:+sin, K:-sin) -------------
__global__ void rope_ip_kernel(short* __restrict__ QK, const float* __restrict__ ct,
                               const float* __restrict__ st) {
  const int idx = blockIdx.x * 256 + threadIdx.x;  // < B*S*H*64
  const int f = idx & 63;
  const int h = (idx >> 6) & 7;
  const int r = idx >> 9;            // b*S+s
  const int s = r & (Ss - 1);
  const float c = ct[(s << 6) + f], sn = st[(s << 6) + f];
  const size_t qo = (size_t)r * LDQ + h * DHd + 2 * f;
  const unsigned qp = *(const unsigned*)(QK + qo);
  const unsigned kp = *(const unsigned*)(QK + qo + 1024);
  const float qx = bfu2f((unsigned short)(qp & 0xffff)), qy = bfu2f((unsigned short)(qp >> 16));
  const float kx = bfu2f((unsigned short)(kp & 0xffff)), ky = bfu2f((unsigned short)(kp >> 16));
  const unsigned qn = (unsigned)f2bfu(qx * c - qy * sn) | ((unsigned)f2bfu(qx * sn + qy * c) << 16);
  const unsigned kn = (unsigned)f2bfu(kx * c + ky * sn) | ((unsigned)f2bfu(-kx * sn + ky * c) << 16);
  *(unsigned*)(QK + qo) = qn;
  *(unsigned*)(QK + qo + 1024) = kn;
}

// ---------------- transpose-convert QKVG concat: 4x W[K][1024] fp32 -> Wt[4096][K] bf16 ----
__global__ __launch_bounds__(256) void wtrans4_kernel(const float* __restrict__ W0,
                                                      const float* __restrict__ W1,
                                                      const float* __restrict__ W2,
                                                      const float* __restrict__ W3,
                                                      short* __restrict__ Wt) {
  __shared__ float tile[32][33];
  const int t = threadIdx.x;
  const int n0 = blockIdx.x * 32, k0 = blockIdx.y * 32;
  const int which = n0 >> 10;
  const float* W = (which == 0) ? W0 : (which == 1) ? W1 : (which == 2) ? W2 : W3;
  const int nl = n0 & 1023;
  const int tc = t & 31, tr8 = t >> 5;
#pragma unroll
  for (int i = 0; i < 4; ++i) {
    const int r = tr8 + i * 8;
    tile[r][tc] = W[(size_t)(k0 + r) * 1024 + nl + tc];
  }
  __syncthreads();
#pragma unroll
  for (int i = 0; i < 4; ++i) {
    const int r = tr8 + i * 8;
    Wt[(size_t)(n0 + r) * 1024 + k0 + tc] = (short)f2bfu(tile[tc][r]);
  }
}

// ---------------- transpose-convert single: W[K][N] fp32 -> Wt[N][K] bf16 ----------------
__global__ __launch_bounds__(256) void wtrans1_kernel(const float* __restrict__ W,
                                                      short* __restrict__ Wt, int K, int N) {
  __shared__ float tile[32][33];
  const int t = threadIdx.x;
  const int n0 = blockIdx.x * 32, k0 = blockIdx.y * 32;
  const int tc = t & 31, tr8 = t >> 5;
#pragma unroll
  for (int i = 0; i < 4; ++i) {
    const int r = tr8 + i * 8;
    tile[r][tc] = W[(size_t)(k0 + r) * N + n0 + tc];
  }
  __syncthreads();
#pragma unroll
  for (int i = 0; i < 4; ++i) {
    const int r = tr8 + i * 8;
    Wt[(size_t)(n0 + r) * K + k0 + tc] = (short)f2bfu(tile[tc][r]);
  }
}

// ---------------- V transpose bf16: combined buf col-slice -> Vt [(bh*128+d)][S] ----------
__global__ __launch_bounds__(256) void vtrans16_kernel(const short* __restrict__ Vb,
                                                       short* __restrict__ Vt) {
  __shared__ short tile[32][33];
  const int t = threadIdx.x;
  const int s0 = blockIdx.x * 32, d0 = blockIdx.y * 32, bh = blockIdx.z;
  const int bb = bh >> 3, h = bh & 7;
  const int tc = t & 31, tr8 = t >> 5;
#pragma unroll
  for (int i = 0; i < 4; ++i) {
    const int r = tr8 + i * 8;
    tile[r][tc] = Vb[(size_t)(bb * Ss + s0 + r) * LDQ + 2048 + h * DHd + d0 + tc];
  }
  __syncthreads();
#pragma unroll
  for (int i = 0; i < 4; ++i) {
    const int r = tr8 + i * 8;
    Vt[(size_t)(bh * DHd + d0 + r) * Ss + s0 + tc] = tile[tc][r];
  }
}

// ---------------- bf16 MFMA GEMM v9: A in LDS (dbuf-2), B direct global->reg (dbuf) -------
// 256 threads = 4 waves (2x2). BM=128, BN in {128,64}. LDS only 16 KB.
// B-frags for step t+1 prefetched before the barrier: the vmcnt(0) drain COMPLETES them.
// EPI: 0 = bf16 out, 1 = +Res fp32 out, 2 = gelu bf16 out
template <int BM, int BN, int EPI>
__global__ __launch_bounds__(256, 3) void gemm9(const short* __restrict__ A,
                                                const short* __restrict__ Bt,
                                                float* __restrict__ Cf,
                                                short* __restrict__ Cb,
                                                const float* __restrict__ Res,
                                                int N, int K, int ldc) {
  constexpr int NTHR = 256;
  constexpr int WM = BM / 2, WN = BN / 2;
  constexpr int MR = WM / 16, NR = WN / 16;
  constexpr int LA = (BM * 4) / NTHR;
  __shared__ __align__(16) short As[2][BM * 32];
  const int t = threadIdx.x;
  const int w = t >> 6, l = t & 63;
  const int lq = l >> 4, lr = l & 15;
  const int wr = w >> 1, wc = w & 1;
  // XCD-contiguous 8x8 block squares (L2-resident panels); gridDim.x%8==0, y%8==0
  const int nwg = gridDim.x * gridDim.y;
  const int bid0 = blockIdx.x + blockIdx.y * gridDim.x;
  const int lgid = (bid0 & 7) * (nwg >> 3) + (bid0 >> 3);
  const int nsx = gridDim.x >> 3;
  const int sq = lgid >> 6, wi = lgid & 63;
  const int by = (sq / nsx) * 8 + (wi >> 3);
  const int bx = (sq % nsx) * 8 + (wi & 7);
  const int row0 = by * BM, col0 = bx * BN;
  f32x4 acc[MR][NR] = {};
  const int NTK = K >> 5;

  auto stageA = [&](int tile, int buf) {
    const int k0 = tile << 5;
#pragma unroll
    for (int i = 0; i < LA; ++i) {
      const int c = t + i * NTHR;
      const int row = c >> 2, sc = c & 3;
      gl_lds16(A + (size_t)(row0 + row) * K + k0 + ((sc ^ ((row >> 1) & 3)) << 3),
               &As[buf][c * 8]);
    }
  };
  const short* bptr[NR];
#pragma unroll
  for (int n = 0; n < NR; ++n)
    bptr[n] = Bt + (size_t)(col0 + wc * WN + n * 16 + lr) * K + lq * 8;

  short8v bA[NR], bB[NR], a[MR];
#pragma unroll
  for (int n = 0; n < NR; ++n) bA[n] = *(const short8v*)(bptr[n]);
  stageA(0, 0);

  for (int tt = 0; tt < NTK; tt += 2) {
    __syncthreads();  // vmcnt(0) drain completes stage(tt) AND the b-prefetch for tt
    if (tt + 1 < NTK) {
      stageA(tt + 1, 1);
#pragma unroll
      for (int n = 0; n < NR; ++n) bB[n] = *(const short8v*)(bptr[n] + ((tt + 1) << 5));
    }
#pragma unroll
    for (int m = 0; m < MR; ++m) {
      const int row = wr * WM + m * 16 + lr;
      a[m] = *(const short8v*)&As[0][row * 32 + ((lq ^ ((row >> 1) & 3)) << 3)];
    }
    __builtin_amdgcn_s_setprio(1);
#pragma unroll
    for (int m = 0; m < MR; ++m)
#pragma unroll
      for (int n = 0; n < NR; ++n) acc[m][n] = mfma16(a[m], bA[n], acc[m][n]);
    __builtin_amdgcn_s_setprio(0);

    __syncthreads();  // completes stage(tt+1) and bB prefetch
    if (tt + 2 < NTK) {
      stageA(tt + 2, 0);
#pragma unroll
      for (int n = 0; n < NR; ++n) bA[n] = *(const short8v*)(bptr[n] + ((tt + 2) << 5));
    }
#pragma unroll
    for (int m = 0; m < MR; ++m) {
      const int row = wr * WM + m * 16 + lr;
      a[m] = *(const short8v*)&As[1][row * 32 + ((lq ^ ((row >> 1) & 3)) << 3)];
    }
    __builtin_amdgcn_s_setprio(1);
#pragma unroll
    for (int m = 0; m < MR; ++m)
#pragma unroll
      for (int n = 0; n < NR; ++n) acc[m][n] = mfma16(a[m], bB[n], acc[m][n]);
    __builtin_amdgcn_s_setprio(0);
  }

#pragma unroll
  for (int m = 0; m < MR; ++m) {
#pragma unroll
    for (int n = 0; n < NR; ++n) {
#pragma unroll
      for (int r = 0; r < 4; ++r) {
        const int row = row0 + wr * WM + m * 16 + lq * 4 + r;
        const int col = col0 + wc * WN + n * 16 + lr;
        const size_t o = (size_t)row * ldc + col;
        float v = acc[m][n][r];
        if (EPI == 0) Cb[o] = (short)f2bfu(v);
        else if (EPI == 1) Cf[o] = v + Res[o];
        else Cb[o] = (short)f2bfu(gelu_f(v));
      }
    }
  }
}

// ---------------- Retention v5: K direct from L2, V-only LDS dbuf, setprio --------------
// Q,K read from combined QKVG buffer (stride LDQ); V^T from Vtb via LDS.
__global__ __launch_bounds__(256) void ret5_kernel(const short* __restrict__ QKb,
                                                   const short* __restrict__ Vt,
                                                   float* __restrict__ Y0,
                                                   float* __restrict__ Y1) {
  __shared__ __align__(16) short Vs[2][128 * 64];
  const int t = threadIdx.x, w = t >> 6, l = t & 63;
  const int lq = l >> 4, lr = l & 15;
  const int u = blockIdx.x;                 // 0..511
  const int lgid = (u & 7) * 64 + (u >> 3);
  const int half = lgid >> 8;
  const int rest = lgid & 255;
  const int bh = rest >> 3, j = rest & 7;
  const int qb = half ? j : 7 - j;          // dispatch-order-balanced triangular pairing
  const int b = bh >> 3, h = bh & 7;
  const int q0 = qb * 128;
  const float lstep = (logf(1.f / 512.f) - logf(1.f / 32.f)) * (1.f / 7.f);
  const float gamma = 1.f - expf(logf(1.f / 32.f) + (float)h * lstep);
  const float l2g = logf(gamma) * 1.44269504f;  // log2(gamma)
  const short* Qp = QKb;
  const short* Kp = QKb + 1024;

  short8v qf[2][4];
#pragma unroll
  for (int qn = 0; qn < 2; ++qn)
#pragma unroll
    for (int ks = 0; ks < 4; ++ks)
      qf[qn][ks] = *(const short8v*)(Qp + (size_t)(b * Ss + q0 + w * 32 + qn * 16 + lr) * LDQ +
                                     h * DHd + ks * 32 + lq * 8);

  float cmf[4], csr[4];
#pragma unroll
  for (int mf = 0; mf < 4; ++mf) cmf[mf] = exp2f(l2g * (float)(-16 * mf));
#pragma unroll
  for (int r = 0; r < 4; ++r) csr[r] = exp2f(l2g * (float)(63 - 4 * lq - r));

  f32x4 yacc[2][8] = {};
  const int nt = 2 * qb + 2;
  const int sb = ((lq & 1) * 2) * 16 + lr;

  auto stageV = [&](int m0, int buf) {
#pragma unroll
    for (int i = 0; i < 4; ++i) {
      const int c = (w * 4 + i) * 64 + l;
      const int row = c >> 3, slot = c & 7;
      gl_lds16(Vt + (size_t)(bh * DHd + row) * Ss + m0 + ((slot ^ (row & 7)) * 8),
               &Vs[buf][(w * 4 + i) * 512]);
    }
  };

  stageV(half * 64, 0);
  __syncthreads();
  int cur = 0;
  for (int tt = half; tt < nt; tt += 2) {
    const int m0 = tt * 64;
    if (tt + 2 < nt) stageV((tt + 2) * 64, cur ^ 1);

    // St = K x Q^T, K-fragments straight from global (L2-hot panel)
    f32x4 st[4][2] = {};
#pragma unroll
    for (int mf = 0; mf < 4; ++mf) {
      const size_t krow = (size_t)(b * Ss + m0 + mf * 16 + lr) * LDQ + h * DHd;
#pragma unroll
      for (int ks = 0; ks < 4; ++ks) {
        short8v kf = *(const short8v*)(Kp + krow + ks * 32 + lq * 8);
        st[mf][0] = mfma16(kf, qf[0][ks], st[mf][0]);
        st[mf][1] = mfma16(kf, qf[1][ks], st[mf][1]);
      }
    }
    float rs[2];
#pragma unroll
    for (int qn = 0; qn < 2; ++qn)
      rs[qn] = exp2f(l2g * (float)(q0 + w * 32 + qn * 16 + lr - m0 - 63));
#pragma unroll
    for (int mf = 0; mf < 4; ++mf)
#pragma unroll
      for (int qn = 0; qn < 2; ++qn)
#pragma unroll
        for (int r = 0; r < 4; ++r) {
          const int qg = q0 + w * 32 + qn * 16 + lr;
          const int kvg = m0 + mf * 16 + lq * 4 + r;
          const float wgt = (qg >= kvg) ? rs[qn] * cmf[mf] * csr[r] : 0.f;
          st[mf][qn][r] *= wgt;
        }
    unsigned pk[4][2][2];
#pragma unroll
    for (int mf = 0; mf < 4; ++mf)
#pragma unroll
      for (int qn = 0; qn < 2; ++qn)
#pragma unroll
        for (int p = 0; p < 2; ++p)
          pk[mf][qn][p] = (unsigned)f2bfu(st[mf][qn][2 * p]) |
                          ((unsigned)f2bfu(st[mf][qn][2 * p + 1]) << 16);
    short8v afr[2][2];
#pragma unroll
    for (int qn = 0; qn < 2; ++qn)
#pragma unroll
      for (int ks2 = 0; ks2 < 2; ++ks2) {
        u32x4 wd;
#pragma unroll
        for (int wj = 0; wj < 4; ++wj) {
          const int src = sb + (wj >> 1) * 16;
          const unsigned v0 = __shfl(pk[2 * ks2 + 0][qn][wj & 1], src);
          const unsigned v1 = __shfl(pk[2 * ks2 + 1][qn][wj & 1], src);
          wd[wj] = (lq >= 2) ? v1 : v0;
        }
        afr[qn][ks2] = __builtin_bit_cast(short8v, wd);
      }
    __builtin_amdgcn_s_setprio(1);
#pragma unroll
    for (int nd = 0; nd < 8; ++nd) {
      const int row = nd * 16 + lr;
#pragma unroll
      for (int ks2 = 0; ks2 < 2; ++ks2) {
        short8v vf = *(const short8v*)&Vs[cur][row * 64 + (((4 * ks2 + lq) ^ (row & 7)) * 8)];
        yacc[0][nd] = mfma16(afr[0][ks2], vf, yacc[0][nd]);
        yacc[1][nd] = mfma16(afr[1][ks2], vf, yacc[1][nd]);
      }
    }
    __builtin_amdgcn_s_setprio(0);
    __syncthreads();
    cur ^= 1;
  }
  float* Y = half ? Y1 : Y0;
#pragma unroll
  for (int qn = 0; qn < 2; ++qn)
#pragma unroll
    for (int r = 0; r < 4; ++r) {
      const int q = q0 + w * 32 + qn * 16 + lq * 4 + r;
#pragma unroll
      for (int nd = 0; nd < 8; ++nd)
        Y[(size_t)(b * Ss + q) * Dd + h * DHd + nd * 16 + lr] = yacc[qn][nd][r];
    }
}

// ---------------- gate: Gb = bf16( swish(Graw) * GN(Y0+Y1) ) ----------------
__global__ __launch_bounds__(256) void gate_kernel(const float* __restrict__ Y0,
                                                   const float* __restrict__ Y1,
                                                   const short* __restrict__ Graw,
                                                   short* __restrict__ Gb,
                                                   const float* __restrict__ gs,
                                                   const float* __restrict__ gb) {
  const int lane = threadIdx.x & 63;
  const int rowh = blockIdx.x * 4 + (threadIdx.x >> 6);  // (b*S+s)*H + h
  const int h = rowh & 7;
  const int row = rowh >> 3;
  const size_t ybase = (size_t)row * Dd + (size_t)h * DHd + lane * 2;
  float2 a = *(const float2*)(Y0 + ybase);
  const float2 c = *(const float2*)(Y1 + ybase);
  a.x += c.x; a.y += c.y;
  float s = a.x + a.y, s2 = a.x * a.x + a.y * a.y;
#pragma unroll
  for (int o = 32; o > 0; o >>= 1) { s += __shfl_down(s, o); s2 += __shfl_down(s2, o); }
  s = __shfl(s, 0);
  s2 = __shfl(s2, 0);
  const float mu = s * (1.f / DHd);
  const float rstd = rsqrtf(s2 * (1.f / DHd) - mu * mu + EPSf);
  const int d = h * DHd + lane * 2;
  const float2 g = *(const float2*)(gs + d);
  const float2 bbv = *(const float2*)(gb + d);
  const float y0 = (a.x - mu) * rstd * g.x + bbv.x;
  const float y1 = (a.y - mu) * rstd * g.y + bbv.y;
  const unsigned gr = *(const unsigned*)(Graw + (size_t)row * LDQ + 3072 + h * DHd + lane * 2);
  const float gx = bfu2f((unsigned short)(gr & 0xffff));
  const float gy = bfu2f((unsigned short)(gr >> 16));
  const unsigned o01 = (unsigned)f2bfu(swish_f(gx) * y0) |
                       ((unsigned)f2bfu(swish_f(gy) * y1) << 16);
  *(unsigned*)(Gb + ybase) = o01;
}

extern "C" void kernel_launch(void* const* d_in, const int* in_sizes, int n_in,
                              void* d_out, int out_size, void* d_ws, size_t ws_size,
                              hipStream_t stream) {
  const float* X = (const float*)d_in[0];
  const float* Wq = (const float*)d_in[1];
  const float* Wk = (const float*)d_in[2];
  const float* Wv = (const float*)d_in[3];
  const float* Wg = (const float*)d_in[4];
  const float* Wo = (const float*)d_in[5];
  const float* W1 = (const float*)d_in[6];
  const float* W2 = (const float*)d_in[7];
  const float* lns = (const float*)d_in[8];
  const float* lnb = (const float*)d_in[9];
  const float* gns = (const float*)d_in[10];
  const float* gnb = (const float*)d_in[11];
  float* out = (float*)d_out;

  char* W = (char*)d_ws;
  const size_t MB = 1u << 20;
  float* Abuf  = (float*)(W);             // 16 MB fp32
  short* Xnb   = (short*)(W + 16 * MB);   // 8 MB bf16
  short* QKVGb = (short*)(W + 24 * MB);   // 32 MB bf16 [4096][4096]; Hb aliases first 16 MB
  float* Y0    = (float*)(W + 56 * MB);   // 16 MB fp32
  float* Y1    = (float*)(W + 72 * MB);   // 16 MB fp32
  short* Vtb   = (short*)(W + 88 * MB);   // 8 MB bf16
  short* Gb    = (short*)(W + 96 * MB);   // 8 MB bf16
  short* Wqkvgt= (short*)(W + 104 * MB);  // 8 MB
  short* Wot   = (short*)(W + 112 * MB);  // 2 MB
  short* W1t   = (short*)(W + 114 * MB);  // 4 MB
  short* W2t   = (short*)(W + 118 * MB);  // 4 MB
  float* ct    = (float*)(W + 122 * MB);  // 256 KB
  float* st    = ct + Ss * 64;            // 256 KB
  short* Hb = QKVGb;  // FFN hidden 4096x2048 bf16 (16 MB), G consumed by gate before W1

  hipMemcpyAsync(Abuf, X, (size_t)Mm * Dd * sizeof(float), hipMemcpyDeviceToDevice, stream);
  rope_table_kernel<<<(Ss * 64) / 256, 256, 0, stream>>>(ct, st);

  for (int l = 0; l < LAYERS; ++l) {
    const size_t DD = (size_t)Dd * Dd;
    wtrans4_kernel<<<dim3(128, 32), 256, 0, stream>>>(Wq + l * DD, Wk + l * DD, Wv + l * DD,
                                                      Wg + l * DD, Wqkvgt);
    wtrans1_kernel<<<dim3(32, 32), 256, 0, stream>>>(Wo + l * DD, Wot, Dd, Dd);
    wtrans1_kernel<<<dim3(64, 32), 256, 0, stream>>>(W1 + (size_t)l * Dd * Ff, W1t, Dd, Ff);
    wtrans1_kernel<<<dim3(32, 64), 256, 0, stream>>>(W2 + (size_t)l * Ff * Dd, W2t, Ff, Dd);

    // Xn = LN(A) -> bf16
    ln_bf16_kernel<<<Mm, 256, 0, stream>>>(Abuf, Xnb, lns, lnb);
    // fused QKVG projection -> combined bf16 buffer [4096][4096] (1024 blocks)
    gemm9<128, 128, 0><<<dim3(32, 32), 256, 0, stream>>>(Xnb, Wqkvgt, nullptr, QKVGb,
                                                         nullptr, 4096, Dd, LDQ);
    // RoPE in-place on Q,K slices
    rope_ip_kernel<<<(Bb * Ss * Hh * 64) / 256, 256, 0, stream>>>(QKVGb, ct, st);
    // V transpose
    vtrans16_kernel<<<dim3(Ss / 32, DHd / 32, Bb * Hh), 256, 0, stream>>>(QKVGb, Vtb);
    // retention -> partial Y0,Y1 (fp32)
    ret5_kernel<<<512, 256, 0, stream>>>(QKVGb, Vtb, Y0, Y1);
    // gate: Gb = swish(Graw) * GN(Y0+Y1)
    gate_kernel<<<(Mm * Hh) / 4, 256, 0, stream>>>(Y0, Y1, QKVGb, Gb,
                                                   gns + (size_t)l * Dd, gnb + (size_t)l * Dd);
    // A = (Gb @ Wo) + A : 128x64 tiles, 512 blocks
    gemm9<128, 64, 1><<<dim3(16, 32), 256, 0, stream>>>(Gb, Wot, Abuf, nullptr, Abuf,
                                                        Dd, Dd, Dd);
    // FFN
    ln_bf16_kernel<<<Mm, 256, 0, stream>>>(Abuf, Xnb, lns, lnb);
    gemm9<128, 128, 2><<<dim3(16, 32), 256, 0, stream>>>(Xnb, W1t, nullptr, Hb, nullptr,
                                                         Ff, Dd, Ff);
    float* dst = (l == LAYERS - 1) ? out : Abuf;
    gemm9<128, 64, 1><<<dim3(16, 32), 256, 0, stream>>>(Hb, W2t, dst, nullptr, Abuf,
                                                        Dd, Ff, Dd);
  }
}

// Round 10
// 886.117 us; speedup vs baseline: 1.3046x; 1.3046x over previous
//
#include <hip/hip_runtime.h>
#include <hip/hip_bf16.h>
#include <cmath>

#define LAYERS 4
#define Bb 4
#define Ss 1024
#define Dd 1024
#define Ff 2048
#define Hh 8
#define DHd 128
#define Mm (Bb * Ss)   // 4096 rows
#define EPSf 1e-5f
#define LDQ 4096       // combined QKVG row stride

typedef __attribute__((ext_vector_type(8))) short short8v;
typedef __attribute__((ext_vector_type(4))) float f32x4;
typedef __attribute__((ext_vector_type(4))) unsigned int u32x4;

__device__ __forceinline__ float swish_f(float x) { return x / (1.f + expf(-x)); }
__device__ __forceinline__ float gelu_f(float x) {
  return 0.5f * x * (1.f + tanhf(0.7978845608028654f * (x + 0.044715f * x * x * x)));
}
__device__ __forceinline__ unsigned short f2bfu(float f) {
  __hip_bfloat16 h = __float2bfloat16(f);
  return __builtin_bit_cast(unsigned short, h);
}
__device__ __forceinline__ float bfu2f(unsigned short u) {
  unsigned v = ((unsigned)u) << 16;
  return __builtin_bit_cast(float, v);
}
__device__ __forceinline__ void gl_lds16(const void* g, void* l) {
  __builtin_amdgcn_global_load_lds((__attribute__((address_space(1))) void*)g,
                                   (__attribute__((address_space(3))) void*)l, 16, 0, 0);
}
__device__ __forceinline__ f32x4 mfma16(short8v a, short8v b, f32x4 c) {
  return __builtin_amdgcn_mfma_f32_16x16x32_bf16(a, b, c, 0, 0, 0);
}

// ---------------- LayerNorm fp32 -> bf16 ----------------
__global__ __launch_bounds__(256) void ln_bf16_kernel(const float* __restrict__ x,
                                                      short* __restrict__ outb,
                                                      const float* __restrict__ sc,
                                                      const float* __restrict__ bi) {
  const int row = blockIdx.x;
  const int t = threadIdx.x;
  const float4 v = *(const float4*)(x + (size_t)row * Dd + t * 4);
  float s = v.x + v.y + v.z + v.w;
  float s2 = v.x * v.x + v.y * v.y + v.z * v.z + v.w * v.w;
#pragma unroll
  for (int o = 32; o > 0; o >>= 1) { s += __shfl_down(s, o); s2 += __shfl_down(s2, o); }
  __shared__ float ps[4], ps2[4];
  if ((t & 63) == 0) { ps[t >> 6] = s; ps2[t >> 6] = s2; }
  __syncthreads();
  s = ps[0] + ps[1] + ps[2] + ps[3];
  s2 = ps2[0] + ps2[1] + ps2[2] + ps2[3];
  const float mu = s * (1.f / Dd);
  const float var = s2 * (1.f / Dd) - mu * mu;
  const float rstd = rsqrtf(var + EPSf);
  const float4 g = *(const float4*)(sc + t * 4);
  const float4 b = *(const float4*)(bi + t * 4);
  const float o0 = (v.x - mu) * rstd * g.x + b.x;
  const float o1 = (v.y - mu) * rstd * g.y + b.y;
  const float o2 = (v.z - mu) * rstd * g.z + b.z;
  const float o3 = (v.w - mu) * rstd * g.w + b.w;
  unsigned p0 = (unsigned)f2bfu(o0) | ((unsigned)f2bfu(o1) << 16);
  unsigned p1 = (unsigned)f2bfu(o2) | ((unsigned)f2bfu(o3) << 16);
  uint2 pk; pk.x = p0; pk.y = p1;
  *(uint2*)(outb + (size_t)row * Dd + t * 4) = pk;
}

// ---------------- RoPE tables ----------------
__global__ void rope_table_kernel(float* __restrict__ ct, float* __restrict__ st) {
  const int i = blockIdx.x * 256 + threadIdx.x;  // < Ss*64
  const int s = i >> 6, f = i & 63;
  const float inv = powf(10000.f, -(float)f / 64.f);
  const float a = (float)s * inv;
  ct[i] = cosf(a);
  st[i] = sinf(a);
}

// ---------------- RoPE in-place on combined bf16 QKVG buffer (Q:+sin, K:-sin) -------------
__global__ void rope_ip_kernel(short* __restrict__ QK, const float* __restrict__ ct,
                               const float* __restrict__ st) {
  const int idx = blockIdx.x * 256 + threadIdx.x;  // < B*S*H*64
  const int f = idx & 63;
  const int h = (idx >> 6) & 7;
  const int r = idx >> 9;            // b*S+s
  const int s = r & (Ss - 1);
  const float c = ct[(s << 6) + f], sn = st[(s << 6) + f];
  const size_t qo = (size_t)r * LDQ + h * DHd + 2 * f;
  const unsigned qp = *(const unsigned*)(QK + qo);
  const unsigned kp = *(const unsigned*)(QK + qo + 1024);
  const float qx = bfu2f((unsigned short)(qp & 0xffff)), qy = bfu2f((unsigned short)(qp >> 16));
  const float kx = bfu2f((unsigned short)(kp & 0xffff)), ky = bfu2f((unsigned short)(kp >> 16));
  const unsigned qn = (unsigned)f2bfu(qx * c - qy * sn) | ((unsigned)f2bfu(qx * sn + qy * c) << 16);
  const unsigned kn = (unsigned)f2bfu(kx * c + ky * sn) | ((unsigned)f2bfu(-kx * sn + ky * c) << 16);
  *(unsigned*)(QK + qo) = qn;
  *(unsigned*)(QK + qo + 1024) = kn;
}

// ---------------- transpose-convert QKVG concat: 4x W[K][1024] fp32 -> Wt[4096][K] bf16 ----
__global__ __launch_bounds__(256) void wtrans4_kernel(const float* __restrict__ W0,
                                                      const float* __restrict__ W1,
                                                      const float* __restrict__ W2,
                                                      const float* __restrict__ W3,
                                                      short* __restrict__ Wt) {
  __shared__ float tile[32][33];
  const int t = threadIdx.x;
  const int n0 = blockIdx.x * 32, k0 = blockIdx.y * 32;
  const int which = n0 >> 10;
  const float* W = (which == 0) ? W0 : (which == 1) ? W1 : (which == 2) ? W2 : W3;
  const int nl = n0 & 1023;
  const int tc = t & 31, tr8 = t >> 5;
#pragma unroll
  for (int i = 0; i < 4; ++i) {
    const int r = tr8 + i * 8;
    tile[r][tc] = W[(size_t)(k0 + r) * 1024 + nl + tc];
  }
  __syncthreads();
#pragma unroll
  for (int i = 0; i < 4; ++i) {
    const int r = tr8 + i * 8;
    Wt[(size_t)(n0 + r) * 1024 + k0 + tc] = (short)f2bfu(tile[tc][r]);
  }
}

// ---------------- transpose-convert single: W[K][N] fp32 -> Wt[N][K] bf16 ----------------
__global__ __launch_bounds__(256) void wtrans1_kernel(const float* __restrict__ W,
                                                      short* __restrict__ Wt, int K, int N) {
  __shared__ float tile[32][33];
  const int t = threadIdx.x;
  const int n0 = blockIdx.x * 32, k0 = blockIdx.y * 32;
  const int tc = t & 31, tr8 = t >> 5;
#pragma unroll
  for (int i = 0; i < 4; ++i) {
    const int r = tr8 + i * 8;
    tile[r][tc] = W[(size_t)(k0 + r) * N + n0 + tc];
  }
  __syncthreads();
#pragma unroll
  for (int i = 0; i < 4; ++i) {
    const int r = tr8 + i * 8;
    Wt[(size_t)(n0 + r) * K + k0 + tc] = (short)f2bfu(tile[tc][r]);
  }
}

// ---------------- V transpose bf16: combined buf col-slice -> Vt [(bh*128+d)][S] ----------
__global__ __launch_bounds__(256) void vtrans16_kernel(const short* __restrict__ Vb,
                                                       short* __restrict__ Vt) {
  __shared__ short tile[32][33];
  const int t = threadIdx.x;
  const int s0 = blockIdx.x * 32, d0 = blockIdx.y * 32, bh = blockIdx.z;
  const int bb = bh >> 3, h = bh & 7;
  const int tc = t & 31, tr8 = t >> 5;
#pragma unroll
  for (int i = 0; i < 4; ++i) {
    const int r = tr8 + i * 8;
    tile[r][tc] = Vb[(size_t)(bb * Ss + s0 + r) * LDQ + 2048 + h * DHd + d0 + tc];
  }
  __syncthreads();
#pragma unroll
  for (int i = 0; i < 4; ++i) {
    const int r = tr8 + i * 8;
    Vt[(size_t)(bh * DHd + d0 + r) * Ss + s0 + tc] = tile[tc][r];
  }
}

// ---------------- bf16 MFMA GEMM v7: m97 structure, dbuf-2, fixed XOR swizzle ------------
// 256 threads = 4 waves (2x2). Wave tile BM/2 x BN/2.
// EPI: 0 = bf16 out, 1 = +Res fp32 out, 2 = gelu bf16 out
template <int BM, int BN, int EPI>
__global__ __launch_bounds__(256) void gemm7(const short* __restrict__ A,
                                             const short* __restrict__ Bt,
                                             float* __restrict__ Cf,
                                             short* __restrict__ Cb,
                                             const float* __restrict__ Res,
                                             int N, int K, int ldc) {
  constexpr int NTHR = 256;
  constexpr int WM = BM / 2, WN = BN / 2;
  constexpr int MR = WM / 16, NR = WN / 16;
  constexpr int LA = (BM * 4) / NTHR, LB = (BN * 4) / NTHR;
  __shared__ __align__(16) short As[2][BM * 32];
  __shared__ __align__(16) short Bs[2][BN * 32];
  const int t = threadIdx.x;
  const int w = t >> 6, l = t & 63;
  const int lq = l >> 4, lr = l & 15;
  const int wr = w >> 1, wc = w & 1;
  // T1: bijective XCD swizzle (nwg % 8 == 0 for all grids here)
  const int nwg = gridDim.x * gridDim.y;
  const int bid0 = blockIdx.x + blockIdx.y * gridDim.x;
  const int lgid = (bid0 & 7) * (nwg >> 3) + (bid0 >> 3);
  const int bx = lgid % gridDim.x, by = lgid / gridDim.x;
  const int row0 = by * BM, col0 = bx * BN;
  f32x4 acc[MR][NR] = {};
  const int NTK = K >> 5;

  auto stage = [&](int tile, int buf) {
    const int k0 = tile << 5;
#pragma unroll
    for (int i = 0; i < LA; ++i) {
      const int c = t + i * NTHR;
      const int row = c >> 2, sc = c & 3;
      gl_lds16(A + (size_t)(row0 + row) * K + k0 + ((sc ^ ((row >> 1) & 3)) << 3),
               &As[buf][c * 8]);
    }
#pragma unroll
    for (int i = 0; i < LB; ++i) {
      const int c = t + i * NTHR;
      const int row = c >> 2, sc = c & 3;
      gl_lds16(Bt + (size_t)(col0 + row) * K + k0 + ((sc ^ ((row >> 1) & 3)) << 3),
               &Bs[buf][c * 8]);
    }
  };

  stage(0, 0);
  int cur = 0;
  for (int tt = 0; tt < NTK; ++tt) {
    __syncthreads();  // drains vmcnt(0): tile tt landed; prev iter's reads complete
    if (tt + 1 < NTK) stage(tt + 1, cur ^ 1);
    short8v a[MR], b[NR];
#pragma unroll
    for (int m = 0; m < MR; ++m) {
      const int row = wr * WM + m * 16 + lr;
      a[m] = *(const short8v*)&As[cur][row * 32 + ((lq ^ ((row >> 1) & 3)) << 3)];
    }
#pragma unroll
    for (int n = 0; n < NR; ++n) {
      const int col = wc * WN + n * 16 + lr;
      b[n] = *(const short8v*)&Bs[cur][col * 32 + ((lq ^ ((col >> 1) & 3)) << 3)];
    }
    __builtin_amdgcn_s_setprio(1);
#pragma unroll
    for (int m = 0; m < MR; ++m)
#pragma unroll
      for (int n = 0; n < NR; ++n) acc[m][n] = mfma16(a[m], b[n], acc[m][n]);
    __builtin_amdgcn_s_setprio(0);
    cur ^= 1;
  }

#pragma unroll
  for (int m = 0; m < MR; ++m) {
#pragma unroll
    for (int n = 0; n < NR; ++n) {
#pragma unroll
      for (int r = 0; r < 4; ++r) {
        const int row = row0 + wr * WM + m * 16 + lq * 4 + r;
        const int col = col0 + wc * WN + n * 16 + lr;
        const size_t o = (size_t)row * ldc + col;
        float v = acc[m][n][r];
        if (EPI == 0) Cb[o] = (short)f2bfu(v);
        else if (EPI == 1) Cf[o] = v + Res[o];
        else Cb[o] = (short)f2bfu(gelu_f(v));
      }
    }
  }
}

// ---------------- Retention v4: dbuf K/V, 1 barrier/tile, setprio, XCD-local bh ----------
// Q,K read from combined QKVG buffer (stride LDQ); V^T from Vtb.
__global__ __launch_bounds__(256) void ret4_kernel(const short* __restrict__ QKb,
                                                   const short* __restrict__ Vt,
                                                   float* __restrict__ Y0,
                                                   float* __restrict__ Y1) {
  __shared__ __align__(16) short Ks[2][64 * 128];
  __shared__ __align__(16) short Vs[2][128 * 64];
  const int t = threadIdx.x, w = t >> 6, l = t & 63;
  const int lq = l >> 4, lr = l & 15;
  const int u = blockIdx.x;                 // 0..511
  const int lgid = (u & 7) * 64 + (u >> 3);
  const int half = lgid >> 8;
  const int rest = lgid & 255;
  const int bh = rest >> 3, j = rest & 7;
  const int qb = half ? j : 7 - j;          // dispatch-order-balanced triangular pairing
  const int b = bh >> 3, h = bh & 7;
  const int q0 = qb * 128;
  const float lstep = (logf(1.f / 512.f) - logf(1.f / 32.f)) * (1.f / 7.f);
  const float gamma = 1.f - expf(logf(1.f / 32.f) + (float)h * lstep);
  const float l2g = logf(gamma) * 1.44269504f;  // log2(gamma)
  const short* Qp = QKb;
  const short* Kp = QKb + 1024;

  short8v qf[2][4];
#pragma unroll
  for (int qn = 0; qn < 2; ++qn)
#pragma unroll
    for (int ks = 0; ks < 4; ++ks)
      qf[qn][ks] = *(const short8v*)(Qp + (size_t)(b * Ss + q0 + w * 32 + qn * 16 + lr) * LDQ +
                                     h * DHd + ks * 32 + lq * 8);

  float cmf[4], csr[4];
#pragma unroll
  for (int mf = 0; mf < 4; ++mf) cmf[mf] = exp2f(l2g * (float)(-16 * mf));
#pragma unroll
  for (int r = 0; r < 4; ++r) csr[r] = exp2f(l2g * (float)(63 - 4 * lq - r));

  f32x4 yacc[2][8] = {};
  const int nt = 2 * qb + 2;
  const int sb = ((lq & 1) * 2) * 16 + lr;

  auto stageKV = [&](int m0, int buf) {
#pragma unroll
    for (int i = 0; i < 4; ++i) {
      const int c = (w * 4 + i) * 64 + l;
      const int row = c >> 4, slot = c & 15;
      gl_lds16(Kp + (size_t)(b * Ss + m0 + row) * LDQ + h * DHd + ((slot ^ (row & 7)) * 8),
               &Ks[buf][(w * 4 + i) * 512]);
    }
#pragma unroll
    for (int i = 0; i < 4; ++i) {
      const int c = (w * 4 + i) * 64 + l;
      const int row = c >> 3, slot = c & 7;
      gl_lds16(Vt + (size_t)(bh * DHd + row) * Ss + m0 + ((slot ^ (row & 7)) * 8),
               &Vs[buf][(w * 4 + i) * 512]);
    }
  };

  stageKV(half * 64, 0);
  __syncthreads();
  int cur = 0;
  for (int tt = half; tt < nt; tt += 2) {
    const int m0 = tt * 64;
    if (tt + 2 < nt) stageKV((tt + 2) * 64, cur ^ 1);

    f32x4 st[4][2] = {};
    __builtin_amdgcn_s_setprio(1);
#pragma unroll
    for (int mf = 0; mf < 4; ++mf) {
      const int row = mf * 16 + lr;
#pragma unroll
      for (int ks = 0; ks < 4; ++ks) {
        short8v kf = *(const short8v*)&Ks[cur][row * 128 + (((4 * ks + lq) ^ (row & 7)) * 8)];
        st[mf][0] = mfma16(kf, qf[0][ks], st[mf][0]);
        st[mf][1] = mfma16(kf, qf[1][ks], st[mf][1]);
      }
    }
    __builtin_amdgcn_s_setprio(0);
    float rs[2];
#pragma unroll
    for (int qn = 0; qn < 2; ++qn)
      rs[qn] = exp2f(l2g * (float)(q0 + w * 32 + qn * 16 + lr - m0 - 63));
#pragma unroll
    for (int mf = 0; mf < 4; ++mf)
#pragma unroll
      for (int qn = 0; qn < 2; ++qn)
#pragma unroll
        for (int r = 0; r < 4; ++r) {
          const int qg = q0 + w * 32 + qn * 16 + lr;
          const int kvg = m0 + mf * 16 + lq * 4 + r;
          const float wgt = (qg >= kvg) ? rs[qn] * cmf[mf] * csr[r] : 0.f;
          st[mf][qn][r] *= wgt;
        }
    unsigned pk[4][2][2];
#pragma unroll
    for (int mf = 0; mf < 4; ++mf)
#pragma unroll
      for (int qn = 0; qn < 2; ++qn)
#pragma unroll
        for (int p = 0; p < 2; ++p)
          pk[mf][qn][p] = (unsigned)f2bfu(st[mf][qn][2 * p]) |
                          ((unsigned)f2bfu(st[mf][qn][2 * p + 1]) << 16);
    short8v afr[2][2];
#pragma unroll
    for (int qn = 0; qn < 2; ++qn)
#pragma unroll
      for (int ks2 = 0; ks2 < 2; ++ks2) {
        u32x4 wd;
#pragma unroll
        for (int wj = 0; wj < 4; ++wj) {
          const int src = sb + (wj >> 1) * 16;
          const unsigned v0 = __shfl(pk[2 * ks2 + 0][qn][wj & 1], src);
          const unsigned v1 = __shfl(pk[2 * ks2 + 1][qn][wj & 1], src);
          wd[wj] = (lq >= 2) ? v1 : v0;
        }
        afr[qn][ks2] = __builtin_bit_cast(short8v, wd);
      }
    __builtin_amdgcn_s_setprio(1);
#pragma unroll
    for (int nd = 0; nd < 8; ++nd) {
      const int row = nd * 16 + lr;
#pragma unroll
      for (int ks2 = 0; ks2 < 2; ++ks2) {
        short8v vf = *(const short8v*)&Vs[cur][row * 64 + (((4 * ks2 + lq) ^ (row & 7)) * 8)];
        yacc[0][nd] = mfma16(afr[0][ks2], vf, yacc[0][nd]);
        yacc[1][nd] = mfma16(afr[1][ks2], vf, yacc[1][nd]);
      }
    }
    __builtin_amdgcn_s_setprio(0);
    __syncthreads();
    cur ^= 1;
  }
  float* Y = half ? Y1 : Y0;
#pragma unroll
  for (int qn = 0; qn < 2; ++qn)
#pragma unroll
    for (int r = 0; r < 4; ++r) {
      const int q = q0 + w * 32 + qn * 16 + lq * 4 + r;
#pragma unroll
      for (int nd = 0; nd < 8; ++nd)
        Y[(size_t)(b * Ss + q) * Dd + h * DHd + nd * 16 + lr] = yacc[qn][nd][r];
    }
}

// ---------------- gate: Gb = bf16( swish(Graw) * GN(Y0+Y1) ) ----------------
__global__ __launch_bounds__(256) void gate_kernel(const float* __restrict__ Y0,
                                                   const float* __restrict__ Y1,
                                                   const short* __restrict__ Graw,
                                                   short* __restrict__ Gb,
                                                   const float* __restrict__ gs,
                                                   const float* __restrict__ gb) {
  const int lane = threadIdx.x & 63;
  const int rowh = blockIdx.x * 4 + (threadIdx.x >> 6);  // (b*S+s)*H + h
  const int h = rowh & 7;
  const int row = rowh >> 3;
  const size_t ybase = (size_t)row * Dd + (size_t)h * DHd + lane * 2;
  float2 a = *(const float2*)(Y0 + ybase);
  const float2 c = *(const float2*)(Y1 + ybase);
  a.x += c.x; a.y += c.y;
  float s = a.x + a.y, s2 = a.x * a.x + a.y * a.y;
#pragma unroll
  for (int o = 32; o > 0; o >>= 1) { s += __shfl_down(s, o); s2 += __shfl_down(s2, o); }
  s = __shfl(s, 0);
  s2 = __shfl(s2, 0);
  const float mu = s * (1.f / DHd);
  const float rstd = rsqrtf(s2 * (1.f / DHd) - mu * mu + EPSf);
  const int d = h * DHd + lane * 2;
  const float2 g = *(const float2*)(gs + d);
  const float2 bbv = *(const float2*)(gb + d);
  const float y0 = (a.x - mu) * rstd * g.x + bbv.x;
  const float y1 = (a.y - mu) * rstd * g.y + bbv.y;
  const unsigned gr = *(const unsigned*)(Graw + (size_t)row * LDQ + 3072 + h * DHd + lane * 2);
  const float gx = bfu2f((unsigned short)(gr & 0xffff));
  const float gy = bfu2f((unsigned short)(gr >> 16));
  const unsigned o01 = (unsigned)f2bfu(swish_f(gx) * y0) |
                       ((unsigned)f2bfu(swish_f(gy) * y1) << 16);
  *(unsigned*)(Gb + ybase) = o01;
}

extern "C" void kernel_launch(void* const* d_in, const int* in_sizes, int n_in,
                              void* d_out, int out_size, void* d_ws, size_t ws_size,
                              hipStream_t stream) {
  const float* X = (const float*)d_in[0];
  const float* Wq = (const float*)d_in[1];
  const float* Wk = (const float*)d_in[2];
  const float* Wv = (const float*)d_in[3];
  const float* Wg = (const float*)d_in[4];
  const float* Wo = (const float*)d_in[5];
  const float* W1 = (const float*)d_in[6];
  const float* W2 = (const float*)d_in[7];
  const float* lns = (const float*)d_in[8];
  const float* lnb = (const float*)d_in[9];
  const float* gns = (const float*)d_in[10];
  const float* gnb = (const float*)d_in[11];
  float* out = (float*)d_out;

  char* W = (char*)d_ws;
  const size_t MB = 1u << 20;
  float* Abuf  = (float*)(W);             // 16 MB fp32
  short* Xnb   = (short*)(W + 16 * MB);   // 8 MB bf16
  short* QKVGb = (short*)(W + 24 * MB);   // 32 MB bf16 [4096][4096]; Hb aliases first 16 MB
  float* Y0    = (float*)(W + 56 * MB);   // 16 MB fp32
  float* Y1    = (float*)(W + 72 * MB);   // 16 MB fp32
  short* Vtb   = (short*)(W + 88 * MB);   // 8 MB bf16
  short* Gb    = (short*)(W + 96 * MB);   // 8 MB bf16
  short* Wqkvgt= (short*)(W + 104 * MB);  // 8 MB
  short* Wot   = (short*)(W + 112 * MB);  // 2 MB
  short* W1t   = (short*)(W + 114 * MB);  // 4 MB
  short* W2t   = (short*)(W + 118 * MB);  // 4 MB
  float* ct    = (float*)(W + 122 * MB);  // 256 KB
  float* st    = ct + Ss * 64;            // 256 KB
  short* Hb = QKVGb;  // FFN hidden 4096x2048 bf16 (16 MB), G consumed by gate before W1

  hipMemcpyAsync(Abuf, X, (size_t)Mm * Dd * sizeof(float), hipMemcpyDeviceToDevice, stream);
  rope_table_kernel<<<(Ss * 64) / 256, 256, 0, stream>>>(ct, st);

  for (int l = 0; l < LAYERS; ++l) {
    const size_t DD = (size_t)Dd * Dd;
    wtrans4_kernel<<<dim3(128, 32), 256, 0, stream>>>(Wq + l * DD, Wk + l * DD, Wv + l * DD,
                                                      Wg + l * DD, Wqkvgt);
    wtrans1_kernel<<<dim3(32, 32), 256, 0, stream>>>(Wo + l * DD, Wot, Dd, Dd);
    wtrans1_kernel<<<dim3(64, 32), 256, 0, stream>>>(W1 + (size_t)l * Dd * Ff, W1t, Dd, Ff);
    wtrans1_kernel<<<dim3(32, 64), 256, 0, stream>>>(W2 + (size_t)l * Ff * Dd, W2t, Ff, Dd);

    // Xn = LN(A) -> bf16
    ln_bf16_kernel<<<Mm, 256, 0, stream>>>(Abuf, Xnb, lns, lnb);
    // fused QKVG projection -> combined bf16 buffer [4096][4096] (1024 blocks = 4/CU)
    gemm7<128, 128, 0><<<dim3(32, 32), 256, 0, stream>>>(Xnb, Wqkvgt, nullptr, QKVGb,
                                                         nullptr, 4096, Dd, LDQ);
    // RoPE in-place on Q,K slices
    rope_ip_kernel<<<(Bb * Ss * Hh * 64) / 256, 256, 0, stream>>>(QKVGb, ct, st);
    // V transpose
    vtrans16_kernel<<<dim3(Ss / 32, DHd / 32, Bb * Hh), 256, 0, stream>>>(QKVGb, Vtb);
    // retention -> partial Y0,Y1 (fp32)
    ret4_kernel<<<512, 256, 0, stream>>>(QKVGb, Vtb, Y0, Y1);
    // gate: Gb = swish(Graw) * GN(Y0+Y1)
    gate_kernel<<<(Mm * Hh) / 4, 256, 0, stream>>>(Y0, Y1, QKVGb, Gb,
                                                   gns + (size_t)l * Dd, gnb + (size_t)l * Dd);
    // A = (Gb @ Wo) + A : 128x64 tiles, 512 blocks = 2/CU (control config)
    gemm7<128, 64, 1><<<dim3(16, 32), 256, 0, stream>>>(Gb, Wot, Abuf, nullptr, Abuf,
                                                        Dd, Dd, Dd);
    // FFN
    ln_bf16_kernel<<<Mm, 256, 0, stream>>>(Abuf, Xnb, lns, lnb);
    // W1: 128x64 tiles -> 1024 blocks = 4/CU (blocks/CU experiment)
    gemm7<128, 64, 2><<<dim3(32, 32), 256, 0, stream>>>(Xnb, W1t, nullptr, Hb, nullptr,
                                                        Ff, Dd, Ff);
    float* dst = (l == LAYERS - 1) ? out : Abuf;
    // W2: 64x64 tiles -> 1024 blocks = 4/CU (blocks/CU experiment)
    gemm7<64, 64, 1><<<dim3(16, 64), 256, 0, stream>>>(Hb, W2t, dst, nullptr, Abuf,
                                                       Dd, Ff, Dd);
  }
}

// Round 11
// 826.099 us; speedup vs baseline: 1.3994x; 1.0727x over previous
//
#include <hip/hip_runtime.h>
#include <hip/hip_bf16.h>
#include <cmath>

#define LAYERS 4
#define Bb 4
#define Ss 1024
#define Dd 1024
#define Ff 2048
#define Hh 8
#define DHd 128
#define Mm (Bb * Ss)   // 4096 rows
#define EPSf 1e-5f
#define LDQ 4096       // combined QKVG row stride

typedef __attribute__((ext_vector_type(8))) short short8v;
typedef __attribute__((ext_vector_type(4))) float f32x4;
typedef __attribute__((ext_vector_type(4))) unsigned int u32x4;

__device__ __forceinline__ float swish_f(float x) { return x / (1.f + expf(-x)); }
__device__ __forceinline__ float gelu_f(float x) {
  return 0.5f * x * (1.f + tanhf(0.7978845608028654f * (x + 0.044715f * x * x * x)));
}
__device__ __forceinline__ unsigned short f2bfu(float f) {
  __hip_bfloat16 h = __float2bfloat16(f);
  return __builtin_bit_cast(unsigned short, h);
}
__device__ __forceinline__ float bfu2f(unsigned short u) {
  unsigned v = ((unsigned)u) << 16;
  return __builtin_bit_cast(float, v);
}
__device__ __forceinline__ void gl_lds16(const void* g, void* l) {
  __builtin_amdgcn_global_load_lds((__attribute__((address_space(1))) void*)g,
                                   (__attribute__((address_space(3))) void*)l, 16, 0, 0);
}
__device__ __forceinline__ f32x4 mfma16(short8v a, short8v b, f32x4 c) {
  return __builtin_amdgcn_mfma_f32_16x16x32_bf16(a, b, c, 0, 0, 0);
}

// ---------------- LayerNorm fp32 -> bf16 ----------------
__global__ __launch_bounds__(256) void ln_bf16_kernel(const float* __restrict__ x,
                                                      short* __restrict__ outb,
                                                      const float* __restrict__ sc,
                                                      const float* __restrict__ bi) {
  const int row = blockIdx.x;
  const int t = threadIdx.x;
  const float4 v = *(const float4*)(x + (size_t)row * Dd + t * 4);
  float s = v.x + v.y + v.z + v.w;
  float s2 = v.x * v.x + v.y * v.y + v.z * v.z + v.w * v.w;
#pragma unroll
  for (int o = 32; o > 0; o >>= 1) { s += __shfl_down(s, o); s2 += __shfl_down(s2, o); }
  __shared__ float ps[4], ps2[4];
  if ((t & 63) == 0) { ps[t >> 6] = s; ps2[t >> 6] = s2; }
  __syncthreads();
  s = ps[0] + ps[1] + ps[2] + ps[3];
  s2 = ps2[0] + ps2[1] + ps2[2] + ps2[3];
  const float mu = s * (1.f / Dd);
  const float var = s2 * (1.f / Dd) - mu * mu;
  const float rstd = rsqrtf(var + EPSf);
  const float4 g = *(const float4*)(sc + t * 4);
  const float4 b = *(const float4*)(bi + t * 4);
  const float o0 = (v.x - mu) * rstd * g.x + b.x;
  const float o1 = (v.y - mu) * rstd * g.y + b.y;
  const float o2 = (v.z - mu) * rstd * g.z + b.z;
  const float o3 = (v.w - mu) * rstd * g.w + b.w;
  unsigned p0 = (unsigned)f2bfu(o0) | ((unsigned)f2bfu(o1) << 16);
  unsigned p1 = (unsigned)f2bfu(o2) | ((unsigned)f2bfu(o3) << 16);
  uint2 pk; pk.x = p0; pk.y = p1;
  *(uint2*)(outb + (size_t)row * Dd + t * 4) = pk;
}

// ---------------- RoPE tables ----------------
__global__ void rope_table_kernel(float* __restrict__ ct, float* __restrict__ st) {
  const int i = blockIdx.x * 256 + threadIdx.x;  // < Ss*64
  const int s = i >> 6, f = i & 63;
  const float inv = powf(10000.f, -(float)f / 64.f);
  const float a = (float)s * inv;
  ct[i] = cosf(a);
  st[i] = sinf(a);
}

// ---------------- RoPE in-place on combined bf16 QKVG buffer (Q:+sin, K:-sin) -------------
__global__ void rope_ip_kernel(short* __restrict__ QK, const float* __restrict__ ct,
                               const float* __restrict__ st) {
  const int idx = blockIdx.x * 256 + threadIdx.x;  // < B*S*H*64
  const int f = idx & 63;
  const int h = (idx >> 6) & 7;
  const int r = idx >> 9;            // b*S+s
  const int s = r & (Ss - 1);
  const float c = ct[(s << 6) + f], sn = st[(s << 6) + f];
  const size_t qo = (size_t)r * LDQ + h * DHd + 2 * f;
  const unsigned qp = *(const unsigned*)(QK + qo);
  const unsigned kp = *(const unsigned*)(QK + qo + 1024);
  const float qx = bfu2f((unsigned short)(qp & 0xffff)), qy = bfu2f((unsigned short)(qp >> 16));
  const float kx = bfu2f((unsigned short)(kp & 0xffff)), ky = bfu2f((unsigned short)(kp >> 16));
  const unsigned qn = (unsigned)f2bfu(qx * c - qy * sn) | ((unsigned)f2bfu(qx * sn + qy * c) << 16);
  const unsigned kn = (unsigned)f2bfu(kx * c + ky * sn) | ((unsigned)f2bfu(-kx * sn + ky * c) << 16);
  *(unsigned*)(QK + qo) = qn;
  *(unsigned*)(QK + qo + 1024) = kn;
}

// ---------------- transpose-convert QKVG concat: 4x W[K][1024] fp32 -> Wt[4096][K] bf16 ----
__global__ __launch_bounds__(256) void wtrans4_kernel(const float* __restrict__ W0,
                                                      const float* __restrict__ W1,
                                                      const float* __restrict__ W2,
                                                      const float* __restrict__ W3,
                                                      short* __restrict__ Wt) {
  __shared__ float tile[32][33];
  const int t = threadIdx.x;
  const int n0 = blockIdx.x * 32, k0 = blockIdx.y * 32;
  const int which = n0 >> 10;
  const float* W = (which == 0) ? W0 : (which == 1) ? W1 : (which == 2) ? W2 : W3;
  const int nl = n0 & 1023;
  const int tc = t & 31, tr8 = t >> 5;
#pragma unroll
  for (int i = 0; i < 4; ++i) {
    const int r = tr8 + i * 8;
    tile[r][tc] = W[(size_t)(k0 + r) * 1024 + nl + tc];
  }
  __syncthreads();
#pragma unroll
  for (int i = 0; i < 4; ++i) {
    const int r = tr8 + i * 8;
    Wt[(size_t)(n0 + r) * 1024 + k0 + tc] = (short)f2bfu(tile[tc][r]);
  }
}

// ---------------- transpose-convert single: W[K][N] fp32 -> Wt[N][K] bf16 ----------------
__global__ __launch_bounds__(256) void wtrans1_kernel(const float* __restrict__ W,
                                                      short* __restrict__ Wt, int K, int N) {
  __shared__ float tile[32][33];
  const int t = threadIdx.x;
  const int n0 = blockIdx.x * 32, k0 = blockIdx.y * 32;
  const int tc = t & 31, tr8 = t >> 5;
#pragma unroll
  for (int i = 0; i < 4; ++i) {
    const int r = tr8 + i * 8;
    tile[r][tc] = W[(size_t)(k0 + r) * N + n0 + tc];
  }
  __syncthreads();
#pragma unroll
  for (int i = 0; i < 4; ++i) {
    const int r = tr8 + i * 8;
    Wt[(size_t)(n0 + r) * K + k0 + tc] = (short)f2bfu(tile[tc][r]);
  }
}

// ---------------- V transpose bf16: combined buf col-slice -> Vt [(bh*128+d)][S] ----------
__global__ __launch_bounds__(256) void vtrans16_kernel(const short* __restrict__ Vb,
                                                       short* __restrict__ Vt) {
  __shared__ short tile[32][33];
  const int t = threadIdx.x;
  const int s0 = blockIdx.x * 32, d0 = blockIdx.y * 32, bh = blockIdx.z;
  const int bb = bh >> 3, h = bh & 7;
  const int tc = t & 31, tr8 = t >> 5;
#pragma unroll
  for (int i = 0; i < 4; ++i) {
    const int r = tr8 + i * 8;
    tile[r][tc] = Vb[(size_t)(bb * Ss + s0 + r) * LDQ + 2048 + h * DHd + d0 + tc];
  }
  __syncthreads();
#pragma unroll
  for (int i = 0; i < 4; ++i) {
    const int r = tr8 + i * 8;
    Vt[(size_t)(bh * DHd + d0 + r) * Ss + s0 + tc] = tile[tc][r];
  }
}

// ---------------- bf16 MFMA GEMM v10: 256x256 8-phase schedule, counted vmcnt -------------
// 512 threads = 8 waves (2M x 4N), wave tile 128x64 (acc 8x4). BK=64, db = kt&1.
// Per K-tile 4 phases: {ds-reads; 1 half-tile stage; setprio MFMA-quadrant(16); s_barrier}.
// vmcnt(4) once per K-tile (phD), 0 only at tail. Swizzle: chunk slot ^ (row&7), both sides.
template <int EPI>
__global__ __launch_bounds__(512, 2) void gemm10(const short* __restrict__ A,
                                                 const short* __restrict__ Bt,
                                                 float* __restrict__ Cf,
                                                 short* __restrict__ Cb,
                                                 const float* __restrict__ Res,
                                                 int N, int K, int ldc) {
  __shared__ __align__(16) short As[2][2][128 * 64];  // [dbuf][half] 64 KB
  __shared__ __align__(16) short Bs[2][2][128 * 64];  // 64 KB
  const int t = threadIdx.x;
  const int w = t >> 6, l = t & 63;
  const int lq = l >> 4, lr = l & 15;
  const int wr = w >> 2, wc = w & 3;
  const int bhalf = wc >> 1, brow0 = (wc & 1) * 64;
  // T1 bijective XCD swizzle (nwg % 8 == 0)
  const int nwg = gridDim.x * gridDim.y;
  const int bid0 = blockIdx.x + blockIdx.y * gridDim.x;
  const int lgid = (bid0 & 7) * (nwg >> 3) + (bid0 >> 3);
  const int bx = lgid % gridDim.x, by = lgid / gridDim.x;
  const int row0 = by * 256, col0 = bx * 256;
  const int NT = K >> 6;

  f32x4 acc[8][4] = {};
  short8v a[4][2], b[4][2];

  auto stageA = [&](int kt, int hf) {
    const int db = kt & 1;
#pragma unroll
    for (int i = 0; i < 2; ++i) {
      const int c = t + i * 512;
      const int row = c >> 3, slot = c & 7;
      gl_lds16(A + (size_t)(row0 + hf * 128 + row) * K + kt * 64 + ((slot ^ (row & 7)) << 3),
               &As[db][hf][c * 8]);
    }
  };
  auto stageB = [&](int kt, int hf) {
    const int db = kt & 1;
#pragma unroll
    for (int i = 0; i < 2; ++i) {
      const int c = t + i * 512;
      const int row = c >> 3, slot = c & 7;
      gl_lds16(Bt + (size_t)(col0 + hf * 128 + row) * K + kt * 64 + ((slot ^ (row & 7)) << 3),
               &Bs[db][hf][c * 8]);
    }
  };
  auto rdA = [&](int db, int m, int ks) -> short8v {
    const int row = m * 16 + lr;
    return *(const short8v*)&As[db][wr][row * 64 + (((ks << 2) + lq) ^ (row & 7)) * 8];
  };
  auto rdB = [&](int db, int n, int ks) -> short8v {
    const int row = brow0 + n * 16 + lr;
    return *(const short8v*)&Bs[db][bhalf][row * 64 + (((ks << 2) + lq) ^ (row & 7)) * 8];
  };

  // prologue: kt0 all 4 halves + kt1 B halves; wait kt0 landed (B(1) may fly)
  stageA(0, 0); stageA(0, 1); stageB(0, 0); stageB(0, 1);
  if (NT > 1) { stageB(1, 0); stageB(1, 1); }
  if (NT > 1) { asm volatile("s_waitcnt vmcnt(4)" ::: "memory"); }
  else        { asm volatile("s_waitcnt vmcnt(0)" ::: "memory"); }
  asm volatile("s_barrier" ::: "memory");

  for (int kt = 0; kt < NT; ++kt) {
    const int db = kt & 1;
    // ---- phA: read A-low + B-low; stage A0(kt+1); MFMA m0-3 x n0-1 ----
#pragma unroll
    for (int m = 0; m < 4; ++m) { a[m][0] = rdA(db, m, 0); a[m][1] = rdA(db, m, 1); }
#pragma unroll
    for (int n = 0; n < 2; ++n) { b[n][0] = rdB(db, n, 0); b[n][1] = rdB(db, n, 1); }
    if (kt + 1 < NT) stageA(kt + 1, 0);
    __builtin_amdgcn_s_setprio(1);
#pragma unroll
    for (int m = 0; m < 4; ++m)
#pragma unroll
      for (int n = 0; n < 2; ++n) {
        acc[m][n] = mfma16(a[m][0], b[n][0], acc[m][n]);
        acc[m][n] = mfma16(a[m][1], b[n][1], acc[m][n]);
      }
    __builtin_amdgcn_s_setprio(0);
    asm volatile("s_barrier" ::: "memory");
    // ---- phB: read B-high; stage A1(kt+1); MFMA m0-3 x n2-3 ----
#pragma unroll
    for (int n = 2; n < 4; ++n) { b[n][0] = rdB(db, n, 0); b[n][1] = rdB(db, n, 1); }
    if (kt + 1 < NT) stageA(kt + 1, 1);
    __builtin_amdgcn_s_setprio(1);
#pragma unroll
    for (int m = 0; m < 4; ++m)
#pragma unroll
      for (int n = 2; n < 4; ++n) {
        acc[m][n] = mfma16(a[m][0], b[n][0], acc[m][n]);
        acc[m][n] = mfma16(a[m][1], b[n][1], acc[m][n]);
      }
    __builtin_amdgcn_s_setprio(0);
    asm volatile("s_barrier" ::: "memory");
    // ---- phC: read A-high (reuse regs); stage B0(kt+2); MFMA m4-7 x n0-1 ----
#pragma unroll
    for (int m = 0; m < 4; ++m) { a[m][0] = rdA(db, m + 4, 0); a[m][1] = rdA(db, m + 4, 1); }
    if (kt + 2 < NT) stageB(kt + 2, 0);
    __builtin_amdgcn_s_setprio(1);
#pragma unroll
    for (int m = 0; m < 4; ++m)
#pragma unroll
      for (int n = 0; n < 2; ++n) {
        acc[m + 4][n] = mfma16(a[m][0], b[n][0], acc[m + 4][n]);
        acc[m + 4][n] = mfma16(a[m][1], b[n][1], acc[m + 4][n]);
      }
    __builtin_amdgcn_s_setprio(0);
    asm volatile("s_barrier" ::: "memory");
    // ---- phD: stage B1(kt+2); MFMA m4-7 x n2-3; counted vmcnt; barrier ----
    if (kt + 2 < NT) stageB(kt + 2, 1);
    __builtin_amdgcn_s_setprio(1);
#pragma unroll
    for (int m = 0; m < 4; ++m)
#pragma unroll
      for (int n = 2; n < 4; ++n) {
        acc[m + 4][n] = mfma16(a[m][0], b[n][0], acc[m + 4][n]);
        acc[m + 4][n] = mfma16(a[m][1], b[n][1], acc[m + 4][n]);
      }
    __builtin_amdgcn_s_setprio(0);
    if (kt + 2 < NT) { asm volatile("s_waitcnt vmcnt(4)" ::: "memory"); }
    else             { asm volatile("s_waitcnt vmcnt(0)" ::: "memory"); }
    asm volatile("s_barrier" ::: "memory");
  }

#pragma unroll
  for (int m = 0; m < 8; ++m) {
#pragma unroll
    for (int n = 0; n < 4; ++n) {
#pragma unroll
      for (int r = 0; r < 4; ++r) {
        const int row = row0 + wr * 128 + m * 16 + lq * 4 + r;
        const int col = col0 + wc * 64 + n * 16 + lr;
        const size_t o = (size_t)row * ldc + col;
        float v = acc[m][n][r];
        if (EPI == 0) Cb[o] = (short)f2bfu(v);
        else if (EPI == 1) Cf[o] = v + Res[o];
        else Cb[o] = (short)f2bfu(gelu_f(v));
      }
    }
  }
}

// ---------------- bf16 MFMA GEMM v7: m97 structure, dbuf-2, fixed XOR swizzle ------------
// 256 threads = 4 waves (2x2). Wave tile BM/2 x BN/2.
// EPI: 0 = bf16 out, 1 = +Res fp32 out, 2 = gelu bf16 out
template <int BM, int BN, int EPI>
__global__ __launch_bounds__(256) void gemm7(const short* __restrict__ A,
                                             const short* __restrict__ Bt,
                                             float* __restrict__ Cf,
                                             short* __restrict__ Cb,
                                             const float* __restrict__ Res,
                                             int N, int K, int ldc) {
  constexpr int NTHR = 256;
  constexpr int WM = BM / 2, WN = BN / 2;
  constexpr int MR = WM / 16, NR = WN / 16;
  constexpr int LA = (BM * 4) / NTHR, LB = (BN * 4) / NTHR;
  __shared__ __align__(16) short As[2][BM * 32];
  __shared__ __align__(16) short Bs[2][BN * 32];
  const int t = threadIdx.x;
  const int w = t >> 6, l = t & 63;
  const int lq = l >> 4, lr = l & 15;
  const int wr = w >> 1, wc = w & 1;
  const int nwg = gridDim.x * gridDim.y;
  const int bid0 = blockIdx.x + blockIdx.y * gridDim.x;
  const int lgid = (bid0 & 7) * (nwg >> 3) + (bid0 >> 3);
  const int bx = lgid % gridDim.x, by = lgid / gridDim.x;
  const int row0 = by * BM, col0 = bx * BN;
  f32x4 acc[MR][NR] = {};
  const int NTK = K >> 5;

  auto stage = [&](int tile, int buf) {
    const int k0 = tile << 5;
#pragma unroll
    for (int i = 0; i < LA; ++i) {
      const int c = t + i * NTHR;
      const int row = c >> 2, sc = c & 3;
      gl_lds16(A + (size_t)(row0 + row) * K + k0 + ((sc ^ ((row >> 1) & 3)) << 3),
               &As[buf][c * 8]);
    }
#pragma unroll
    for (int i = 0; i < LB; ++i) {
      const int c = t + i * NTHR;
      const int row = c >> 2, sc = c & 3;
      gl_lds16(Bt + (size_t)(col0 + row) * K + k0 + ((sc ^ ((row >> 1) & 3)) << 3),
               &Bs[buf][c * 8]);
    }
  };

  stage(0, 0);
  int cur = 0;
  for (int tt = 0; tt < NTK; ++tt) {
    __syncthreads();
    if (tt + 1 < NTK) stage(tt + 1, cur ^ 1);
    short8v a[MR], b[NR];
#pragma unroll
    for (int m = 0; m < MR; ++m) {
      const int row = wr * WM + m * 16 + lr;
      a[m] = *(const short8v*)&As[cur][row * 32 + ((lq ^ ((row >> 1) & 3)) << 3)];
    }
#pragma unroll
    for (int n = 0; n < NR; ++n) {
      const int col = wc * WN + n * 16 + lr;
      b[n] = *(const short8v*)&Bs[cur][col * 32 + ((lq ^ ((col >> 1) & 3)) << 3)];
    }
    __builtin_amdgcn_s_setprio(1);
#pragma unroll
    for (int m = 0; m < MR; ++m)
#pragma unroll
      for (int n = 0; n < NR; ++n) acc[m][n] = mfma16(a[m], b[n], acc[m][n]);
    __builtin_amdgcn_s_setprio(0);
    cur ^= 1;
  }

#pragma unroll
  for (int m = 0; m < MR; ++m) {
#pragma unroll
    for (int n = 0; n < NR; ++n) {
#pragma unroll
      for (int r = 0; r < 4; ++r) {
        const int row = row0 + wr * WM + m * 16 + lq * 4 + r;
        const int col = col0 + wc * WN + n * 16 + lr;
        const size_t o = (size_t)row * ldc + col;
        float v = acc[m][n][r];
        if (EPI == 0) Cb[o] = (short)f2bfu(v);
        else if (EPI == 1) Cf[o] = v + Res[o];
        else Cb[o] = (short)f2bfu(gelu_f(v));
      }
    }
  }
}

// ---------------- Retention v4: dbuf K/V, 1 barrier/tile, setprio, XCD-local bh ----------
__global__ __launch_bounds__(256) void ret4_kernel(const short* __restrict__ QKb,
                                                   const short* __restrict__ Vt,
                                                   float* __restrict__ Y0,
                                                   float* __restrict__ Y1) {
  __shared__ __align__(16) short Ks[2][64 * 128];
  __shared__ __align__(16) short Vs[2][128 * 64];
  const int t = threadIdx.x, w = t >> 6, l = t & 63;
  const int lq = l >> 4, lr = l & 15;
  const int u = blockIdx.x;                 // 0..511
  const int lgid = (u & 7) * 64 + (u >> 3);
  const int half = lgid >> 8;
  const int rest = lgid & 255;
  const int bh = rest >> 3, j = rest & 7;
  const int qb = half ? j : 7 - j;
  const int b = bh >> 3, h = bh & 7;
  const int q0 = qb * 128;
  const float lstep = (logf(1.f / 512.f) - logf(1.f / 32.f)) * (1.f / 7.f);
  const float gamma = 1.f - expf(logf(1.f / 32.f) + (float)h * lstep);
  const float l2g = logf(gamma) * 1.44269504f;
  const short* Qp = QKb;
  const short* Kp = QKb + 1024;

  short8v qf[2][4];
#pragma unroll
  for (int qn = 0; qn < 2; ++qn)
#pragma unroll
    for (int ks = 0; ks < 4; ++ks)
      qf[qn][ks] = *(const short8v*)(Qp + (size_t)(b * Ss + q0 + w * 32 + qn * 16 + lr) * LDQ +
                                     h * DHd + ks * 32 + lq * 8);

  float cmf[4], csr[4];
#pragma unroll
  for (int mf = 0; mf < 4; ++mf) cmf[mf] = exp2f(l2g * (float)(-16 * mf));
#pragma unroll
  for (int r = 0; r < 4; ++r) csr[r] = exp2f(l2g * (float)(63 - 4 * lq - r));

  f32x4 yacc[2][8] = {};
  const int nt = 2 * qb + 2;
  const int sb = ((lq & 1) * 2) * 16 + lr;

  auto stageKV = [&](int m0, int buf) {
#pragma unroll
    for (int i = 0; i < 4; ++i) {
      const int c = (w * 4 + i) * 64 + l;
      const int row = c >> 4, slot = c & 15;
      gl_lds16(Kp + (size_t)(b * Ss + m0 + row) * LDQ + h * DHd + ((slot ^ (row & 7)) * 8),
               &Ks[buf][(w * 4 + i) * 512]);
    }
#pragma unroll
    for (int i = 0; i < 4; ++i) {
      const int c = (w * 4 + i) * 64 + l;
      const int row = c >> 3, slot = c & 7;
      gl_lds16(Vt + (size_t)(bh * DHd + row) * Ss + m0 + ((slot ^ (row & 7)) * 8),
               &Vs[buf][(w * 4 + i) * 512]);
    }
  };

  stageKV(half * 64, 0);
  __syncthreads();
  int cur = 0;
  for (int tt = half; tt < nt; tt += 2) {
    const int m0 = tt * 64;
    if (tt + 2 < nt) stageKV((tt + 2) * 64, cur ^ 1);

    f32x4 st[4][2] = {};
    __builtin_amdgcn_s_setprio(1);
#pragma unroll
    for (int mf = 0; mf < 4; ++mf) {
      const int row = mf * 16 + lr;
#pragma unroll
      for (int ks = 0; ks < 4; ++ks) {
        short8v kf = *(const short8v*)&Ks[cur][row * 128 + (((4 * ks + lq) ^ (row & 7)) * 8)];
        st[mf][0] = mfma16(kf, qf[0][ks], st[mf][0]);
        st[mf][1] = mfma16(kf, qf[1][ks], st[mf][1]);
      }
    }
    __builtin_amdgcn_s_setprio(0);
    float rs[2];
#pragma unroll
    for (int qn = 0; qn < 2; ++qn)
      rs[qn] = exp2f(l2g * (float)(q0 + w * 32 + qn * 16 + lr - m0 - 63));
#pragma unroll
    for (int mf = 0; mf < 4; ++mf)
#pragma unroll
      for (int qn = 0; qn < 2; ++qn)
#pragma unroll
        for (int r = 0; r < 4; ++r) {
          const int qg = q0 + w * 32 + qn * 16 + lr;
          const int kvg = m0 + mf * 16 + lq * 4 + r;
          const float wgt = (qg >= kvg) ? rs[qn] * cmf[mf] * csr[r] : 0.f;
          st[mf][qn][r] *= wgt;
        }
    unsigned pk[4][2][2];
#pragma unroll
    for (int mf = 0; mf < 4; ++mf)
#pragma unroll
      for (int qn = 0; qn < 2; ++qn)
#pragma unroll
        for (int p = 0; p < 2; ++p)
          pk[mf][qn][p] = (unsigned)f2bfu(st[mf][qn][2 * p]) |
                          ((unsigned)f2bfu(st[mf][qn][2 * p + 1]) << 16);
    short8v afr[2][2];
#pragma unroll
    for (int qn = 0; qn < 2; ++qn)
#pragma unroll
      for (int ks2 = 0; ks2 < 2; ++ks2) {
        u32x4 wd;
#pragma unroll
        for (int wj = 0; wj < 4; ++wj) {
          const int src = sb + (wj >> 1) * 16;
          const unsigned v0 = __shfl(pk[2 * ks2 + 0][qn][wj & 1], src);
          const unsigned v1 = __shfl(pk[2 * ks2 + 1][qn][wj & 1], src);
          wd[wj] = (lq >= 2) ? v1 : v0;
        }
        afr[qn][ks2] = __builtin_bit_cast(short8v, wd);
      }
    __builtin_amdgcn_s_setprio(1);
#pragma unroll
    for (int nd = 0; nd < 8; ++nd) {
      const int row = nd * 16 + lr;
#pragma unroll
      for (int ks2 = 0; ks2 < 2; ++ks2) {
        short8v vf = *(const short8v*)&Vs[cur][row * 64 + (((4 * ks2 + lq) ^ (row & 7)) * 8)];
        yacc[0][nd] = mfma16(afr[0][ks2], vf, yacc[0][nd]);
        yacc[1][nd] = mfma16(afr[1][ks2], vf, yacc[1][nd]);
      }
    }
    __builtin_amdgcn_s_setprio(0);
    __syncthreads();
    cur ^= 1;
  }
  float* Y = half ? Y1 : Y0;
#pragma unroll
  for (int qn = 0; qn < 2; ++qn)
#pragma unroll
    for (int r = 0; r < 4; ++r) {
      const int q = q0 + w * 32 + qn * 16 + lq * 4 + r;
#pragma unroll
      for (int nd = 0; nd < 8; ++nd)
        Y[(size_t)(b * Ss + q) * Dd + h * DHd + nd * 16 + lr] = yacc[qn][nd][r];
    }
}

// ---------------- gate: Gb = bf16( swish(Graw) * GN(Y0+Y1) ) ----------------
__global__ __launch_bounds__(256) void gate_kernel(const float* __restrict__ Y0,
                                                   const float* __restrict__ Y1,
                                                   const short* __restrict__ Graw,
                                                   short* __restrict__ Gb,
                                                   const float* __restrict__ gs,
                                                   const float* __restrict__ gb) {
  const int lane = threadIdx.x & 63;
  const int rowh = blockIdx.x * 4 + (threadIdx.x >> 6);  // (b*S+s)*H + h
  const int h = rowh & 7;
  const int row = rowh >> 3;
  const size_t ybase = (size_t)row * Dd + (size_t)h * DHd + lane * 2;
  float2 a = *(const float2*)(Y0 + ybase);
  const float2 c = *(const float2*)(Y1 + ybase);
  a.x += c.x; a.y += c.y;
  float s = a.x + a.y, s2 = a.x * a.x + a.y * a.y;
#pragma unroll
  for (int o = 32; o > 0; o >>= 1) { s += __shfl_down(s, o); s2 += __shfl_down(s2, o); }
  s = __shfl(s, 0);
  s2 = __shfl(s2, 0);
  const float mu = s * (1.f / DHd);
  const float rstd = rsqrtf(s2 * (1.f / DHd) - mu * mu + EPSf);
  const int d = h * DHd + lane * 2;
  const float2 g = *(const float2*)(gs + d);
  const float2 bbv = *(const float2*)(gb + d);
  const float y0 = (a.x - mu) * rstd * g.x + bbv.x;
  const float y1 = (a.y - mu) * rstd * g.y + bbv.y;
  const unsigned gr = *(const unsigned*)(Graw + (size_t)row * LDQ + 3072 + h * DHd + lane * 2);
  const float gx = bfu2f((unsigned short)(gr & 0xffff));
  const float gy = bfu2f((unsigned short)(gr >> 16));
  const unsigned o01 = (unsigned)f2bfu(swish_f(gx) * y0) |
                       ((unsigned)f2bfu(swish_f(gy) * y1) << 16);
  *(unsigned*)(Gb + ybase) = o01;
}

extern "C" void kernel_launch(void* const* d_in, const int* in_sizes, int n_in,
                              void* d_out, int out_size, void* d_ws, size_t ws_size,
                              hipStream_t stream) {
  const float* X = (const float*)d_in[0];
  const float* Wq = (const float*)d_in[1];
  const float* Wk = (const float*)d_in[2];
  const float* Wv = (const float*)d_in[3];
  const float* Wg = (const float*)d_in[4];
  const float* Wo = (const float*)d_in[5];
  const float* W1 = (const float*)d_in[6];
  const float* W2 = (const float*)d_in[7];
  const float* lns = (const float*)d_in[8];
  const float* lnb = (const float*)d_in[9];
  const float* gns = (const float*)d_in[10];
  const float* gnb = (const float*)d_in[11];
  float* out = (float*)d_out;

  char* W = (char*)d_ws;
  const size_t MB = 1u << 20;
  float* Abuf  = (float*)(W);             // 16 MB fp32
  short* Xnb   = (short*)(W + 16 * MB);   // 8 MB bf16
  short* QKVGb = (short*)(W + 24 * MB);   // 32 MB bf16 [4096][4096]; Hb aliases first 16 MB
  float* Y0    = (float*)(W + 56 * MB);   // 16 MB fp32
  float* Y1    = (float*)(W + 72 * MB);   // 16 MB fp32
  short* Vtb   = (short*)(W + 88 * MB);   // 8 MB bf16
  short* Gb    = (short*)(W + 96 * MB);   // 8 MB bf16
  short* Wqkvgt= (short*)(W + 104 * MB);  // 8 MB
  short* Wot   = (short*)(W + 112 * MB);  // 2 MB
  short* W1t   = (short*)(W + 114 * MB);  // 4 MB
  short* W2t   = (short*)(W + 118 * MB);  // 4 MB
  float* ct    = (float*)(W + 122 * MB);  // 256 KB
  float* st    = ct + Ss * 64;            // 256 KB
  short* Hb = QKVGb;  // FFN hidden 4096x2048 bf16 (16 MB)

  hipMemcpyAsync(Abuf, X, (size_t)Mm * Dd * sizeof(float), hipMemcpyDeviceToDevice, stream);
  rope_table_kernel<<<(Ss * 64) / 256, 256, 0, stream>>>(ct, st);

  for (int l = 0; l < LAYERS; ++l) {
    const size_t DD = (size_t)Dd * Dd;
    wtrans4_kernel<<<dim3(128, 32), 256, 0, stream>>>(Wq + l * DD, Wk + l * DD, Wv + l * DD,
                                                      Wg + l * DD, Wqkvgt);
    wtrans1_kernel<<<dim3(32, 32), 256, 0, stream>>>(Wo + l * DD, Wot, Dd, Dd);
    wtrans1_kernel<<<dim3(64, 32), 256, 0, stream>>>(W1 + (size_t)l * Dd * Ff, W1t, Dd, Ff);
    wtrans1_kernel<<<dim3(32, 64), 256, 0, stream>>>(W2 + (size_t)l * Ff * Dd, W2t, Ff, Dd);

    // Xn = LN(A) -> bf16
    ln_bf16_kernel<<<Mm, 256, 0, stream>>>(Abuf, Xnb, lns, lnb);
    // fused QKVG projection -> combined bf16 buffer (8-phase 256x256, 256 blocks = 1/CU)
    gemm10<0><<<dim3(16, 16), 512, 0, stream>>>(Xnb, Wqkvgt, nullptr, QKVGb,
                                                nullptr, 4096, Dd, LDQ);
    // RoPE in-place on Q,K slices
    rope_ip_kernel<<<(Bb * Ss * Hh * 64) / 256, 256, 0, stream>>>(QKVGb, ct, st);
    // V transpose
    vtrans16_kernel<<<dim3(Ss / 32, DHd / 32, Bb * Hh), 256, 0, stream>>>(QKVGb, Vtb);
    // retention -> partial Y0,Y1 (fp32)
    ret4_kernel<<<512, 256, 0, stream>>>(QKVGb, Vtb, Y0, Y1);
    // gate: Gb = swish(Graw) * GN(Y0+Y1)
    gate_kernel<<<(Mm * Hh) / 4, 256, 0, stream>>>(Y0, Y1, QKVGb, Gb,
                                                   gns + (size_t)l * Dd, gnb + (size_t)l * Dd);
    // A = (Gb @ Wo) + A : 128x64 tiles, 512 blocks
    gemm7<128, 64, 1><<<dim3(16, 32), 256, 0, stream>>>(Gb, Wot, Abuf, nullptr, Abuf,
                                                        Dd, Dd, Dd);
    // FFN
    ln_bf16_kernel<<<Mm, 256, 0, stream>>>(Abuf, Xnb, lns, lnb);
    // W1: 128x64 tiles -> 1024 blocks = 4/CU
    gemm7<128, 64, 2><<<dim3(32, 32), 256, 0, stream>>>(Xnb, W1t, nullptr, Hb, nullptr,
                                                        Ff, Dd, Ff);
    float* dst = (l == LAYERS - 1) ? out : Abuf;
    // W2: 64x64 tiles -> 1024 blocks = 4/CU
    gemm7<64, 64, 1><<<dim3(16, 64), 256, 0, stream>>>(Hb, W2t, dst, nullptr, Abuf,
                                                       Dd, Ff, Dd);
  }
}

// Round 12
// 801.153 us; speedup vs baseline: 1.4429x; 1.0311x over previous
//
#include <hip/hip_runtime.h>
#include <hip/hip_bf16.h>
#include <cmath>

#define LAYERS 4
#define Bb 4
#define Ss 1024
#define Dd 1024
#define Ff 2048
#define Hh 8
#define DHd 128
#define Mm (Bb * Ss)   // 4096 rows
#define EPSf 1e-5f
#define LDQ 4096       // combined QKVG row stride

typedef __attribute__((ext_vector_type(8))) short short8v;
typedef __attribute__((ext_vector_type(4))) float f32x4;
typedef __attribute__((ext_vector_type(4))) unsigned int u32x4;

__device__ __forceinline__ float swish_f(float x) { return x / (1.f + expf(-x)); }
__device__ __forceinline__ float gelu_f(float x) {
  return 0.5f * x * (1.f + tanhf(0.7978845608028654f * (x + 0.044715f * x * x * x)));
}
__device__ __forceinline__ unsigned short f2bfu(float f) {
  __hip_bfloat16 h = __float2bfloat16(f);
  return __builtin_bit_cast(unsigned short, h);
}
__device__ __forceinline__ float bfu2f(unsigned short u) {
  unsigned v = ((unsigned)u) << 16;
  return __builtin_bit_cast(float, v);
}
__device__ __forceinline__ void gl_lds16(const void* g, void* l) {
  __builtin_amdgcn_global_load_lds((__attribute__((address_space(1))) void*)g,
                                   (__attribute__((address_space(3))) void*)l, 16, 0, 0);
}
__device__ __forceinline__ f32x4 mfma16(short8v a, short8v b, f32x4 c) {
  return __builtin_amdgcn_mfma_f32_16x16x32_bf16(a, b, c, 0, 0, 0);
}

// ---------------- LayerNorm fp32 -> bf16 ----------------
__global__ __launch_bounds__(256) void ln_bf16_kernel(const float* __restrict__ x,
                                                      short* __restrict__ outb,
                                                      const float* __restrict__ sc,
                                                      const float* __restrict__ bi) {
  const int row = blockIdx.x;
  const int t = threadIdx.x;
  const float4 v = *(const float4*)(x + (size_t)row * Dd + t * 4);
  float s = v.x + v.y + v.z + v.w;
  float s2 = v.x * v.x + v.y * v.y + v.z * v.z + v.w * v.w;
#pragma unroll
  for (int o = 32; o > 0; o >>= 1) { s += __shfl_down(s, o); s2 += __shfl_down(s2, o); }
  __shared__ float ps[4], ps2[4];
  if ((t & 63) == 0) { ps[t >> 6] = s; ps2[t >> 6] = s2; }
  __syncthreads();
  s = ps[0] + ps[1] + ps[2] + ps[3];
  s2 = ps2[0] + ps2[1] + ps2[2] + ps2[3];
  const float mu = s * (1.f / Dd);
  const float var = s2 * (1.f / Dd) - mu * mu;
  const float rstd = rsqrtf(var + EPSf);
  const float4 g = *(const float4*)(sc + t * 4);
  const float4 b = *(const float4*)(bi + t * 4);
  const float o0 = (v.x - mu) * rstd * g.x + b.x;
  const float o1 = (v.y - mu) * rstd * g.y + b.y;
  const float o2 = (v.z - mu) * rstd * g.z + b.z;
  const float o3 = (v.w - mu) * rstd * g.w + b.w;
  unsigned p0 = (unsigned)f2bfu(o0) | ((unsigned)f2bfu(o1) << 16);
  unsigned p1 = (unsigned)f2bfu(o2) | ((unsigned)f2bfu(o3) << 16);
  uint2 pk; pk.x = p0; pk.y = p1;
  *(uint2*)(outb + (size_t)row * Dd + t * 4) = pk;
}

// ---------------- RoPE tables ----------------
__global__ void rope_table_kernel(float* __restrict__ ct, float* __restrict__ st) {
  const int i = blockIdx.x * 256 + threadIdx.x;  // < Ss*64
  const int s = i >> 6, f = i & 63;
  const float inv = powf(10000.f, -(float)f / 64.f);
  const float a = (float)s * inv;
  ct[i] = cosf(a);
  st[i] = sinf(a);
}

// ---------------- RoPE in-place on combined bf16 QKVG buffer (Q:+sin, K:-sin) -------------
__global__ void rope_ip_kernel(short* __restrict__ QK, const float* __restrict__ ct,
                               const float* __restrict__ st) {
  const int idx = blockIdx.x * 256 + threadIdx.x;  // < B*S*H*64
  const int f = idx & 63;
  const int h = (idx >> 6) & 7;
  const int r = idx >> 9;            // b*S+s
  const int s = r & (Ss - 1);
  const float c = ct[(s << 6) + f], sn = st[(s << 6) + f];
  const size_t qo = (size_t)r * LDQ + h * DHd + 2 * f;
  const unsigned qp = *(const unsigned*)(QK + qo);
  const unsigned kp = *(const unsigned*)(QK + qo + 1024);
  const float qx = bfu2f((unsigned short)(qp & 0xffff)), qy = bfu2f((unsigned short)(qp >> 16));
  const float kx = bfu2f((unsigned short)(kp & 0xffff)), ky = bfu2f((unsigned short)(kp >> 16));
  const unsigned qn = (unsigned)f2bfu(qx * c - qy * sn) | ((unsigned)f2bfu(qx * sn + qy * c) << 16);
  const unsigned kn = (unsigned)f2bfu(kx * c + ky * sn) | ((unsigned)f2bfu(-kx * sn + ky * c) << 16);
  *(unsigned*)(QK + qo) = qn;
  *(unsigned*)(QK + qo + 1024) = kn;
}

// ---------------- transpose-convert QKVG concat: 4x W[K][1024] fp32 -> Wt[4096][K] bf16 ----
__global__ __launch_bounds__(256) void wtrans4_kernel(const float* __restrict__ W0,
                                                      const float* __restrict__ W1,
                                                      const float* __restrict__ W2,
                                                      const float* __restrict__ W3,
                                                      short* __restrict__ Wt) {
  __shared__ float tile[32][33];
  const int t = threadIdx.x;
  const int n0 = blockIdx.x * 32, k0 = blockIdx.y * 32;
  const int which = n0 >> 10;
  const float* W = (which == 0) ? W0 : (which == 1) ? W1 : (which == 2) ? W2 : W3;
  const int nl = n0 & 1023;
  const int tc = t & 31, tr8 = t >> 5;
#pragma unroll
  for (int i = 0; i < 4; ++i) {
    const int r = tr8 + i * 8;
    tile[r][tc] = W[(size_t)(k0 + r) * 1024 + nl + tc];
  }
  __syncthreads();
#pragma unroll
  for (int i = 0; i < 4; ++i) {
    const int r = tr8 + i * 8;
    Wt[(size_t)(n0 + r) * 1024 + k0 + tc] = (short)f2bfu(tile[tc][r]);
  }
}

// ---------------- transpose-convert single: W[K][N] fp32 -> Wt[N][K] bf16 ----------------
__global__ __launch_bounds__(256) void wtrans1_kernel(const float* __restrict__ W,
                                                      short* __restrict__ Wt, int K, int N) {
  __shared__ float tile[32][33];
  const int t = threadIdx.x;
  const int n0 = blockIdx.x * 32, k0 = blockIdx.y * 32;
  const int tc = t & 31, tr8 = t >> 5;
#pragma unroll
  for (int i = 0; i < 4; ++i) {
    const int r = tr8 + i * 8;
    tile[r][tc] = W[(size_t)(k0 + r) * N + n0 + tc];
  }
  __syncthreads();
#pragma unroll
  for (int i = 0; i < 4; ++i) {
    const int r = tr8 + i * 8;
    Wt[(size_t)(n0 + r) * K + k0 + tc] = (short)f2bfu(tile[tc][r]);
  }
}

// ---------------- V transpose bf16: combined buf col-slice -> Vt [(bh*128+d)][S] ----------
__global__ __launch_bounds__(256) void vtrans16_kernel(const short* __restrict__ Vb,
                                                       short* __restrict__ Vt) {
  __shared__ short tile[32][33];
  const int t = threadIdx.x;
  const int s0 = blockIdx.x * 32, d0 = blockIdx.y * 32, bh = blockIdx.z;
  const int bb = bh >> 3, h = bh & 7;
  const int tc = t & 31, tr8 = t >> 5;
#pragma unroll
  for (int i = 0; i < 4; ++i) {
    const int r = tr8 + i * 8;
    tile[r][tc] = Vb[(size_t)(bb * Ss + s0 + r) * LDQ + 2048 + h * DHd + d0 + tc];
  }
  __syncthreads();
#pragma unroll
  for (int i = 0; i < 4; ++i) {
    const int r = tr8 + i * 8;
    Vt[(size_t)(bh * DHd + d0 + r) * Ss + s0 + tc] = tile[tc][r];
  }
}

// ---------------- bf16 MFMA GEMM v10: 256x256 8-phase schedule, counted vmcnt -------------
template <int EPI>
__global__ __launch_bounds__(512, 2) void gemm10(const short* __restrict__ A,
                                                 const short* __restrict__ Bt,
                                                 float* __restrict__ Cf,
                                                 short* __restrict__ Cb,
                                                 const float* __restrict__ Res,
                                                 int N, int K, int ldc) {
  __shared__ __align__(16) short As[2][2][128 * 64];  // [dbuf][half] 64 KB
  __shared__ __align__(16) short Bs[2][2][128 * 64];  // 64 KB
  const int t = threadIdx.x;
  const int w = t >> 6, l = t & 63;
  const int lq = l >> 4, lr = l & 15;
  const int wr = w >> 2, wc = w & 3;
  const int bhalf = wc >> 1, brow0 = (wc & 1) * 64;
  const int nwg = gridDim.x * gridDim.y;
  const int bid0 = blockIdx.x + blockIdx.y * gridDim.x;
  const int lgid = (bid0 & 7) * (nwg >> 3) + (bid0 >> 3);
  const int bx = lgid % gridDim.x, by = lgid / gridDim.x;
  const int row0 = by * 256, col0 = bx * 256;
  const int NT = K >> 6;

  f32x4 acc[8][4] = {};
  short8v a[4][2], b[4][2];

  auto stageA = [&](int kt, int hf) {
    const int db = kt & 1;
#pragma unroll
    for (int i = 0; i < 2; ++i) {
      const int c = t + i * 512;
      const int row = c >> 3, slot = c & 7;
      gl_lds16(A + (size_t)(row0 + hf * 128 + row) * K + kt * 64 + ((slot ^ (row & 7)) << 3),
               &As[db][hf][c * 8]);
    }
  };
  auto stageB = [&](int kt, int hf) {
    const int db = kt & 1;
#pragma unroll
    for (int i = 0; i < 2; ++i) {
      const int c = t + i * 512;
      const int row = c >> 3, slot = c & 7;
      gl_lds16(Bt + (size_t)(col0 + hf * 128 + row) * K + kt * 64 + ((slot ^ (row & 7)) << 3),
               &Bs[db][hf][c * 8]);
    }
  };
  auto rdA = [&](int db, int m, int ks) -> short8v {
    const int row = m * 16 + lr;
    return *(const short8v*)&As[db][wr][row * 64 + (((ks << 2) + lq) ^ (row & 7)) * 8];
  };
  auto rdB = [&](int db, int n, int ks) -> short8v {
    const int row = brow0 + n * 16 + lr;
    return *(const short8v*)&Bs[db][bhalf][row * 64 + (((ks << 2) + lq) ^ (row & 7)) * 8];
  };

  stageA(0, 0); stageA(0, 1); stageB(0, 0); stageB(0, 1);
  if (NT > 1) { stageB(1, 0); stageB(1, 1); }
  if (NT > 1) { asm volatile("s_waitcnt vmcnt(4)" ::: "memory"); }
  else        { asm volatile("s_waitcnt vmcnt(0)" ::: "memory"); }
  asm volatile("s_barrier" ::: "memory");

  for (int kt = 0; kt < NT; ++kt) {
    const int db = kt & 1;
#pragma unroll
    for (int m = 0; m < 4; ++m) { a[m][0] = rdA(db, m, 0); a[m][1] = rdA(db, m, 1); }
#pragma unroll
    for (int n = 0; n < 2; ++n) { b[n][0] = rdB(db, n, 0); b[n][1] = rdB(db, n, 1); }
    if (kt + 1 < NT) stageA(kt + 1, 0);
    __builtin_amdgcn_s_setprio(1);
#pragma unroll
    for (int m = 0; m < 4; ++m)
#pragma unroll
      for (int n = 0; n < 2; ++n) {
        acc[m][n] = mfma16(a[m][0], b[n][0], acc[m][n]);
        acc[m][n] = mfma16(a[m][1], b[n][1], acc[m][n]);
      }
    __builtin_amdgcn_s_setprio(0);
    asm volatile("s_barrier" ::: "memory");
#pragma unroll
    for (int n = 2; n < 4; ++n) { b[n][0] = rdB(db, n, 0); b[n][1] = rdB(db, n, 1); }
    if (kt + 1 < NT) stageA(kt + 1, 1);
    __builtin_amdgcn_s_setprio(1);
#pragma unroll
    for (int m = 0; m < 4; ++m)
#pragma unroll
      for (int n = 2; n < 4; ++n) {
        acc[m][n] = mfma16(a[m][0], b[n][0], acc[m][n]);
        acc[m][n] = mfma16(a[m][1], b[n][1], acc[m][n]);
      }
    __builtin_amdgcn_s_setprio(0);
    asm volatile("s_barrier" ::: "memory");
#pragma unroll
    for (int m = 0; m < 4; ++m) { a[m][0] = rdA(db, m + 4, 0); a[m][1] = rdA(db, m + 4, 1); }
    if (kt + 2 < NT) stageB(kt + 2, 0);
    __builtin_amdgcn_s_setprio(1);
#pragma unroll
    for (int m = 0; m < 4; ++m)
#pragma unroll
      for (int n = 0; n < 2; ++n) {
        acc[m + 4][n] = mfma16(a[m][0], b[n][0], acc[m + 4][n]);
        acc[m + 4][n] = mfma16(a[m][1], b[n][1], acc[m + 4][n]);
      }
    __builtin_amdgcn_s_setprio(0);
    asm volatile("s_barrier" ::: "memory");
    if (kt + 2 < NT) stageB(kt + 2, 1);
    __builtin_amdgcn_s_setprio(1);
#pragma unroll
    for (int m = 0; m < 4; ++m)
#pragma unroll
      for (int n = 2; n < 4; ++n) {
        acc[m + 4][n] = mfma16(a[m][0], b[n][0], acc[m + 4][n]);
        acc[m + 4][n] = mfma16(a[m][1], b[n][1], acc[m + 4][n]);
      }
    __builtin_amdgcn_s_setprio(0);
    if (kt + 2 < NT) { asm volatile("s_waitcnt vmcnt(4)" ::: "memory"); }
    else             { asm volatile("s_waitcnt vmcnt(0)" ::: "memory"); }
    asm volatile("s_barrier" ::: "memory");
  }

#pragma unroll
  for (int m = 0; m < 8; ++m) {
#pragma unroll
    for (int n = 0; n < 4; ++n) {
#pragma unroll
      for (int r = 0; r < 4; ++r) {
        const int row = row0 + wr * 128 + m * 16 + lq * 4 + r;
        const int col = col0 + wc * 64 + n * 16 + lr;
        const size_t o = (size_t)row * ldc + col;
        float v = acc[m][n][r];
        if (EPI == 0) Cb[o] = (short)f2bfu(v);
        else if (EPI == 1) Cf[o] = v + Res[o];
        else Cb[o] = (short)f2bfu(gelu_f(v));
      }
    }
  }
}

// ---------------- bf16 MFMA GEMM v11: 256x128 2-phase/K-tile, ring-3 LDS, vmcnt(6) --------
// 512 threads = 8 waves (2M x 4N), wave tile 128x32 (acc 8x2). BK=64. Grid = 1D, nxt N-tiles.
// EPI: 0 = bf16 out, 1 = +Res fp32 out, 2 = gelu bf16 out
template <int EPI>
__global__ __launch_bounds__(512) void gemm11(const short* __restrict__ A,
                                              const short* __restrict__ Bt,
                                              float* __restrict__ Cf,
                                              short* __restrict__ Cb,
                                              const float* __restrict__ Res,
                                              int K, int lda, int ldb, int ldc, int nxt) {
  __shared__ __align__(16) short As[3][256 * 64];  // 96 KB ring-3
  __shared__ __align__(16) short Bs[3][128 * 64];  // 48 KB ring-3
  const int t = threadIdx.x;
  const int w = t >> 6, l = t & 63;
  const int lq = l >> 4, lr = l & 15;
  const int wr = w >> 2, wc = w & 3;
  const int nwg = gridDim.x;
  const int lgid = (blockIdx.x & 7) * (nwg >> 3) + (blockIdx.x >> 3);
  const int mt = lgid / nxt, nt_ = lgid % nxt;
  const int row0 = mt * 256, col0 = nt_ * 128;
  const int NT = K >> 6;
  f32x4 acc[8][2] = {};
  short8v a[4][2], b[2][2];

  auto stageA = [&](int kt, int hf) {
    const int s = kt % 3;
#pragma unroll
    for (int i = 0; i < 2; ++i) {
      const int c = t + i * 512;
      const int row = c >> 3, slot = c & 7;
      gl_lds16(A + (size_t)(row0 + hf * 128 + row) * lda + kt * 64 + ((slot ^ (row & 7)) << 3),
               &As[s][hf * 8192 + c * 8]);
    }
  };
  auto stageB = [&](int kt) {
    const int s = kt % 3;
#pragma unroll
    for (int i = 0; i < 2; ++i) {
      const int c = t + i * 512;
      const int row = c >> 3, slot = c & 7;
      gl_lds16(Bt + (size_t)(col0 + row) * ldb + kt * 64 + ((slot ^ (row & 7)) << 3),
               &Bs[s][c * 8]);
    }
  };
  auto rdA = [&](int s, int m, int ks) -> short8v {
    const int row = wr * 128 + m * 16 + lr;
    return *(const short8v*)&As[s][row * 64 + (((ks << 2) + lq) ^ (row & 7)) * 8];
  };
  auto rdB = [&](int s, int n, int ks) -> short8v {
    const int row = wc * 32 + n * 16 + lr;
    return *(const short8v*)&Bs[s][row * 64 + (((ks << 2) + lq) ^ (row & 7)) * 8];
  };

  // prologue: tiles 0 and 1 fully staged (12 loads); wait for tile 0 (6 newest keep flying)
  stageA(0, 0); stageA(0, 1); stageB(0);
  stageA(1, 0); stageA(1, 1); stageB(1);
  asm volatile("s_waitcnt vmcnt(6)" ::: "memory");
  asm volatile("s_barrier" ::: "memory");

  for (int kt = 0; kt < NT; ++kt) {
    const int s = kt % 3;
    // ph1: read a(m0-3)+b(all); stage A0(kt+2); MFMA m0-3 (16)
#pragma unroll
    for (int m = 0; m < 4; ++m) { a[m][0] = rdA(s, m, 0); a[m][1] = rdA(s, m, 1); }
#pragma unroll
    for (int n = 0; n < 2; ++n) { b[n][0] = rdB(s, n, 0); b[n][1] = rdB(s, n, 1); }
    if (kt + 2 < NT) stageA(kt + 2, 0);
    __builtin_amdgcn_s_setprio(1);
#pragma unroll
    for (int m = 0; m < 4; ++m)
#pragma unroll
      for (int n = 0; n < 2; ++n) {
        acc[m][n] = mfma16(a[m][0], b[n][0], acc[m][n]);
        acc[m][n] = mfma16(a[m][1], b[n][1], acc[m][n]);
      }
    __builtin_amdgcn_s_setprio(0);
    asm volatile("s_barrier" ::: "memory");
    // ph2: read a(m4-7); stage A1(kt+2)+B(kt+2); MFMA m4-7 (16); vmcnt(6); barrier
#pragma unroll
    for (int m = 0; m < 4; ++m) { a[m][0] = rdA(s, m + 4, 0); a[m][1] = rdA(s, m + 4, 1); }
    if (kt + 2 < NT) { stageA(kt + 2, 1); stageB(kt + 2); }
    __builtin_amdgcn_s_setprio(1);
#pragma unroll
    for (int m = 0; m < 4; ++m)
#pragma unroll
      for (int n = 0; n < 2; ++n) {
        acc[m + 4][n] = mfma16(a[m][0], b[n][0], acc[m + 4][n]);
        acc[m + 4][n] = mfma16(a[m][1], b[n][1], acc[m + 4][n]);
      }
    __builtin_amdgcn_s_setprio(0);
    if (kt + 2 < NT) { asm volatile("s_waitcnt vmcnt(6)" ::: "memory"); }
    else             { asm volatile("s_waitcnt vmcnt(0)" ::: "memory"); }
    asm volatile("s_barrier" ::: "memory");
  }

#pragma unroll
  for (int m = 0; m < 8; ++m) {
#pragma unroll
    for (int n = 0; n < 2; ++n) {
#pragma unroll
      for (int r = 0; r < 4; ++r) {
        const int row = row0 + wr * 128 + m * 16 + lq * 4 + r;
        const int col = col0 + wc * 32 + n * 16 + lr;
        const size_t o = (size_t)row * ldc + col;
        float v = acc[m][n][r];
        if (EPI == 0) Cb[o] = (short)f2bfu(v);
        else if (EPI == 1) Cf[o] = v + Res[o];
        else Cb[o] = (short)f2bfu(gelu_f(v));
      }
    }
  }
}

// ---------------- bf16 MFMA GEMM v7: m97 structure, dbuf-2, fixed XOR swizzle ------------
template <int BM, int BN, int EPI>
__global__ __launch_bounds__(256) void gemm7(const short* __restrict__ A,
                                             const short* __restrict__ Bt,
                                             float* __restrict__ Cf,
                                             short* __restrict__ Cb,
                                             const float* __restrict__ Res,
                                             int N, int K, int ldc) {
  constexpr int NTHR = 256;
  constexpr int WM = BM / 2, WN = BN / 2;
  constexpr int MR = WM / 16, NR = WN / 16;
  constexpr int LA = (BM * 4) / NTHR, LB = (BN * 4) / NTHR;
  __shared__ __align__(16) short As[2][BM * 32];
  __shared__ __align__(16) short Bs[2][BN * 32];
  const int t = threadIdx.x;
  const int w = t >> 6, l = t & 63;
  const int lq = l >> 4, lr = l & 15;
  const int wr = w >> 1, wc = w & 1;
  const int nwg = gridDim.x * gridDim.y;
  const int bid0 = blockIdx.x + blockIdx.y * gridDim.x;
  const int lgid = (bid0 & 7) * (nwg >> 3) + (bid0 >> 3);
  const int bx = lgid % gridDim.x, by = lgid / gridDim.x;
  const int row0 = by * BM, col0 = bx * BN;
  f32x4 acc[MR][NR] = {};
  const int NTK = K >> 5;

  auto stage = [&](int tile, int buf) {
    const int k0 = tile << 5;
#pragma unroll
    for (int i = 0; i < LA; ++i) {
      const int c = t + i * NTHR;
      const int row = c >> 2, sc = c & 3;
      gl_lds16(A + (size_t)(row0 + row) * K + k0 + ((sc ^ ((row >> 1) & 3)) << 3),
               &As[buf][c * 8]);
    }
#pragma unroll
    for (int i = 0; i < LB; ++i) {
      const int c = t + i * NTHR;
      const int row = c >> 2, sc = c & 3;
      gl_lds16(Bt + (size_t)(col0 + row) * K + k0 + ((sc ^ ((row >> 1) & 3)) << 3),
               &Bs[buf][c * 8]);
    }
  };

  stage(0, 0);
  int cur = 0;
  for (int tt = 0; tt < NTK; ++tt) {
    __syncthreads();
    if (tt + 1 < NTK) stage(tt + 1, cur ^ 1);
    short8v a[MR], b[NR];
#pragma unroll
    for (int m = 0; m < MR; ++m) {
      const int row = wr * WM + m * 16 + lr;
      a[m] = *(const short8v*)&As[cur][row * 32 + ((lq ^ ((row >> 1) & 3)) << 3)];
    }
#pragma unroll
    for (int n = 0; n < NR; ++n) {
      const int col = wc * WN + n * 16 + lr;
      b[n] = *(const short8v*)&Bs[cur][col * 32 + ((lq ^ ((col >> 1) & 3)) << 3)];
    }
    __builtin_amdgcn_s_setprio(1);
#pragma unroll
    for (int m = 0; m < MR; ++m)
#pragma unroll
      for (int n = 0; n < NR; ++n) acc[m][n] = mfma16(a[m], b[n], acc[m][n]);
    __builtin_amdgcn_s_setprio(0);
    cur ^= 1;
  }

#pragma unroll
  for (int m = 0; m < MR; ++m) {
#pragma unroll
    for (int n = 0; n < NR; ++n) {
#pragma unroll
      for (int r = 0; r < 4; ++r) {
        const int row = row0 + wr * WM + m * 16 + lq * 4 + r;
        const int col = col0 + wc * WN + n * 16 + lr;
        const size_t o = (size_t)row * ldc + col;
        float v = acc[m][n][r];
        if (EPI == 0) Cb[o] = (short)f2bfu(v);
        else if (EPI == 1) Cf[o] = v + Res[o];
        else Cb[o] = (short)f2bfu(gelu_f(v));
      }
    }
  }
}

// ---------------- Retention v4: dbuf K/V, 1 barrier/tile, setprio, XCD-local bh ----------
__global__ __launch_bounds__(256) void ret4_kernel(const short* __restrict__ QKb,
                                                   const short* __restrict__ Vt,
                                                   float* __restrict__ Y0,
                                                   float* __restrict__ Y1) {
  __shared__ __align__(16) short Ks[2][64 * 128];
  __shared__ __align__(16) short Vs[2][128 * 64];
  const int t = threadIdx.x, w = t >> 6, l = t & 63;
  const int lq = l >> 4, lr = l & 15;
  const int u = blockIdx.x;                 // 0..511
  const int lgid = (u & 7) * 64 + (u >> 3);
  const int half = lgid >> 8;
  const int rest = lgid & 255;
  const int bh = rest >> 3, j = rest & 7;
  const int qb = half ? j : 7 - j;
  const int b = bh >> 3, h = bh & 7;
  const int q0 = qb * 128;
  const float lstep = (logf(1.f / 512.f) - logf(1.f / 32.f)) * (1.f / 7.f);
  const float gamma = 1.f - expf(logf(1.f / 32.f) + (float)h * lstep);
  const float l2g = logf(gamma) * 1.44269504f;
  const short* Qp = QKb;
  const short* Kp = QKb + 1024;

  short8v qf[2][4];
#pragma unroll
  for (int qn = 0; qn < 2; ++qn)
#pragma unroll
    for (int ks = 0; ks < 4; ++ks)
      qf[qn][ks] = *(const short8v*)(Qp + (size_t)(b * Ss + q0 + w * 32 + qn * 16 + lr) * LDQ +
                                     h * DHd + ks * 32 + lq * 8);

  float cmf[4], csr[4];
#pragma unroll
  for (int mf = 0; mf < 4; ++mf) cmf[mf] = exp2f(l2g * (float)(-16 * mf));
#pragma unroll
  for (int r = 0; r < 4; ++r) csr[r] = exp2f(l2g * (float)(63 - 4 * lq - r));

  f32x4 yacc[2][8] = {};
  const int nt = 2 * qb + 2;
  const int sb = ((lq & 1) * 2) * 16 + lr;

  auto stageKV = [&](int m0, int buf) {
#pragma unroll
    for (int i = 0; i < 4; ++i) {
      const int c = (w * 4 + i) * 64 + l;
      const int row = c >> 4, slot = c & 15;
      gl_lds16(Kp + (size_t)(b * Ss + m0 + row) * LDQ + h * DHd + ((slot ^ (row & 7)) * 8),
               &Ks[buf][(w * 4 + i) * 512]);
    }
#pragma unroll
    for (int i = 0; i < 4; ++i) {
      const int c = (w * 4 + i) * 64 + l;
      const int row = c >> 3, slot = c & 7;
      gl_lds16(Vt + (size_t)(bh * DHd + row) * Ss + m0 + ((slot ^ (row & 7)) * 8),
               &Vs[buf][(w * 4 + i) * 512]);
    }
  };

  stageKV(half * 64, 0);
  __syncthreads();
  int cur = 0;
  for (int tt = half; tt < nt; tt += 2) {
    const int m0 = tt * 64;
    if (tt + 2 < nt) stageKV((tt + 2) * 64, cur ^ 1);

    f32x4 st[4][2] = {};
    __builtin_amdgcn_s_setprio(1);
#pragma unroll
    for (int mf = 0; mf < 4; ++mf) {
      const int row = mf * 16 + lr;
#pragma unroll
      for (int ks = 0; ks < 4; ++ks) {
        short8v kf = *(const short8v*)&Ks[cur][row * 128 + (((4 * ks + lq) ^ (row & 7)) * 8)];
        st[mf][0] = mfma16(kf, qf[0][ks], st[mf][0]);
        st[mf][1] = mfma16(kf, qf[1][ks], st[mf][1]);
      }
    }
    __builtin_amdgcn_s_setprio(0);
    float rs[2];
#pragma unroll
    for (int qn = 0; qn < 2; ++qn)
      rs[qn] = exp2f(l2g * (float)(q0 + w * 32 + qn * 16 + lr - m0 - 63));
#pragma unroll
    for (int mf = 0; mf < 4; ++mf)
#pragma unroll
      for (int qn = 0; qn < 2; ++qn)
#pragma unroll
        for (int r = 0; r < 4; ++r) {
          const int qg = q0 + w * 32 + qn * 16 + lr;
          const int kvg = m0 + mf * 16 + lq * 4 + r;
          const float wgt = (qg >= kvg) ? rs[qn] * cmf[mf] * csr[r] : 0.f;
          st[mf][qn][r] *= wgt;
        }
    unsigned pk[4][2][2];
#pragma unroll
    for (int mf = 0; mf < 4; ++mf)
#pragma unroll
      for (int qn = 0; qn < 2; ++qn)
#pragma unroll
        for (int p = 0; p < 2; ++p)
          pk[mf][qn][p] = (unsigned)f2bfu(st[mf][qn][2 * p]) |
                          ((unsigned)f2bfu(st[mf][qn][2 * p + 1]) << 16);
    short8v afr[2][2];
#pragma unroll
    for (int qn = 0; qn < 2; ++qn)
#pragma unroll
      for (int ks2 = 0; ks2 < 2; ++ks2) {
        u32x4 wd;
#pragma unroll
        for (int wj = 0; wj < 4; ++wj) {
          const int src = sb + (wj >> 1) * 16;
          const unsigned v0 = __shfl(pk[2 * ks2 + 0][qn][wj & 1], src);
          const unsigned v1 = __shfl(pk[2 * ks2 + 1][qn][wj & 1], src);
          wd[wj] = (lq >= 2) ? v1 : v0;
        }
        afr[qn][ks2] = __builtin_bit_cast(short8v, wd);
      }
    __builtin_amdgcn_s_setprio(1);
#pragma unroll
    for (int nd = 0; nd < 8; ++nd) {
      const int row = nd * 16 + lr;
#pragma unroll
      for (int ks2 = 0; ks2 < 2; ++ks2) {
        short8v vf = *(const short8v*)&Vs[cur][row * 64 + (((4 * ks2 + lq) ^ (row & 7)) * 8)];
        yacc[0][nd] = mfma16(afr[0][ks2], vf, yacc[0][nd]);
        yacc[1][nd] = mfma16(afr[1][ks2], vf, yacc[1][nd]);
      }
    }
    __builtin_amdgcn_s_setprio(0);
    __syncthreads();
    cur ^= 1;
  }
  float* Y = half ? Y1 : Y0;
#pragma unroll
  for (int qn = 0; qn < 2; ++qn)
#pragma unroll
    for (int r = 0; r < 4; ++r) {
      const int q = q0 + w * 32 + qn * 16 + lq * 4 + r;
#pragma unroll
      for (int nd = 0; nd < 8; ++nd)
        Y[(size_t)(b * Ss + q) * Dd + h * DHd + nd * 16 + lr] = yacc[qn][nd][r];
    }
}

// ---------------- gate: Gb = bf16( swish(Graw) * GN(Y0+Y1) ) ----------------
__global__ __launch_bounds__(256) void gate_kernel(const float* __restrict__ Y0,
                                                   const float* __restrict__ Y1,
                                                   const short* __restrict__ Graw,
                                                   short* __restrict__ Gb,
                                                   const float* __restrict__ gs,
                                                   const float* __restrict__ gb) {
  const int lane = threadIdx.x & 63;
  const int rowh = blockIdx.x * 4 + (threadIdx.x >> 6);  // (b*S+s)*H + h
  const int h = rowh & 7;
  const int row = rowh >> 3;
  const size_t ybase = (size_t)row * Dd + (size_t)h * DHd + lane * 2;
  float2 a = *(const float2*)(Y0 + ybase);
  const float2 c = *(const float2*)(Y1 + ybase);
  a.x += c.x; a.y += c.y;
  float s = a.x + a.y, s2 = a.x * a.x + a.y * a.y;
#pragma unroll
  for (int o = 32; o > 0; o >>= 1) { s += __shfl_down(s, o); s2 += __shfl_down(s2, o); }
  s = __shfl(s, 0);
  s2 = __shfl(s2, 0);
  const float mu = s * (1.f / DHd);
  const float rstd = rsqrtf(s2 * (1.f / DHd) - mu * mu + EPSf);
  const int d = h * DHd + lane * 2;
  const float2 g = *(const float2*)(gs + d);
  const float2 bbv = *(const float2*)(gb + d);
  const float y0 = (a.x - mu) * rstd * g.x + bbv.x;
  const float y1 = (a.y - mu) * rstd * g.y + bbv.y;
  const unsigned gr = *(const unsigned*)(Graw + (size_t)row * LDQ + 3072 + h * DHd + lane * 2);
  const float gx = bfu2f((unsigned short)(gr & 0xffff));
  const float gy = bfu2f((unsigned short)(gr >> 16));
  const unsigned o01 = (unsigned)f2bfu(swish_f(gx) * y0) |
                       ((unsigned)f2bfu(swish_f(gy) * y1) << 16);
  *(unsigned*)(Gb + ybase) = o01;
}

extern "C" void kernel_launch(void* const* d_in, const int* in_sizes, int n_in,
                              void* d_out, int out_size, void* d_ws, size_t ws_size,
                              hipStream_t stream) {
  const float* X = (const float*)d_in[0];
  const float* Wq = (const float*)d_in[1];
  const float* Wk = (const float*)d_in[2];
  const float* Wv = (const float*)d_in[3];
  const float* Wg = (const float*)d_in[4];
  const float* Wo = (const float*)d_in[5];
  const float* W1 = (const float*)d_in[6];
  const float* W2 = (const float*)d_in[7];
  const float* lns = (const float*)d_in[8];
  const float* lnb = (const float*)d_in[9];
  const float* gns = (const float*)d_in[10];
  const float* gnb = (const float*)d_in[11];
  float* out = (float*)d_out;

  char* W = (char*)d_ws;
  const size_t MB = 1u << 20;
  float* Abuf  = (float*)(W);             // 16 MB fp32
  short* Xnb   = (short*)(W + 16 * MB);   // 8 MB bf16
  short* QKVGb = (short*)(W + 24 * MB);   // 32 MB bf16 [4096][4096]; Hb aliases first 16 MB
  float* Y0    = (float*)(W + 56 * MB);   // 16 MB fp32
  float* Y1    = (float*)(W + 72 * MB);   // 16 MB fp32
  short* Vtb   = (short*)(W + 88 * MB);   // 8 MB bf16
  short* Gb    = (short*)(W + 96 * MB);   // 8 MB bf16
  short* Wqkvgt= (short*)(W + 104 * MB);  // 8 MB
  short* Wot   = (short*)(W + 112 * MB);  // 2 MB
  short* W1t   = (short*)(W + 114 * MB);  // 4 MB
  short* W2t   = (short*)(W + 118 * MB);  // 4 MB
  float* ct    = (float*)(W + 122 * MB);  // 256 KB
  float* st    = ct + Ss * 64;            // 256 KB
  short* Hb = QKVGb;  // FFN hidden 4096x2048 bf16 (16 MB)

  hipMemcpyAsync(Abuf, X, (size_t)Mm * Dd * sizeof(float), hipMemcpyDeviceToDevice, stream);
  rope_table_kernel<<<(Ss * 64) / 256, 256, 0, stream>>>(ct, st);

  for (int l = 0; l < LAYERS; ++l) {
    const size_t DD = (size_t)Dd * Dd;
    wtrans4_kernel<<<dim3(128, 32), 256, 0, stream>>>(Wq + l * DD, Wk + l * DD, Wv + l * DD,
                                                      Wg + l * DD, Wqkvgt);
    wtrans1_kernel<<<dim3(32, 32), 256, 0, stream>>>(Wo + l * DD, Wot, Dd, Dd);
    wtrans1_kernel<<<dim3(64, 32), 256, 0, stream>>>(W1 + (size_t)l * Dd * Ff, W1t, Dd, Ff);
    wtrans1_kernel<<<dim3(32, 64), 256, 0, stream>>>(W2 + (size_t)l * Ff * Dd, W2t, Ff, Dd);

    // Xn = LN(A) -> bf16
    ln_bf16_kernel<<<Mm, 256, 0, stream>>>(Abuf, Xnb, lns, lnb);
    // fused QKVG projection -> combined bf16 buffer (8-phase 256x256, 256 blocks = 1/CU)
    gemm10<0><<<dim3(16, 16), 512, 0, stream>>>(Xnb, Wqkvgt, nullptr, QKVGb,
                                                nullptr, 4096, Dd, LDQ);
    // RoPE in-place on Q,K slices
    rope_ip_kernel<<<(Bb * Ss * Hh * 64) / 256, 256, 0, stream>>>(QKVGb, ct, st);
    // V transpose
    vtrans16_kernel<<<dim3(Ss / 32, DHd / 32, Bb * Hh), 256, 0, stream>>>(QKVGb, Vtb);
    // retention -> partial Y0,Y1 (fp32)
    ret4_kernel<<<512, 256, 0, stream>>>(QKVGb, Vtb, Y0, Y1);
    // gate: Gb = swish(Graw) * GN(Y0+Y1)
    gate_kernel<<<(Mm * Hh) / 4, 256, 0, stream>>>(Y0, Y1, QKVGb, Gb,
                                                   gns + (size_t)l * Dd, gnb + (size_t)l * Dd);
    // A = (Gb @ Wo) + A : 128x64 tiles, 512 blocks
    gemm7<128, 64, 1><<<dim3(16, 32), 256, 0, stream>>>(Gb, Wot, Abuf, nullptr, Abuf,
                                                        Dd, Dd, Dd);
    // FFN
    ln_bf16_kernel<<<Mm, 256, 0, stream>>>(Abuf, Xnb, lns, lnb);
    // W1: 256x128 2-phase ring-3 (256 blocks = 1/CU), gelu -> Hb
    gemm11<2><<<256, 512, 0, stream>>>(Xnb, W1t, nullptr, Hb, nullptr,
                                       Dd, Dd, Dd, Ff, 16);
    float* dst = (l == LAYERS - 1) ? out : Abuf;
    // W2: 64x64 tiles -> 1024 blocks = 4/CU
    gemm7<64, 64, 1><<<dim3(16, 64), 256, 0, stream>>>(Hb, W2t, dst, nullptr, Abuf,
                                                       Dd, Ff, Dd);
  }
}

// Round 13
// 767.435 us; speedup vs baseline: 1.5063x; 1.0439x over previous
//
#include <hip/hip_runtime.h>
#include <hip/hip_bf16.h>
#include <cmath>

#define LAYERS 4
#define Bb 4
#define Ss 1024
#define Dd 1024
#define Ff 2048
#define Hh 8
#define DHd 128
#define Mm (Bb * Ss)   // 4096 rows
#define EPSf 1e-5f
#define LDQ 4096       // combined QKVG row stride

typedef __attribute__((ext_vector_type(8))) short short8v;
typedef __attribute__((ext_vector_type(4))) float f32x4;
typedef __attribute__((ext_vector_type(4))) unsigned int u32x4;

__device__ __forceinline__ float swish_f(float x) { return x / (1.f + expf(-x)); }
__device__ __forceinline__ float gelu_f(float x) {
  return 0.5f * x * (1.f + tanhf(0.7978845608028654f * (x + 0.044715f * x * x * x)));
}
__device__ __forceinline__ unsigned short f2bfu(float f) {
  __hip_bfloat16 h = __float2bfloat16(f);
  return __builtin_bit_cast(unsigned short, h);
}
__device__ __forceinline__ float bfu2f(unsigned short u) {
  unsigned v = ((unsigned)u) << 16;
  return __builtin_bit_cast(float, v);
}
__device__ __forceinline__ void gl_lds16(const void* g, void* l) {
  __builtin_amdgcn_global_load_lds((__attribute__((address_space(1))) void*)g,
                                   (__attribute__((address_space(3))) void*)l, 16, 0, 0);
}
__device__ __forceinline__ f32x4 mfma16(short8v a, short8v b, f32x4 c) {
  return __builtin_amdgcn_mfma_f32_16x16x32_bf16(a, b, c, 0, 0, 0);
}

// ---------------- LayerNorm fp32 -> bf16 ----------------
__global__ __launch_bounds__(256) void ln_bf16_kernel(const float* __restrict__ x,
                                                      short* __restrict__ outb,
                                                      const float* __restrict__ sc,
                                                      const float* __restrict__ bi) {
  const int row = blockIdx.x;
  const int t = threadIdx.x;
  const float4 v = *(const float4*)(x + (size_t)row * Dd + t * 4);
  float s = v.x + v.y + v.z + v.w;
  float s2 = v.x * v.x + v.y * v.y + v.z * v.z + v.w * v.w;
#pragma unroll
  for (int o = 32; o > 0; o >>= 1) { s += __shfl_down(s, o); s2 += __shfl_down(s2, o); }
  __shared__ float ps[4], ps2[4];
  if ((t & 63) == 0) { ps[t >> 6] = s; ps2[t >> 6] = s2; }
  __syncthreads();
  s = ps[0] + ps[1] + ps[2] + ps[3];
  s2 = ps2[0] + ps2[1] + ps2[2] + ps2[3];
  const float mu = s * (1.f / Dd);
  const float var = s2 * (1.f / Dd) - mu * mu;
  const float rstd = rsqrtf(var + EPSf);
  const float4 g = *(const float4*)(sc + t * 4);
  const float4 b = *(const float4*)(bi + t * 4);
  const float o0 = (v.x - mu) * rstd * g.x + b.x;
  const float o1 = (v.y - mu) * rstd * g.y + b.y;
  const float o2 = (v.z - mu) * rstd * g.z + b.z;
  const float o3 = (v.w - mu) * rstd * g.w + b.w;
  unsigned p0 = (unsigned)f2bfu(o0) | ((unsigned)f2bfu(o1) << 16);
  unsigned p1 = (unsigned)f2bfu(o2) | ((unsigned)f2bfu(o3) << 16);
  uint2 pk; pk.x = p0; pk.y = p1;
  *(uint2*)(outb + (size_t)row * Dd + t * 4) = pk;
}

// ---------------- RoPE tables ----------------
__global__ void rope_table_kernel(float* __restrict__ ct, float* __restrict__ st) {
  const int i = blockIdx.x * 256 + threadIdx.x;  // < Ss*64
  const int s = i >> 6, f = i & 63;
  const float inv = powf(10000.f, -(float)f / 64.f);
  const float a = (float)s * inv;
  ct[i] = cosf(a);
  st[i] = sinf(a);
}

// ---------------- RoPE in-place on combined bf16 QKVG buffer (Q:+sin, K:-sin) -------------
__global__ void rope_ip_kernel(short* __restrict__ QK, const float* __restrict__ ct,
                               const float* __restrict__ st) {
  const int idx = blockIdx.x * 256 + threadIdx.x;  // < B*S*H*64
  const int f = idx & 63;
  const int h = (idx >> 6) & 7;
  const int r = idx >> 9;            // b*S+s
  const int s = r & (Ss - 1);
  const float c = ct[(s << 6) + f], sn = st[(s << 6) + f];
  const size_t qo = (size_t)r * LDQ + h * DHd + 2 * f;
  const unsigned qp = *(const unsigned*)(QK + qo);
  const unsigned kp = *(const unsigned*)(QK + qo + 1024);
  const float qx = bfu2f((unsigned short)(qp & 0xffff)), qy = bfu2f((unsigned short)(qp >> 16));
  const float kx = bfu2f((unsigned short)(kp & 0xffff)), ky = bfu2f((unsigned short)(kp >> 16));
  const unsigned qn = (unsigned)f2bfu(qx * c - qy * sn) | ((unsigned)f2bfu(qx * sn + qy * c) << 16);
  const unsigned kn = (unsigned)f2bfu(kx * c + ky * sn) | ((unsigned)f2bfu(-kx * sn + ky * c) << 16);
  *(unsigned*)(QK + qo) = qn;
  *(unsigned*)(QK + qo + 1024) = kn;
}

// ---------------- transpose-convert QKVG concat: 4x W[K][1024] fp32 -> Wt[4096][K] bf16 ----
__global__ __launch_bounds__(256) void wtrans4_kernel(const float* __restrict__ W0,
                                                      const float* __restrict__ W1,
                                                      const float* __restrict__ W2,
                                                      const float* __restrict__ W3,
                                                      short* __restrict__ Wt) {
  __shared__ float tile[32][33];
  const int t = threadIdx.x;
  const int n0 = blockIdx.x * 32, k0 = blockIdx.y * 32;
  const int which = n0 >> 10;
  const float* W = (which == 0) ? W0 : (which == 1) ? W1 : (which == 2) ? W2 : W3;
  const int nl = n0 & 1023;
  const int tc = t & 31, tr8 = t >> 5;
#pragma unroll
  for (int i = 0; i < 4; ++i) {
    const int r = tr8 + i * 8;
    tile[r][tc] = W[(size_t)(k0 + r) * 1024 + nl + tc];
  }
  __syncthreads();
#pragma unroll
  for (int i = 0; i < 4; ++i) {
    const int r = tr8 + i * 8;
    Wt[(size_t)(n0 + r) * 1024 + k0 + tc] = (short)f2bfu(tile[tc][r]);
  }
}

// ---------------- transpose-convert single: W[K][N] fp32 -> Wt[N][K] bf16 ----------------
__global__ __launch_bounds__(256) void wtrans1_kernel(const float* __restrict__ W,
                                                      short* __restrict__ Wt, int K, int N) {
  __shared__ float tile[32][33];
  const int t = threadIdx.x;
  const int n0 = blockIdx.x * 32, k0 = blockIdx.y * 32;
  const int tc = t & 31, tr8 = t >> 5;
#pragma unroll
  for (int i = 0; i < 4; ++i) {
    const int r = tr8 + i * 8;
    tile[r][tc] = W[(size_t)(k0 + r) * N + n0 + tc];
  }
  __syncthreads();
#pragma unroll
  for (int i = 0; i < 4; ++i) {
    const int r = tr8 + i * 8;
    Wt[(size_t)(n0 + r) * K + k0 + tc] = (short)f2bfu(tile[tc][r]);
  }
}

// ---------------- V transpose bf16: combined buf col-slice -> Vt [(bh*128+d)][S] ----------
__global__ __launch_bounds__(256) void vtrans16_kernel(const short* __restrict__ Vb,
                                                       short* __restrict__ Vt) {
  __shared__ short tile[32][33];
  const int t = threadIdx.x;
  const int s0 = blockIdx.x * 32, d0 = blockIdx.y * 32, bh = blockIdx.z;
  const int bb = bh >> 3, h = bh & 7;
  const int tc = t & 31, tr8 = t >> 5;
#pragma unroll
  for (int i = 0; i < 4; ++i) {
    const int r = tr8 + i * 8;
    tile[r][tc] = Vb[(size_t)(bb * Ss + s0 + r) * LDQ + 2048 + h * DHd + d0 + tc];
  }
  __syncthreads();
#pragma unroll
  for (int i = 0; i < 4; ++i) {
    const int r = tr8 + i * 8;
    Vt[(size_t)(bh * DHd + d0 + r) * Ss + s0 + tc] = tile[tc][r];
  }
}

// ---------------- bf16 MFMA GEMM v10: 256x256 8-phase schedule, counted vmcnt -------------
template <int EPI>
__global__ __launch_bounds__(512, 2) void gemm10(const short* __restrict__ A,
                                                 const short* __restrict__ Bt,
                                                 float* __restrict__ Cf,
                                                 short* __restrict__ Cb,
                                                 const float* __restrict__ Res,
                                                 int N, int K, int ldc) {
  __shared__ __align__(16) short As[2][2][128 * 64];  // [dbuf][half] 64 KB
  __shared__ __align__(16) short Bs[2][2][128 * 64];  // 64 KB
  const int t = threadIdx.x;
  const int w = t >> 6, l = t & 63;
  const int lq = l >> 4, lr = l & 15;
  const int wr = w >> 2, wc = w & 3;
  const int bhalf = wc >> 1, brow0 = (wc & 1) * 64;
  const int nwg = gridDim.x * gridDim.y;
  const int bid0 = blockIdx.x + blockIdx.y * gridDim.x;
  const int lgid = (bid0 & 7) * (nwg >> 3) + (bid0 >> 3);
  const int bx = lgid % gridDim.x, by = lgid / gridDim.x;
  const int row0 = by * 256, col0 = bx * 256;
  const int NT = K >> 6;

  f32x4 acc[8][4] = {};
  short8v a[4][2], b[4][2];

  auto stageA = [&](int kt, int hf) {
    const int db = kt & 1;
#pragma unroll
    for (int i = 0; i < 2; ++i) {
      const int c = t + i * 512;
      const int row = c >> 3, slot = c & 7;
      gl_lds16(A + (size_t)(row0 + hf * 128 + row) * K + kt * 64 + ((slot ^ (row & 7)) << 3),
               &As[db][hf][c * 8]);
    }
  };
  auto stageB = [&](int kt, int hf) {
    const int db = kt & 1;
#pragma unroll
    for (int i = 0; i < 2; ++i) {
      const int c = t + i * 512;
      const int row = c >> 3, slot = c & 7;
      gl_lds16(Bt + (size_t)(col0 + hf * 128 + row) * K + kt * 64 + ((slot ^ (row & 7)) << 3),
               &Bs[db][hf][c * 8]);
    }
  };
  auto rdA = [&](int db, int m, int ks) -> short8v {
    const int row = m * 16 + lr;
    return *(const short8v*)&As[db][wr][row * 64 + (((ks << 2) + lq) ^ (row & 7)) * 8];
  };
  auto rdB = [&](int db, int n, int ks) -> short8v {
    const int row = brow0 + n * 16 + lr;
    return *(const short8v*)&Bs[db][bhalf][row * 64 + (((ks << 2) + lq) ^ (row & 7)) * 8];
  };

  stageA(0, 0); stageA(0, 1); stageB(0, 0); stageB(0, 1);
  if (NT > 1) { stageB(1, 0); stageB(1, 1); }
  if (NT > 1) { asm volatile("s_waitcnt vmcnt(4)" ::: "memory"); }
  else        { asm volatile("s_waitcnt vmcnt(0)" ::: "memory"); }
  asm volatile("s_barrier" ::: "memory");

  for (int kt = 0; kt < NT; ++kt) {
    const int db = kt & 1;
#pragma unroll
    for (int m = 0; m < 4; ++m) { a[m][0] = rdA(db, m, 0); a[m][1] = rdA(db, m, 1); }
#pragma unroll
    for (int n = 0; n < 2; ++n) { b[n][0] = rdB(db, n, 0); b[n][1] = rdB(db, n, 1); }
    if (kt + 1 < NT) stageA(kt + 1, 0);
    __builtin_amdgcn_s_setprio(1);
#pragma unroll
    for (int m = 0; m < 4; ++m)
#pragma unroll
      for (int n = 0; n < 2; ++n) {
        acc[m][n] = mfma16(a[m][0], b[n][0], acc[m][n]);
        acc[m][n] = mfma16(a[m][1], b[n][1], acc[m][n]);
      }
    __builtin_amdgcn_s_setprio(0);
    asm volatile("s_barrier" ::: "memory");
#pragma unroll
    for (int n = 2; n < 4; ++n) { b[n][0] = rdB(db, n, 0); b[n][1] = rdB(db, n, 1); }
    if (kt + 1 < NT) stageA(kt + 1, 1);
    __builtin_amdgcn_s_setprio(1);
#pragma unroll
    for (int m = 0; m < 4; ++m)
#pragma unroll
      for (int n = 2; n < 4; ++n) {
        acc[m][n] = mfma16(a[m][0], b[n][0], acc[m][n]);
        acc[m][n] = mfma16(a[m][1], b[n][1], acc[m][n]);
      }
    __builtin_amdgcn_s_setprio(0);
    asm volatile("s_barrier" ::: "memory");
#pragma unroll
    for (int m = 0; m < 4; ++m) { a[m][0] = rdA(db, m + 4, 0); a[m][1] = rdA(db, m + 4, 1); }
    if (kt + 2 < NT) stageB(kt + 2, 0);
    __builtin_amdgcn_s_setprio(1);
#pragma unroll
    for (int m = 0; m < 4; ++m)
#pragma unroll
      for (int n = 0; n < 2; ++n) {
        acc[m + 4][n] = mfma16(a[m][0], b[n][0], acc[m + 4][n]);
        acc[m + 4][n] = mfma16(a[m][1], b[n][1], acc[m + 4][n]);
      }
    __builtin_amdgcn_s_setprio(0);
    asm volatile("s_barrier" ::: "memory");
    if (kt + 2 < NT) stageB(kt + 2, 1);
    __builtin_amdgcn_s_setprio(1);
#pragma unroll
    for (int m = 0; m < 4; ++m)
#pragma unroll
      for (int n = 2; n < 4; ++n) {
        acc[m + 4][n] = mfma16(a[m][0], b[n][0], acc[m + 4][n]);
        acc[m + 4][n] = mfma16(a[m][1], b[n][1], acc[m + 4][n]);
      }
    __builtin_amdgcn_s_setprio(0);
    if (kt + 2 < NT) { asm volatile("s_waitcnt vmcnt(4)" ::: "memory"); }
    else             { asm volatile("s_waitcnt vmcnt(0)" ::: "memory"); }
    asm volatile("s_barrier" ::: "memory");
  }

#pragma unroll
  for (int m = 0; m < 8; ++m) {
#pragma unroll
    for (int n = 0; n < 4; ++n) {
#pragma unroll
      for (int r = 0; r < 4; ++r) {
        const int row = row0 + wr * 128 + m * 16 + lq * 4 + r;
        const int col = col0 + wc * 64 + n * 16 + lr;
        const size_t o = (size_t)row * ldc + col;
        float v = acc[m][n][r];
        if (EPI == 0) Cb[o] = (short)f2bfu(v);
        else if (EPI == 1) Cf[o] = v + Res[o];
        else Cb[o] = (short)f2bfu(gelu_f(v));
      }
    }
  }
}

// ---------------- bf16 MFMA GEMM v11: 256x128 2-phase/K-tile, ring-3 LDS, vmcnt(6) --------
template <int EPI>
__global__ __launch_bounds__(512) void gemm11(const short* __restrict__ A,
                                              const short* __restrict__ Bt,
                                              float* __restrict__ Cf,
                                              short* __restrict__ Cb,
                                              const float* __restrict__ Res,
                                              int K, int lda, int ldb, int ldc, int nxt) {
  __shared__ __align__(16) short As[3][256 * 64];  // 96 KB ring-3
  __shared__ __align__(16) short Bs[3][128 * 64];  // 48 KB ring-3
  const int t = threadIdx.x;
  const int w = t >> 6, l = t & 63;
  const int lq = l >> 4, lr = l & 15;
  const int wr = w >> 2, wc = w & 3;
  const int nwg = gridDim.x;
  const int lgid = (blockIdx.x & 7) * (nwg >> 3) + (blockIdx.x >> 3);
  const int mt = lgid / nxt, nt_ = lgid % nxt;
  const int row0 = mt * 256, col0 = nt_ * 128;
  const int NT = K >> 6;
  f32x4 acc[8][2] = {};
  short8v a[4][2], b[2][2];

  auto stageA = [&](int kt, int hf) {
    const int s = kt % 3;
#pragma unroll
    for (int i = 0; i < 2; ++i) {
      const int c = t + i * 512;
      const int row = c >> 3, slot = c & 7;
      gl_lds16(A + (size_t)(row0 + hf * 128 + row) * lda + kt * 64 + ((slot ^ (row & 7)) << 3),
               &As[s][hf * 8192 + c * 8]);
    }
  };
  auto stageB = [&](int kt) {
    const int s = kt % 3;
#pragma unroll
    for (int i = 0; i < 2; ++i) {
      const int c = t + i * 512;
      const int row = c >> 3, slot = c & 7;
      gl_lds16(Bt + (size_t)(col0 + row) * ldb + kt * 64 + ((slot ^ (row & 7)) << 3),
               &Bs[s][c * 8]);
    }
  };
  auto rdA = [&](int s, int m, int ks) -> short8v {
    const int row = wr * 128 + m * 16 + lr;
    return *(const short8v*)&As[s][row * 64 + (((ks << 2) + lq) ^ (row & 7)) * 8];
  };
  auto rdB = [&](int s, int n, int ks) -> short8v {
    const int row = wc * 32 + n * 16 + lr;
    return *(const short8v*)&Bs[s][row * 64 + (((ks << 2) + lq) ^ (row & 7)) * 8];
  };

  stageA(0, 0); stageA(0, 1); stageB(0);
  stageA(1, 0); stageA(1, 1); stageB(1);
  asm volatile("s_waitcnt vmcnt(6)" ::: "memory");
  asm volatile("s_barrier" ::: "memory");

  for (int kt = 0; kt < NT; ++kt) {
    const int s = kt % 3;
#pragma unroll
    for (int m = 0; m < 4; ++m) { a[m][0] = rdA(s, m, 0); a[m][1] = rdA(s, m, 1); }
#pragma unroll
    for (int n = 0; n < 2; ++n) { b[n][0] = rdB(s, n, 0); b[n][1] = rdB(s, n, 1); }
    if (kt + 2 < NT) stageA(kt + 2, 0);
    __builtin_amdgcn_s_setprio(1);
#pragma unroll
    for (int m = 0; m < 4; ++m)
#pragma unroll
      for (int n = 0; n < 2; ++n) {
        acc[m][n] = mfma16(a[m][0], b[n][0], acc[m][n]);
        acc[m][n] = mfma16(a[m][1], b[n][1], acc[m][n]);
      }
    __builtin_amdgcn_s_setprio(0);
    asm volatile("s_barrier" ::: "memory");
#pragma unroll
    for (int m = 0; m < 4; ++m) { a[m][0] = rdA(s, m + 4, 0); a[m][1] = rdA(s, m + 4, 1); }
    if (kt + 2 < NT) { stageA(kt + 2, 1); stageB(kt + 2); }
    __builtin_amdgcn_s_setprio(1);
#pragma unroll
    for (int m = 0; m < 4; ++m)
#pragma unroll
      for (int n = 0; n < 2; ++n) {
        acc[m + 4][n] = mfma16(a[m][0], b[n][0], acc[m + 4][n]);
        acc[m + 4][n] = mfma16(a[m][1], b[n][1], acc[m + 4][n]);
      }
    __builtin_amdgcn_s_setprio(0);
    if (kt + 2 < NT) { asm volatile("s_waitcnt vmcnt(6)" ::: "memory"); }
    else             { asm volatile("s_waitcnt vmcnt(0)" ::: "memory"); }
    asm volatile("s_barrier" ::: "memory");
  }

#pragma unroll
  for (int m = 0; m < 8; ++m) {
#pragma unroll
    for (int n = 0; n < 2; ++n) {
#pragma unroll
      for (int r = 0; r < 4; ++r) {
        const int row = row0 + wr * 128 + m * 16 + lq * 4 + r;
        const int col = col0 + wc * 32 + n * 16 + lr;
        const size_t o = (size_t)row * ldc + col;
        float v = acc[m][n][r];
        if (EPI == 0) Cb[o] = (short)f2bfu(v);
        else if (EPI == 1) Cf[o] = v + Res[o];
        else Cb[o] = (short)f2bfu(gelu_f(v));
      }
    }
  }
}

// ---------------- bf16 MFMA GEMM v12: 128x128 2-phase/K-tile, ring-3 LDS, vmcnt(4) --------
// 512 threads = 8 waves (2M x 4N), wave tile 64x32 (acc 4x2). BK=64. 1D grid, nxt N-tiles.
// LDS 96 KB -> 1 block/CU; for N=1024 GEMMs (Wo, W2): grid 32x8 = 256 blocks = 1/CU.
template <int EPI>
__global__ __launch_bounds__(512) void gemm12(const short* __restrict__ A,
                                              const short* __restrict__ Bt,
                                              float* __restrict__ Cf,
                                              short* __restrict__ Cb,
                                              const float* __restrict__ Res,
                                              int K, int lda, int ldb, int ldc, int nxt) {
  __shared__ __align__(16) short As[3][128 * 64];  // 48 KB ring-3
  __shared__ __align__(16) short Bs[3][128 * 64];  // 48 KB ring-3
  const int t = threadIdx.x;
  const int w = t >> 6, l = t & 63;
  const int lq = l >> 4, lr = l & 15;
  const int wr = w >> 2, wc = w & 3;
  const int nwg = gridDim.x;
  const int lgid = (blockIdx.x & 7) * (nwg >> 3) + (blockIdx.x >> 3);
  const int mt = lgid / nxt, nt_ = lgid % nxt;
  const int row0 = mt * 128, col0 = nt_ * 128;
  const int NT = K >> 6;
  f32x4 acc[4][2] = {};
  short8v a[4][2], b[2][2];

  auto stageA = [&](int kt) {
    const int s = kt % 3;
#pragma unroll
    for (int i = 0; i < 2; ++i) {
      const int c = t + i * 512;
      const int row = c >> 3, slot = c & 7;
      gl_lds16(A + (size_t)(row0 + row) * lda + kt * 64 + ((slot ^ (row & 7)) << 3),
               &As[s][c * 8]);
    }
  };
  auto stageB = [&](int kt) {
    const int s = kt % 3;
#pragma unroll
    for (int i = 0; i < 2; ++i) {
      const int c = t + i * 512;
      const int row = c >> 3, slot = c & 7;
      gl_lds16(Bt + (size_t)(col0 + row) * ldb + kt * 64 + ((slot ^ (row & 7)) << 3),
               &Bs[s][c * 8]);
    }
  };
  auto rdA = [&](int s, int m, int ks) -> short8v {
    const int row = wr * 64 + m * 16 + lr;
    return *(const short8v*)&As[s][row * 64 + (((ks << 2) + lq) ^ (row & 7)) * 8];
  };
  auto rdB = [&](int s, int n, int ks) -> short8v {
    const int row = wc * 32 + n * 16 + lr;
    return *(const short8v*)&Bs[s][row * 64 + (((ks << 2) + lq) ^ (row & 7)) * 8];
  };

  // prologue: tiles 0 and 1 staged (8 loads/thread); wait tile 0 (tile 1's 4 keep flying)
  stageA(0); stageB(0);
  stageA(1); stageB(1);
  asm volatile("s_waitcnt vmcnt(4)" ::: "memory");
  asm volatile("s_barrier" ::: "memory");

  for (int kt = 0; kt < NT; ++kt) {
    const int s = kt % 3;
    // ph1: read all frags; stage A(kt+2); MFMA m0-1 (8)
#pragma unroll
    for (int m = 0; m < 4; ++m) { a[m][0] = rdA(s, m, 0); a[m][1] = rdA(s, m, 1); }
#pragma unroll
    for (int n = 0; n < 2; ++n) { b[n][0] = rdB(s, n, 0); b[n][1] = rdB(s, n, 1); }
    if (kt + 2 < NT) stageA(kt + 2);
    __builtin_amdgcn_s_setprio(1);
#pragma unroll
    for (int m = 0; m < 2; ++m)
#pragma unroll
      for (int n = 0; n < 2; ++n) {
        acc[m][n] = mfma16(a[m][0], b[n][0], acc[m][n]);
        acc[m][n] = mfma16(a[m][1], b[n][1], acc[m][n]);
      }
    __builtin_amdgcn_s_setprio(0);
    asm volatile("s_barrier" ::: "memory");
    // ph2: stage B(kt+2); MFMA m2-3 (8); vmcnt(4); barrier
    if (kt + 2 < NT) stageB(kt + 2);
    __builtin_amdgcn_s_setprio(1);
#pragma unroll
    for (int m = 2; m < 4; ++m)
#pragma unroll
      for (int n = 0; n < 2; ++n) {
        acc[m][n] = mfma16(a[m][0], b[n][0], acc[m][n]);
        acc[m][n] = mfma16(a[m][1], b[n][1], acc[m][n]);
      }
    __builtin_amdgcn_s_setprio(0);
    if (kt + 2 < NT) { asm volatile("s_waitcnt vmcnt(4)" ::: "memory"); }
    else             { asm volatile("s_waitcnt vmcnt(0)" ::: "memory"); }
    asm volatile("s_barrier" ::: "memory");
  }

#pragma unroll
  for (int m = 0; m < 4; ++m) {
#pragma unroll
    for (int n = 0; n < 2; ++n) {
#pragma unroll
      for (int r = 0; r < 4; ++r) {
        const int row = row0 + wr * 64 + m * 16 + lq * 4 + r;
        const int col = col0 + wc * 32 + n * 16 + lr;
        const size_t o = (size_t)row * ldc + col;
        float v = acc[m][n][r];
        if (EPI == 0) Cb[o] = (short)f2bfu(v);
        else if (EPI == 1) Cf[o] = v + Res[o];
        else Cb[o] = (short)f2bfu(gelu_f(v));
      }
    }
  }
}

// ---------------- Retention v4: dbuf K/V, 1 barrier/tile, setprio, XCD-local bh ----------
__global__ __launch_bounds__(256) void ret4_kernel(const short* __restrict__ QKb,
                                                   const short* __restrict__ Vt,
                                                   float* __restrict__ Y0,
                                                   float* __restrict__ Y1) {
  __shared__ __align__(16) short Ks[2][64 * 128];
  __shared__ __align__(16) short Vs[2][128 * 64];
  const int t = threadIdx.x, w = t >> 6, l = t & 63;
  const int lq = l >> 4, lr = l & 15;
  const int u = blockIdx.x;                 // 0..511
  const int lgid = (u & 7) * 64 + (u >> 3);
  const int half = lgid >> 8;
  const int rest = lgid & 255;
  const int bh = rest >> 3, j = rest & 7;
  const int qb = half ? j : 7 - j;
  const int b = bh >> 3, h = bh & 7;
  const int q0 = qb * 128;
  const float lstep = (logf(1.f / 512.f) - logf(1.f / 32.f)) * (1.f / 7.f);
  const float gamma = 1.f - expf(logf(1.f / 32.f) + (float)h * lstep);
  const float l2g = logf(gamma) * 1.44269504f;
  const short* Qp = QKb;
  const short* Kp = QKb + 1024;

  short8v qf[2][4];
#pragma unroll
  for (int qn = 0; qn < 2; ++qn)
#pragma unroll
    for (int ks = 0; ks < 4; ++ks)
      qf[qn][ks] = *(const short8v*)(Qp + (size_t)(b * Ss + q0 + w * 32 + qn * 16 + lr) * LDQ +
                                     h * DHd + ks * 32 + lq * 8);

  float cmf[4], csr[4];
#pragma unroll
  for (int mf = 0; mf < 4; ++mf) cmf[mf] = exp2f(l2g * (float)(-16 * mf));
#pragma unroll
  for (int r = 0; r < 4; ++r) csr[r] = exp2f(l2g * (float)(63 - 4 * lq - r));

  f32x4 yacc[2][8] = {};
  const int nt = 2 * qb + 2;
  const int sb = ((lq & 1) * 2) * 16 + lr;

  auto stageKV = [&](int m0, int buf) {
#pragma unroll
    for (int i = 0; i < 4; ++i) {
      const int c = (w * 4 + i) * 64 + l;
      const int row = c >> 4, slot = c & 15;
      gl_lds16(Kp + (size_t)(b * Ss + m0 + row) * LDQ + h * DHd + ((slot ^ (row & 7)) * 8),
               &Ks[buf][(w * 4 + i) * 512]);
    }
#pragma unroll
    for (int i = 0; i < 4; ++i) {
      const int c = (w * 4 + i) * 64 + l;
      const int row = c >> 3, slot = c & 7;
      gl_lds16(Vt + (size_t)(bh * DHd + row) * Ss + m0 + ((slot ^ (row & 7)) * 8),
               &Vs[buf][(w * 4 + i) * 512]);
    }
  };

  stageKV(half * 64, 0);
  __syncthreads();
  int cur = 0;
  for (int tt = half; tt < nt; tt += 2) {
    const int m0 = tt * 64;
    if (tt + 2 < nt) stageKV((tt + 2) * 64, cur ^ 1);

    f32x4 st[4][2] = {};
    __builtin_amdgcn_s_setprio(1);
#pragma unroll
    for (int mf = 0; mf < 4; ++mf) {
      const int row = mf * 16 + lr;
#pragma unroll
      for (int ks = 0; ks < 4; ++ks) {
        short8v kf = *(const short8v*)&Ks[cur][row * 128 + (((4 * ks + lq) ^ (row & 7)) * 8)];
        st[mf][0] = mfma16(kf, qf[0][ks], st[mf][0]);
        st[mf][1] = mfma16(kf, qf[1][ks], st[mf][1]);
      }
    }
    __builtin_amdgcn_s_setprio(0);
    float rs[2];
#pragma unroll
    for (int qn = 0; qn < 2; ++qn)
      rs[qn] = exp2f(l2g * (float)(q0 + w * 32 + qn * 16 + lr - m0 - 63));
#pragma unroll
    for (int mf = 0; mf < 4; ++mf)
#pragma unroll
      for (int qn = 0; qn < 2; ++qn)
#pragma unroll
        for (int r = 0; r < 4; ++r) {
          const int qg = q0 + w * 32 + qn * 16 + lr;
          const int kvg = m0 + mf * 16 + lq * 4 + r;
          const float wgt = (qg >= kvg) ? rs[qn] * cmf[mf] * csr[r] : 0.f;
          st[mf][qn][r] *= wgt;
        }
    unsigned pk[4][2][2];
#pragma unroll
    for (int mf = 0; mf < 4; ++mf)
#pragma unroll
      for (int qn = 0; qn < 2; ++qn)
#pragma unroll
        for (int p = 0; p < 2; ++p)
          pk[mf][qn][p] = (unsigned)f2bfu(st[mf][qn][2 * p]) |
                          ((unsigned)f2bfu(st[mf][qn][2 * p + 1]) << 16);
    short8v afr[2][2];
#pragma unroll
    for (int qn = 0; qn < 2; ++qn)
#pragma unroll
      for (int ks2 = 0; ks2 < 2; ++ks2) {
        u32x4 wd;
#pragma unroll
        for (int wj = 0; wj < 4; ++wj) {
          const int src = sb + (wj >> 1) * 16;
          const unsigned v0 = __shfl(pk[2 * ks2 + 0][qn][wj & 1], src);
          const unsigned v1 = __shfl(pk[2 * ks2 + 1][qn][wj & 1], src);
          wd[wj] = (lq >= 2) ? v1 : v0;
        }
        afr[qn][ks2] = __builtin_bit_cast(short8v, wd);
      }
    __builtin_amdgcn_s_setprio(1);
#pragma unroll
    for (int nd = 0; nd < 8; ++nd) {
      const int row = nd * 16 + lr;
#pragma unroll
      for (int ks2 = 0; ks2 < 2; ++ks2) {
        short8v vf = *(const short8v*)&Vs[cur][row * 64 + (((4 * ks2 + lq) ^ (row & 7)) * 8)];
        yacc[0][nd] = mfma16(afr[0][ks2], vf, yacc[0][nd]);
        yacc[1][nd] = mfma16(afr[1][ks2], vf, yacc[1][nd]);
      }
    }
    __builtin_amdgcn_s_setprio(0);
    __syncthreads();
    cur ^= 1;
  }
  float* Y = half ? Y1 : Y0;
#pragma unroll
  for (int qn = 0; qn < 2; ++qn)
#pragma unroll
    for (int r = 0; r < 4; ++r) {
      const int q = q0 + w * 32 + qn * 16 + lq * 4 + r;
#pragma unroll
      for (int nd = 0; nd < 8; ++nd)
        Y[(size_t)(b * Ss + q) * Dd + h * DHd + nd * 16 + lr] = yacc[qn][nd][r];
    }
}

// ---------------- gate: Gb = bf16( swish(Graw) * GN(Y0+Y1) ) ----------------
__global__ __launch_bounds__(256) void gate_kernel(const float* __restrict__ Y0,
                                                   const float* __restrict__ Y1,
                                                   const short* __restrict__ Graw,
                                                   short* __restrict__ Gb,
                                                   const float* __restrict__ gs,
                                                   const float* __restrict__ gb) {
  const int lane = threadIdx.x & 63;
  const int rowh = blockIdx.x * 4 + (threadIdx.x >> 6);  // (b*S+s)*H + h
  const int h = rowh & 7;
  const int row = rowh >> 3;
  const size_t ybase = (size_t)row * Dd + (size_t)h * DHd + lane * 2;
  float2 a = *(const float2*)(Y0 + ybase);
  const float2 c = *(const float2*)(Y1 + ybase);
  a.x += c.x; a.y += c.y;
  float s = a.x + a.y, s2 = a.x * a.x + a.y * a.y;
#pragma unroll
  for (int o = 32; o > 0; o >>= 1) { s += __shfl_down(s, o); s2 += __shfl_down(s2, o); }
  s = __shfl(s, 0);
  s2 = __shfl(s2, 0);
  const float mu = s * (1.f / DHd);
  const float rstd = rsqrtf(s2 * (1.f / DHd) - mu * mu + EPSf);
  const int d = h * DHd + lane * 2;
  const float2 g = *(const float2*)(gs + d);
  const float2 bbv = *(const float2*)(gb + d);
  const float y0 = (a.x - mu) * rstd * g.x + bbv.x;
  const float y1 = (a.y - mu) * rstd * g.y + bbv.y;
  const unsigned gr = *(const unsigned*)(Graw + (size_t)row * LDQ + 3072 + h * DHd + lane * 2);
  const float gx = bfu2f((unsigned short)(gr & 0xffff));
  const float gy = bfu2f((unsigned short)(gr >> 16));
  const unsigned o01 = (unsigned)f2bfu(swish_f(gx) * y0) |
                       ((unsigned)f2bfu(swish_f(gy) * y1) << 16);
  *(unsigned*)(Gb + ybase) = o01;
}

extern "C" void kernel_launch(void* const* d_in, const int* in_sizes, int n_in,
                              void* d_out, int out_size, void* d_ws, size_t ws_size,
                              hipStream_t stream) {
  const float* X = (const float*)d_in[0];
  const float* Wq = (const float*)d_in[1];
  const float* Wk = (const float*)d_in[2];
  const float* Wv = (const float*)d_in[3];
  const float* Wg = (const float*)d_in[4];
  const float* Wo = (const float*)d_in[5];
  const float* W1 = (const float*)d_in[6];
  const float* W2 = (const float*)d_in[7];
  const float* lns = (const float*)d_in[8];
  const float* lnb = (const float*)d_in[9];
  const float* gns = (const float*)d_in[10];
  const float* gnb = (const float*)d_in[11];
  float* out = (float*)d_out;

  char* W = (char*)d_ws;
  const size_t MB = 1u << 20;
  float* Abuf  = (float*)(W);             // 16 MB fp32
  short* Xnb   = (short*)(W + 16 * MB);   // 8 MB bf16
  short* QKVGb = (short*)(W + 24 * MB);   // 32 MB bf16 [4096][4096]; Hb aliases first 16 MB
  float* Y0    = (float*)(W + 56 * MB);   // 16 MB fp32
  float* Y1    = (float*)(W + 72 * MB);   // 16 MB fp32
  short* Vtb   = (short*)(W + 88 * MB);   // 8 MB bf16
  short* Gb    = (short*)(W + 96 * MB);   // 8 MB bf16
  short* Wqkvgt= (short*)(W + 104 * MB);  // 8 MB
  short* Wot   = (short*)(W + 112 * MB);  // 2 MB
  short* W1t   = (short*)(W + 114 * MB);  // 4 MB
  short* W2t   = (short*)(W + 118 * MB);  // 4 MB
  float* ct    = (float*)(W + 122 * MB);  // 256 KB
  float* st    = ct + Ss * 64;            // 256 KB
  short* Hb = QKVGb;  // FFN hidden 4096x2048 bf16 (16 MB)

  hipMemcpyAsync(Abuf, X, (size_t)Mm * Dd * sizeof(float), hipMemcpyDeviceToDevice, stream);
  rope_table_kernel<<<(Ss * 64) / 256, 256, 0, stream>>>(ct, st);

  for (int l = 0; l < LAYERS; ++l) {
    const size_t DD = (size_t)Dd * Dd;
    wtrans4_kernel<<<dim3(128, 32), 256, 0, stream>>>(Wq + l * DD, Wk + l * DD, Wv + l * DD,
                                                      Wg + l * DD, Wqkvgt);
    wtrans1_kernel<<<dim3(32, 32), 256, 0, stream>>>(Wo + l * DD, Wot, Dd, Dd);
    wtrans1_kernel<<<dim3(64, 32), 256, 0, stream>>>(W1 + (size_t)l * Dd * Ff, W1t, Dd, Ff);
    wtrans1_kernel<<<dim3(32, 64), 256, 0, stream>>>(W2 + (size_t)l * Ff * Dd, W2t, Ff, Dd);

    // Xn = LN(A) -> bf16
    ln_bf16_kernel<<<Mm, 256, 0, stream>>>(Abuf, Xnb, lns, lnb);
    // fused QKVG projection -> combined bf16 buffer (8-phase 256x256, 256 blocks = 1/CU)
    gemm10<0><<<dim3(16, 16), 512, 0, stream>>>(Xnb, Wqkvgt, nullptr, QKVGb,
                                                nullptr, 4096, Dd, LDQ);
    // RoPE in-place on Q,K slices
    rope_ip_kernel<<<(Bb * Ss * Hh * 64) / 256, 256, 0, stream>>>(QKVGb, ct, st);
    // V transpose
    vtrans16_kernel<<<dim3(Ss / 32, DHd / 32, Bb * Hh), 256, 0, stream>>>(QKVGb, Vtb);
    // retention -> partial Y0,Y1 (fp32)
    ret4_kernel<<<512, 256, 0, stream>>>(QKVGb, Vtb, Y0, Y1);
    // gate: Gb = swish(Graw) * GN(Y0+Y1)
    gate_kernel<<<(Mm * Hh) / 4, 256, 0, stream>>>(Y0, Y1, QKVGb, Gb,
                                                   gns + (size_t)l * Dd, gnb + (size_t)l * Dd);
    // A = (Gb @ Wo) + A : 128x128 ring-3 2-phase (256 blocks = 1/CU)
    gemm12<1><<<256, 512, 0, stream>>>(Gb, Wot, Abuf, nullptr, Abuf,
                                       Dd, Dd, Dd, Dd, 8);
    // FFN
    ln_bf16_kernel<<<Mm, 256, 0, stream>>>(Abuf, Xnb, lns, lnb);
    // W1: 256x128 2-phase ring-3 (256 blocks = 1/CU), gelu -> Hb
    gemm11<2><<<256, 512, 0, stream>>>(Xnb, W1t, nullptr, Hb, nullptr,
                                       Dd, Dd, Dd, Ff, 16);
    float* dst = (l == LAYERS - 1) ? out : Abuf;
    // W2: 128x128 ring-3 2-phase (256 blocks = 1/CU), K=2048
    gemm12<1><<<256, 512, 0, stream>>>(Hb, W2t, dst, nullptr, Abuf,
                                       Ff, Ff, Ff, Dd, 8);
  }
}

// Round 14
// 757.392 us; speedup vs baseline: 1.5263x; 1.0133x over previous
//
#include <hip/hip_runtime.h>
#include <hip/hip_bf16.h>
#include <cmath>

#define LAYERS 4
#define Bb 4
#define Ss 1024
#define Dd 1024
#define Ff 2048
#define Hh 8
#define DHd 128
#define Mm (Bb * Ss)   // 4096 rows
#define EPSf 1e-5f
#define LDQ 4096       // combined QKVG row stride

typedef __attribute__((ext_vector_type(8))) short short8v;
typedef __attribute__((ext_vector_type(4))) float f32x4;
typedef __attribute__((ext_vector_type(4))) unsigned int u32x4;

__device__ __forceinline__ float swish_f(float x) { return x / (1.f + expf(-x)); }
__device__ __forceinline__ float gelu_f(float x) {
  return 0.5f * x * (1.f + tanhf(0.7978845608028654f * (x + 0.044715f * x * x * x)));
}
__device__ __forceinline__ unsigned short f2bfu(float f) {
  __hip_bfloat16 h = __float2bfloat16(f);
  return __builtin_bit_cast(unsigned short, h);
}
__device__ __forceinline__ float bfu2f(unsigned short u) {
  unsigned v = ((unsigned)u) << 16;
  return __builtin_bit_cast(float, v);
}
__device__ __forceinline__ void gl_lds16(const void* g, void* l) {
  __builtin_amdgcn_global_load_lds((__attribute__((address_space(1))) void*)g,
                                   (__attribute__((address_space(3))) void*)l, 16, 0, 0);
}
__device__ __forceinline__ f32x4 mfma16(short8v a, short8v b, f32x4 c) {
  return __builtin_amdgcn_mfma_f32_16x16x32_bf16(a, b, c, 0, 0, 0);
}

// ---------------- LayerNorm fp32 -> bf16 ----------------
__global__ __launch_bounds__(256) void ln_bf16_kernel(const float* __restrict__ x,
                                                      short* __restrict__ outb,
                                                      const float* __restrict__ sc,
                                                      const float* __restrict__ bi) {
  const int row = blockIdx.x;
  const int t = threadIdx.x;
  const float4 v = *(const float4*)(x + (size_t)row * Dd + t * 4);
  float s = v.x + v.y + v.z + v.w;
  float s2 = v.x * v.x + v.y * v.y + v.z * v.z + v.w * v.w;
#pragma unroll
  for (int o = 32; o > 0; o >>= 1) { s += __shfl_down(s, o); s2 += __shfl_down(s2, o); }
  __shared__ float ps[4], ps2[4];
  if ((t & 63) == 0) { ps[t >> 6] = s; ps2[t >> 6] = s2; }
  __syncthreads();
  s = ps[0] + ps[1] + ps[2] + ps[3];
  s2 = ps2[0] + ps2[1] + ps2[2] + ps2[3];
  const float mu = s * (1.f / Dd);
  const float var = s2 * (1.f / Dd) - mu * mu;
  const float rstd = rsqrtf(var + EPSf);
  const float4 g = *(const float4*)(sc + t * 4);
  const float4 b = *(const float4*)(bi + t * 4);
  const float o0 = (v.x - mu) * rstd * g.x + b.x;
  const float o1 = (v.y - mu) * rstd * g.y + b.y;
  const float o2 = (v.z - mu) * rstd * g.z + b.z;
  const float o3 = (v.w - mu) * rstd * g.w + b.w;
  unsigned p0 = (unsigned)f2bfu(o0) | ((unsigned)f2bfu(o1) << 16);
  unsigned p1 = (unsigned)f2bfu(o2) | ((unsigned)f2bfu(o3) << 16);
  uint2 pk; pk.x = p0; pk.y = p1;
  *(uint2*)(outb + (size_t)row * Dd + t * 4) = pk;
}

// ---------------- RoPE tables ----------------
__global__ void rope_table_kernel(float* __restrict__ ct, float* __restrict__ st) {
  const int i = blockIdx.x * 256 + threadIdx.x;  // < Ss*64
  const int s = i >> 6, f = i & 63;
  const float inv = powf(10000.f, -(float)f / 64.f);
  const float a = (float)s * inv;
  ct[i] = cosf(a);
  st[i] = sinf(a);
}

// ---------------- merged weight transpose: one dispatch per layer (9216 blocks) ----------
__global__ __launch_bounds__(256) void wtrans_all_kernel(
    const float* __restrict__ Wq, const float* __restrict__ Wk,
    const float* __restrict__ Wv, const float* __restrict__ Wg,
    const float* __restrict__ Wo, const float* __restrict__ W1,
    const float* __restrict__ W2,
    short* __restrict__ Wqkvgt, short* __restrict__ Wot,
    short* __restrict__ W1t, short* __restrict__ W2t) {
  __shared__ float tile[32][33];
  const int t = threadIdx.x;
  const int tc = t & 31, tr8 = t >> 5;
  const int blk = blockIdx.x;
  const float* src; short* dst; int K, N, n0, k0, nl;
  if (blk < 4096) {                       // QKVG concat: 128 x 32 tiles
    const int bx = blk & 127, ky = blk >> 7;
    n0 = bx * 32; k0 = ky * 32;
    const int which = n0 >> 10;
    src = (which == 0) ? Wq : (which == 1) ? Wk : (which == 2) ? Wv : Wg;
    nl = n0 & 1023; N = 1024; K = 1024; dst = Wqkvgt;
  } else if (blk < 5120) {                // Wo: 32 x 32
    const int b2 = blk - 4096;
    n0 = (b2 & 31) * 32; k0 = (b2 >> 5) * 32; nl = n0;
    src = Wo; N = 1024; K = 1024; dst = Wot;
  } else if (blk < 7168) {                // W1 [1024][2048] -> [2048][1024]: 64 x 32
    const int b2 = blk - 5120;
    n0 = (b2 & 63) * 32; k0 = (b2 >> 6) * 32; nl = n0;
    src = W1; N = 2048; K = 1024; dst = W1t;
  } else {                                // W2 [2048][1024] -> [1024][2048]: 32 x 64
    const int b2 = blk - 7168;
    n0 = (b2 & 31) * 32; k0 = (b2 >> 5) * 32; nl = n0;
    src = W2; N = 1024; K = 2048; dst = W2t;
  }
#pragma unroll
  for (int i = 0; i < 4; ++i) {
    const int r = tr8 + i * 8;
    tile[r][tc] = src[(size_t)(k0 + r) * N + nl + tc];
  }
  __syncthreads();
#pragma unroll
  for (int i = 0; i < 4; ++i) {
    const int r = tr8 + i * 8;
    dst[(size_t)(n0 + r) * K + k0 + tc] = (short)f2bfu(tile[tc][r]);
  }
}

// ---------------- merged RoPE (in-place Q,K) + V transpose: 12288 blocks -----------------
__global__ __launch_bounds__(256) void rvt_kernel(short* __restrict__ QKVGb,
                                                  short* __restrict__ Vt,
                                                  const float* __restrict__ ct,
                                                  const float* __restrict__ st) {
  __shared__ short tile[32][33];
  const int blk = blockIdx.x, t = threadIdx.x;
  if (blk < 8192) {
    // RoPE path: idx < B*S*H*64
    const int idx = blk * 256 + t;
    const int f = idx & 63;
    const int h = (idx >> 6) & 7;
    const int r = idx >> 9;            // b*S+s
    const int s = r & (Ss - 1);
    const float c = ct[(s << 6) + f], sn = st[(s << 6) + f];
    const size_t qo = (size_t)r * LDQ + h * DHd + 2 * f;
    const unsigned qp = *(const unsigned*)(QKVGb + qo);
    const unsigned kp = *(const unsigned*)(QKVGb + qo + 1024);
    const float qx = bfu2f((unsigned short)(qp & 0xffff)), qy = bfu2f((unsigned short)(qp >> 16));
    const float kx = bfu2f((unsigned short)(kp & 0xffff)), ky = bfu2f((unsigned short)(kp >> 16));
    const unsigned qn = (unsigned)f2bfu(qx * c - qy * sn) |
                        ((unsigned)f2bfu(qx * sn + qy * c) << 16);
    const unsigned kn = (unsigned)f2bfu(kx * c + ky * sn) |
                        ((unsigned)f2bfu(-kx * sn + ky * c) << 16);
    *(unsigned*)(QKVGb + qo) = qn;
    *(unsigned*)(QKVGb + qo + 1024) = kn;
  } else {
    // V transpose path: vb < 32*4*32
    const int vb = blk - 8192;
    const int s0 = (vb & 31) * 32, d0 = ((vb >> 5) & 3) * 32, bh = vb >> 7;
    const int bb = bh >> 3, h = bh & 7;
    const int tc = t & 31, tr8 = t >> 5;
#pragma unroll
    for (int i = 0; i < 4; ++i) {
      const int r = tr8 + i * 8;
      tile[r][tc] = QKVGb[(size_t)(bb * Ss + s0 + r) * LDQ + 2048 + h * DHd + d0 + tc];
    }
    __syncthreads();
#pragma unroll
    for (int i = 0; i < 4; ++i) {
      const int r = tr8 + i * 8;
      Vt[(size_t)(bh * DHd + d0 + r) * Ss + s0 + tc] = tile[tc][r];
    }
  }
}

// ---------------- bf16 MFMA GEMM v13: 256x256 8-phase, deep A+B prefetch, vmcnt(8) --------
// Stage schedule: phC stages B(kt+2) (B-reads done in phB), phD stages A(kt+2) (A-reads
// done in phC). Both land in the buffers read this kt (register-capture makes it safe).
// vmcnt(8) at phD drains exactly kt+1's 8 loads (issued a full K-tile earlier).
template <int EPI>
__global__ __launch_bounds__(512, 2) void gemm13(const short* __restrict__ A,
                                                 const short* __restrict__ Bt,
                                                 float* __restrict__ Cf,
                                                 short* __restrict__ Cb,
                                                 const float* __restrict__ Res,
                                                 int N, int K, int ldc) {
  __shared__ __align__(16) short As[2][2][128 * 64];  // [dbuf][half] 64 KB
  __shared__ __align__(16) short Bs[2][2][128 * 64];  // 64 KB
  const int t = threadIdx.x;
  const int w = t >> 6, l = t & 63;
  const int lq = l >> 4, lr = l & 15;
  const int wr = w >> 2, wc = w & 3;
  const int bhalf = wc >> 1, brow0 = (wc & 1) * 64;
  const int nwg = gridDim.x * gridDim.y;
  const int bid0 = blockIdx.x + blockIdx.y * gridDim.x;
  const int lgid = (bid0 & 7) * (nwg >> 3) + (bid0 >> 3);
  const int bx = lgid % gridDim.x, by = lgid / gridDim.x;
  const int row0 = by * 256, col0 = bx * 256;
  const int NT = K >> 6;

  f32x4 acc[8][4] = {};
  short8v a[4][2], b[4][2];

  auto stageA = [&](int kt, int hf) {
    const int db = kt & 1;
#pragma unroll
    for (int i = 0; i < 2; ++i) {
      const int c = t + i * 512;
      const int row = c >> 3, slot = c & 7;
      gl_lds16(A + (size_t)(row0 + hf * 128 + row) * K + kt * 64 + ((slot ^ (row & 7)) << 3),
               &As[db][hf][c * 8]);
    }
  };
  auto stageB = [&](int kt, int hf) {
    const int db = kt & 1;
#pragma unroll
    for (int i = 0; i < 2; ++i) {
      const int c = t + i * 512;
      const int row = c >> 3, slot = c & 7;
      gl_lds16(Bt + (size_t)(col0 + hf * 128 + row) * K + kt * 64 + ((slot ^ (row & 7)) << 3),
               &Bs[db][hf][c * 8]);
    }
  };
  auto rdA = [&](int db, int m, int ks) -> short8v {
    const int row = m * 16 + lr;
    return *(const short8v*)&As[db][wr][row * 64 + (((ks << 2) + lq) ^ (row & 7)) * 8];
  };
  auto rdB = [&](int db, int n, int ks) -> short8v {
    const int row = brow0 + n * 16 + lr;
    return *(const short8v*)&Bs[db][bhalf][row * 64 + (((ks << 2) + lq) ^ (row & 7)) * 8];
  };

  // prologue: stage kt0 + kt1 fully (16 loads); drain kt0's 8, kt1's keep flying
  stageA(0, 0); stageA(0, 1); stageB(0, 0); stageB(0, 1);
  if (NT > 1) { stageA(1, 0); stageA(1, 1); stageB(1, 0); stageB(1, 1); }
  if (NT > 1) { asm volatile("s_waitcnt vmcnt(8)" ::: "memory"); }
  else        { asm volatile("s_waitcnt vmcnt(0)" ::: "memory"); }
  asm volatile("s_barrier" ::: "memory");

  for (int kt = 0; kt < NT; ++kt) {
    const int db = kt & 1;
    // ---- phA: read a(m0-3)+b(n0-1); MFMA Q1 ----
#pragma unroll
    for (int m = 0; m < 4; ++m) { a[m][0] = rdA(db, m, 0); a[m][1] = rdA(db, m, 1); }
#pragma unroll
    for (int n = 0; n < 2; ++n) { b[n][0] = rdB(db, n, 0); b[n][1] = rdB(db, n, 1); }
    __builtin_amdgcn_s_setprio(1);
#pragma unroll
    for (int m = 0; m < 4; ++m)
#pragma unroll
      for (int n = 0; n < 2; ++n) {
        acc[m][n] = mfma16(a[m][0], b[n][0], acc[m][n]);
        acc[m][n] = mfma16(a[m][1], b[n][1], acc[m][n]);
      }
    __builtin_amdgcn_s_setprio(0);
    asm volatile("s_barrier" ::: "memory");
    // ---- phB: read b(n2-3); MFMA Q2 ----
#pragma unroll
    for (int n = 2; n < 4; ++n) { b[n][0] = rdB(db, n, 0); b[n][1] = rdB(db, n, 1); }
    __builtin_amdgcn_s_setprio(1);
#pragma unroll
    for (int m = 0; m < 4; ++m)
#pragma unroll
      for (int n = 2; n < 4; ++n) {
        acc[m][n] = mfma16(a[m][0], b[n][0], acc[m][n]);
        acc[m][n] = mfma16(a[m][1], b[n][1], acc[m][n]);
      }
    __builtin_amdgcn_s_setprio(0);
    asm volatile("s_barrier" ::: "memory");
    // ---- phC: read a(m4-7); stage B(kt+2) both halves; MFMA Q3 ----
#pragma unroll
    for (int m = 0; m < 4; ++m) { a[m][0] = rdA(db, m + 4, 0); a[m][1] = rdA(db, m + 4, 1); }
    if (kt + 2 < NT) { stageB(kt + 2, 0); stageB(kt + 2, 1); }
    __builtin_amdgcn_s_setprio(1);
#pragma unroll
    for (int m = 0; m < 4; ++m)
#pragma unroll
      for (int n = 0; n < 2; ++n) {
        acc[m + 4][n] = mfma16(a[m][0], b[n][0], acc[m + 4][n]);
        acc[m + 4][n] = mfma16(a[m][1], b[n][1], acc[m + 4][n]);
      }
    __builtin_amdgcn_s_setprio(0);
    asm volatile("s_barrier" ::: "memory");
    // ---- phD: stage A(kt+2) both halves; MFMA Q4; vmcnt(8); barrier ----
    if (kt + 2 < NT) { stageA(kt + 2, 0); stageA(kt + 2, 1); }
    __builtin_amdgcn_s_setprio(1);
#pragma unroll
    for (int m = 0; m < 4; ++m)
#pragma unroll
      for (int n = 2; n < 4; ++n) {
        acc[m + 4][n] = mfma16(a[m][0], b[n][0], acc[m + 4][n]);
        acc[m + 4][n] = mfma16(a[m][1], b[n][1], acc[m + 4][n]);
      }
    __builtin_amdgcn_s_setprio(0);
    if (kt + 2 < NT) { asm volatile("s_waitcnt vmcnt(8)" ::: "memory"); }
    else             { asm volatile("s_waitcnt vmcnt(0)" ::: "memory"); }
    asm volatile("s_barrier" ::: "memory");
  }

#pragma unroll
  for (int m = 0; m < 8; ++m) {
#pragma unroll
    for (int n = 0; n < 4; ++n) {
#pragma unroll
      for (int r = 0; r < 4; ++r) {
        const int row = row0 + wr * 128 + m * 16 + lq * 4 + r;
        const int col = col0 + wc * 64 + n * 16 + lr;
        const size_t o = (size_t)row * ldc + col;
        float v = acc[m][n][r];
        if (EPI == 0) Cb[o] = (short)f2bfu(v);
        else if (EPI == 1) Cf[o] = v + Res[o];
        else Cb[o] = (short)f2bfu(gelu_f(v));
      }
    }
  }
}

// ---------------- bf16 MFMA GEMM v11: 256x128 2-phase/K-tile, ring-3 LDS, vmcnt(6) --------
template <int EPI>
__global__ __launch_bounds__(512) void gemm11(const short* __restrict__ A,
                                              const short* __restrict__ Bt,
                                              float* __restrict__ Cf,
                                              short* __restrict__ Cb,
                                              const float* __restrict__ Res,
                                              int K, int lda, int ldb, int ldc, int nxt) {
  __shared__ __align__(16) short As[3][256 * 64];  // 96 KB ring-3
  __shared__ __align__(16) short Bs[3][128 * 64];  // 48 KB ring-3
  const int t = threadIdx.x;
  const int w = t >> 6, l = t & 63;
  const int lq = l >> 4, lr = l & 15;
  const int wr = w >> 2, wc = w & 3;
  const int nwg = gridDim.x;
  const int lgid = (blockIdx.x & 7) * (nwg >> 3) + (blockIdx.x >> 3);
  const int mt = lgid / nxt, nt_ = lgid % nxt;
  const int row0 = mt * 256, col0 = nt_ * 128;
  const int NT = K >> 6;
  f32x4 acc[8][2] = {};
  short8v a[4][2], b[2][2];

  auto stageA = [&](int kt, int hf) {
    const int s = kt % 3;
#pragma unroll
    for (int i = 0; i < 2; ++i) {
      const int c = t + i * 512;
      const int row = c >> 3, slot = c & 7;
      gl_lds16(A + (size_t)(row0 + hf * 128 + row) * lda + kt * 64 + ((slot ^ (row & 7)) << 3),
               &As[s][hf * 8192 + c * 8]);
    }
  };
  auto stageB = [&](int kt) {
    const int s = kt % 3;
#pragma unroll
    for (int i = 0; i < 2; ++i) {
      const int c = t + i * 512;
      const int row = c >> 3, slot = c & 7;
      gl_lds16(Bt + (size_t)(col0 + row) * ldb + kt * 64 + ((slot ^ (row & 7)) << 3),
               &Bs[s][c * 8]);
    }
  };
  auto rdA = [&](int s, int m, int ks) -> short8v {
    const int row = wr * 128 + m * 16 + lr;
    return *(const short8v*)&As[s][row * 64 + (((ks << 2) + lq) ^ (row & 7)) * 8];
  };
  auto rdB = [&](int s, int n, int ks) -> short8v {
    const int row = wc * 32 + n * 16 + lr;
    return *(const short8v*)&Bs[s][row * 64 + (((ks << 2) + lq) ^ (row & 7)) * 8];
  };

  stageA(0, 0); stageA(0, 1); stageB(0);
  stageA(1, 0); stageA(1, 1); stageB(1);
  asm volatile("s_waitcnt vmcnt(6)" ::: "memory");
  asm volatile("s_barrier" ::: "memory");

  for (int kt = 0; kt < NT; ++kt) {
    const int s = kt % 3;
#pragma unroll
    for (int m = 0; m < 4; ++m) { a[m][0] = rdA(s, m, 0); a[m][1] = rdA(s, m, 1); }
#pragma unroll
    for (int n = 0; n < 2; ++n) { b[n][0] = rdB(s, n, 0); b[n][1] = rdB(s, n, 1); }
    if (kt + 2 < NT) stageA(kt + 2, 0);
    __builtin_amdgcn_s_setprio(1);
#pragma unroll
    for (int m = 0; m < 4; ++m)
#pragma unroll
      for (int n = 0; n < 2; ++n) {
        acc[m][n] = mfma16(a[m][0], b[n][0], acc[m][n]);
        acc[m][n] = mfma16(a[m][1], b[n][1], acc[m][n]);
      }
    __builtin_amdgcn_s_setprio(0);
    asm volatile("s_barrier" ::: "memory");
#pragma unroll
    for (int m = 0; m < 4; ++m) { a[m][0] = rdA(s, m + 4, 0); a[m][1] = rdA(s, m + 4, 1); }
    if (kt + 2 < NT) { stageA(kt + 2, 1); stageB(kt + 2); }
    __builtin_amdgcn_s_setprio(1);
#pragma unroll
    for (int m = 0; m < 4; ++m)
#pragma unroll
      for (int n = 0; n < 2; ++n) {
        acc[m + 4][n] = mfma16(a[m][0], b[n][0], acc[m + 4][n]);
        acc[m + 4][n] = mfma16(a[m][1], b[n][1], acc[m + 4][n]);
      }
    __builtin_amdgcn_s_setprio(0);
    if (kt + 2 < NT) { asm volatile("s_waitcnt vmcnt(6)" ::: "memory"); }
    else             { asm volatile("s_waitcnt vmcnt(0)" ::: "memory"); }
    asm volatile("s_barrier" ::: "memory");
  }

#pragma unroll
  for (int m = 0; m < 8; ++m) {
#pragma unroll
    for (int n = 0; n < 2; ++n) {
#pragma unroll
      for (int r = 0; r < 4; ++r) {
        const int row = row0 + wr * 128 + m * 16 + lq * 4 + r;
        const int col = col0 + wc * 32 + n * 16 + lr;
        const size_t o = (size_t)row * ldc + col;
        float v = acc[m][n][r];
        if (EPI == 0) Cb[o] = (short)f2bfu(v);
        else if (EPI == 1) Cf[o] = v + Res[o];
        else Cb[o] = (short)f2bfu(gelu_f(v));
      }
    }
  }
}

// ---------------- bf16 MFMA GEMM v12: 128x128 2-phase/K-tile, ring-3 LDS, vmcnt(4) --------
template <int EPI>
__global__ __launch_bounds__(512) void gemm12(const short* __restrict__ A,
                                              const short* __restrict__ Bt,
                                              float* __restrict__ Cf,
                                              short* __restrict__ Cb,
                                              const float* __restrict__ Res,
                                              int K, int lda, int ldb, int ldc, int nxt) {
  __shared__ __align__(16) short As[3][128 * 64];  // 48 KB ring-3
  __shared__ __align__(16) short Bs[3][128 * 64];  // 48 KB ring-3
  const int t = threadIdx.x;
  const int w = t >> 6, l = t & 63;
  const int lq = l >> 4, lr = l & 15;
  const int wr = w >> 2, wc = w & 3;
  const int nwg = gridDim.x;
  const int lgid = (blockIdx.x & 7) * (nwg >> 3) + (blockIdx.x >> 3);
  const int mt = lgid / nxt, nt_ = lgid % nxt;
  const int row0 = mt * 128, col0 = nt_ * 128;
  const int NT = K >> 6;
  f32x4 acc[4][2] = {};
  short8v a[4][2], b[2][2];

  auto stageA = [&](int kt) {
    const int s = kt % 3;
#pragma unroll
    for (int i = 0; i < 2; ++i) {
      const int c = t + i * 512;
      const int row = c >> 3, slot = c & 7;
      gl_lds16(A + (size_t)(row0 + row) * lda + kt * 64 + ((slot ^ (row & 7)) << 3),
               &As[s][c * 8]);
    }
  };
  auto stageB = [&](int kt) {
    const int s = kt % 3;
#pragma unroll
    for (int i = 0; i < 2; ++i) {
      const int c = t + i * 512;
      const int row = c >> 3, slot = c & 7;
      gl_lds16(Bt + (size_t)(col0 + row) * ldb + kt * 64 + ((slot ^ (row & 7)) << 3),
               &Bs[s][c * 8]);
    }
  };
  auto rdA = [&](int s, int m, int ks) -> short8v {
    const int row = wr * 64 + m * 16 + lr;
    return *(const short8v*)&As[s][row * 64 + (((ks << 2) + lq) ^ (row & 7)) * 8];
  };
  auto rdB = [&](int s, int n, int ks) -> short8v {
    const int row = wc * 32 + n * 16 + lr;
    return *(const short8v*)&Bs[s][row * 64 + (((ks << 2) + lq) ^ (row & 7)) * 8];
  };

  stageA(0); stageB(0);
  stageA(1); stageB(1);
  asm volatile("s_waitcnt vmcnt(4)" ::: "memory");
  asm volatile("s_barrier" ::: "memory");

  for (int kt = 0; kt < NT; ++kt) {
    const int s = kt % 3;
#pragma unroll
    for (int m = 0; m < 4; ++m) { a[m][0] = rdA(s, m, 0); a[m][1] = rdA(s, m, 1); }
#pragma unroll
    for (int n = 0; n < 2; ++n) { b[n][0] = rdB(s, n, 0); b[n][1] = rdB(s, n, 1); }
    if (kt + 2 < NT) stageA(kt + 2);
    __builtin_amdgcn_s_setprio(1);
#pragma unroll
    for (int m = 0; m < 2; ++m)
#pragma unroll
      for (int n = 0; n < 2; ++n) {
        acc[m][n] = mfma16(a[m][0], b[n][0], acc[m][n]);
        acc[m][n] = mfma16(a[m][1], b[n][1], acc[m][n]);
      }
    __builtin_amdgcn_s_setprio(0);
    asm volatile("s_barrier" ::: "memory");
    if (kt + 2 < NT) stageB(kt + 2);
    __builtin_amdgcn_s_setprio(1);
#pragma unroll
    for (int m = 2; m < 4; ++m)
#pragma unroll
      for (int n = 0; n < 2; ++n) {
        acc[m][n] = mfma16(a[m][0], b[n][0], acc[m][n]);
        acc[m][n] = mfma16(a[m][1], b[n][1], acc[m][n]);
      }
    __builtin_amdgcn_s_setprio(0);
    if (kt + 2 < NT) { asm volatile("s_waitcnt vmcnt(4)" ::: "memory"); }
    else             { asm volatile("s_waitcnt vmcnt(0)" ::: "memory"); }
    asm volatile("s_barrier" ::: "memory");
  }

#pragma unroll
  for (int m = 0; m < 4; ++m) {
#pragma unroll
    for (int n = 0; n < 2; ++n) {
#pragma unroll
      for (int r = 0; r < 4; ++r) {
        const int row = row0 + wr * 64 + m * 16 + lq * 4 + r;
        const int col = col0 + wc * 32 + n * 16 + lr;
        const size_t o = (size_t)row * ldc + col;
        float v = acc[m][n][r];
        if (EPI == 0) Cb[o] = (short)f2bfu(v);
        else if (EPI == 1) Cf[o] = v + Res[o];
        else Cb[o] = (short)f2bfu(gelu_f(v));
      }
    }
  }
}

// ---------------- Retention v4: dbuf K/V, 1 barrier/tile, setprio, XCD-local bh ----------
__global__ __launch_bounds__(256) void ret4_kernel(const short* __restrict__ QKb,
                                                   const short* __restrict__ Vt,
                                                   float* __restrict__ Y0,
                                                   float* __restrict__ Y1) {
  __shared__ __align__(16) short Ks[2][64 * 128];
  __shared__ __align__(16) short Vs[2][128 * 64];
  const int t = threadIdx.x, w = t >> 6, l = t & 63;
  const int lq = l >> 4, lr = l & 15;
  const int u = blockIdx.x;                 // 0..511
  const int lgid = (u & 7) * 64 + (u >> 3);
  const int half = lgid >> 8;
  const int rest = lgid & 255;
  const int bh = rest >> 3, j = rest & 7;
  const int qb = half ? j : 7 - j;
  const int b = bh >> 3, h = bh & 7;
  const int q0 = qb * 128;
  const float lstep = (logf(1.f / 512.f) - logf(1.f / 32.f)) * (1.f / 7.f);
  const float gamma = 1.f - expf(logf(1.f / 32.f) + (float)h * lstep);
  const float l2g = logf(gamma) * 1.44269504f;
  const short* Qp = QKb;
  const short* Kp = QKb + 1024;

  short8v qf[2][4];
#pragma unroll
  for (int qn = 0; qn < 2; ++qn)
#pragma unroll
    for (int ks = 0; ks < 4; ++ks)
      qf[qn][ks] = *(const short8v*)(Qp + (size_t)(b * Ss + q0 + w * 32 + qn * 16 + lr) * LDQ +
                                     h * DHd + ks * 32 + lq * 8);

  float cmf[4], csr[4];
#pragma unroll
  for (int mf = 0; mf < 4; ++mf) cmf[mf] = exp2f(l2g * (float)(-16 * mf));
#pragma unroll
  for (int r = 0; r < 4; ++r) csr[r] = exp2f(l2g * (float)(63 - 4 * lq - r));

  f32x4 yacc[2][8] = {};
  const int nt = 2 * qb + 2;
  const int sb = ((lq & 1) * 2) * 16 + lr;

  auto stageKV = [&](int m0, int buf) {
#pragma unroll
    for (int i = 0; i < 4; ++i) {
      const int c = (w * 4 + i) * 64 + l;
      const int row = c >> 4, slot = c & 15;
      gl_lds16(Kp + (size_t)(b * Ss + m0 + row) * LDQ + h * DHd + ((slot ^ (row & 7)) * 8),
               &Ks[buf][(w * 4 + i) * 512]);
    }
#pragma unroll
    for (int i = 0; i < 4; ++i) {
      const int c = (w * 4 + i) * 64 + l;
      const int row = c >> 3, slot = c & 7;
      gl_lds16(Vt + (size_t)(bh * DHd + row) * Ss + m0 + ((slot ^ (row & 7)) * 8),
               &Vs[buf][(w * 4 + i) * 512]);
    }
  };

  stageKV(half * 64, 0);
  __syncthreads();
  int cur = 0;
  for (int tt = half; tt < nt; tt += 2) {
    const int m0 = tt * 64;
    if (tt + 2 < nt) stageKV((tt + 2) * 64, cur ^ 1);

    f32x4 st[4][2] = {};
    __builtin_amdgcn_s_setprio(1);
#pragma unroll
    for (int mf = 0; mf < 4; ++mf) {
      const int row = mf * 16 + lr;
#pragma unroll
      for (int ks = 0; ks < 4; ++ks) {
        short8v kf = *(const short8v*)&Ks[cur][row * 128 + (((4 * ks + lq) ^ (row & 7)) * 8)];
        st[mf][0] = mfma16(kf, qf[0][ks], st[mf][0]);
        st[mf][1] = mfma16(kf, qf[1][ks], st[mf][1]);
      }
    }
    __builtin_amdgcn_s_setprio(0);
    float rs[2];
#pragma unroll
    for (int qn = 0; qn < 2; ++qn)
      rs[qn] = exp2f(l2g * (float)(q0 + w * 32 + qn * 16 + lr - m0 - 63));
#pragma unroll
    for (int mf = 0; mf < 4; ++mf)
#pragma unroll
      for (int qn = 0; qn < 2; ++qn)
#pragma unroll
        for (int r = 0; r < 4; ++r) {
          const int qg = q0 + w * 32 + qn * 16 + lr;
          const int kvg = m0 + mf * 16 + lq * 4 + r;
          const float wgt = (qg >= kvg) ? rs[qn] * cmf[mf] * csr[r] : 0.f;
          st[mf][qn][r] *= wgt;
        }
    unsigned pk[4][2][2];
#pragma unroll
    for (int mf = 0; mf < 4; ++mf)
#pragma unroll
      for (int qn = 0; qn < 2; ++qn)
#pragma unroll
        for (int p = 0; p < 2; ++p)
          pk[mf][qn][p] = (unsigned)f2bfu(st[mf][qn][2 * p]) |
                          ((unsigned)f2bfu(st[mf][qn][2 * p + 1]) << 16);
    short8v afr[2][2];
#pragma unroll
    for (int qn = 0; qn < 2; ++qn)
#pragma unroll
      for (int ks2 = 0; ks2 < 2; ++ks2) {
        u32x4 wd;
#pragma unroll
        for (int wj = 0; wj < 4; ++wj) {
          const int src = sb + (wj >> 1) * 16;
          const unsigned v0 = __shfl(pk[2 * ks2 + 0][qn][wj & 1], src);
          const unsigned v1 = __shfl(pk[2 * ks2 + 1][qn][wj & 1], src);
          wd[wj] = (lq >= 2) ? v1 : v0;
        }
        afr[qn][ks2] = __builtin_bit_cast(short8v, wd);
      }
    __builtin_amdgcn_s_setprio(1);
#pragma unroll
    for (int nd = 0; nd < 8; ++nd) {
      const int row = nd * 16 + lr;
#pragma unroll
      for (int ks2 = 0; ks2 < 2; ++ks2) {
        short8v vf = *(const short8v*)&Vs[cur][row * 64 + (((4 * ks2 + lq) ^ (row & 7)) * 8)];
        yacc[0][nd] = mfma16(afr[0][ks2], vf, yacc[0][nd]);
        yacc[1][nd] = mfma16(afr[1][ks2], vf, yacc[1][nd]);
      }
    }
    __builtin_amdgcn_s_setprio(0);
    __syncthreads();
    cur ^= 1;
  }
  float* Y = half ? Y1 : Y0;
#pragma unroll
  for (int qn = 0; qn < 2; ++qn)
#pragma unroll
    for (int r = 0; r < 4; ++r) {
      const int q = q0 + w * 32 + qn * 16 + lq * 4 + r;
#pragma unroll
      for (int nd = 0; nd < 8; ++nd)
        Y[(size_t)(b * Ss + q) * Dd + h * DHd + nd * 16 + lr] = yacc[qn][nd][r];
    }
}

// ---------------- gate: Gb = bf16( swish(Graw) * GN(Y0+Y1) ) ----------------
__global__ __launch_bounds__(256) void gate_kernel(const float* __restrict__ Y0,
                                                   const float* __restrict__ Y1,
                                                   const short* __restrict__ Graw,
                                                   short* __restrict__ Gb,
                                                   const float* __restrict__ gs,
                                                   const float* __restrict__ gb) {
  const int lane = threadIdx.x & 63;
  const int rowh = blockIdx.x * 4 + (threadIdx.x >> 6);  // (b*S+s)*H + h
  const int h = rowh & 7;
  const int row = rowh >> 3;
  const size_t ybase = (size_t)row * Dd + (size_t)h * DHd + lane * 2;
  float2 a = *(const float2*)(Y0 + ybase);
  const float2 c = *(const float2*)(Y1 + ybase);
  a.x += c.x; a.y += c.y;
  float s = a.x + a.y, s2 = a.x * a.x + a.y * a.y;
#pragma unroll
  for (int o = 32; o > 0; o >>= 1) { s += __shfl_down(s, o); s2 += __shfl_down(s2, o); }
  s = __shfl(s, 0);
  s2 = __shfl(s2, 0);
  const float mu = s * (1.f / DHd);
  const float rstd = rsqrtf(s2 * (1.f / DHd) - mu * mu + EPSf);
  const int d = h * DHd + lane * 2;
  const float2 g = *(const float2*)(gs + d);
  const float2 bbv = *(const float2*)(gb + d);
  const float y0 = (a.x - mu) * rstd * g.x + bbv.x;
  const float y1 = (a.y - mu) * rstd * g.y + bbv.y;
  const unsigned gr = *(const unsigned*)(Graw + (size_t)row * LDQ + 3072 + h * DHd + lane * 2);
  const float gx = bfu2f((unsigned short)(gr & 0xffff));
  const float gy = bfu2f((unsigned short)(gr >> 16));
  const unsigned o01 = (unsigned)f2bfu(swish_f(gx) * y0) |
                       ((unsigned)f2bfu(swish_f(gy) * y1) << 16);
  *(unsigned*)(Gb + ybase) = o01;
}

extern "C" void kernel_launch(void* const* d_in, const int* in_sizes, int n_in,
                              void* d_out, int out_size, void* d_ws, size_t ws_size,
                              hipStream_t stream) {
  const float* X = (const float*)d_in[0];
  const float* Wq = (const float*)d_in[1];
  const float* Wk = (const float*)d_in[2];
  const float* Wv = (const float*)d_in[3];
  const float* Wg = (const float*)d_in[4];
  const float* Wo = (const float*)d_in[5];
  const float* W1 = (const float*)d_in[6];
  const float* W2 = (const float*)d_in[7];
  const float* lns = (const float*)d_in[8];
  const float* lnb = (const float*)d_in[9];
  const float* gns = (const float*)d_in[10];
  const float* gnb = (const float*)d_in[11];
  float* out = (float*)d_out;

  char* W = (char*)d_ws;
  const size_t MB = 1u << 20;
  float* Abuf  = (float*)(W);             // 16 MB fp32
  short* Xnb   = (short*)(W + 16 * MB);   // 8 MB bf16
  short* QKVGb = (short*)(W + 24 * MB);   // 32 MB bf16 [4096][4096]; Hb aliases first 16 MB
  float* Y0    = (float*)(W + 56 * MB);   // 16 MB fp32
  float* Y1    = (float*)(W + 72 * MB);   // 16 MB fp32
  short* Vtb   = (short*)(W + 88 * MB);   // 8 MB bf16
  short* Gb    = (short*)(W + 96 * MB);   // 8 MB bf16
  short* Wqkvgt= (short*)(W + 104 * MB);  // 8 MB
  short* Wot   = (short*)(W + 112 * MB);  // 2 MB
  short* W1t   = (short*)(W + 114 * MB);  // 4 MB
  short* W2t   = (short*)(W + 118 * MB);  // 4 MB
  float* ct    = (float*)(W + 122 * MB);  // 256 KB
  float* st    = ct + Ss * 64;            // 256 KB
  short* Hb = QKVGb;  // FFN hidden 4096x2048 bf16 (16 MB)

  hipMemcpyAsync(Abuf, X, (size_t)Mm * Dd * sizeof(float), hipMemcpyDeviceToDevice, stream);
  rope_table_kernel<<<(Ss * 64) / 256, 256, 0, stream>>>(ct, st);

  for (int l = 0; l < LAYERS; ++l) {
    const size_t DD = (size_t)Dd * Dd;
    // one merged weight-transpose dispatch per layer
    wtrans_all_kernel<<<9216, 256, 0, stream>>>(Wq + l * DD, Wk + l * DD, Wv + l * DD,
                                                Wg + l * DD, Wo + l * DD,
                                                W1 + (size_t)l * Dd * Ff,
                                                W2 + (size_t)l * Ff * Dd,
                                                Wqkvgt, Wot, W1t, W2t);
    // Xn = LN(A) -> bf16
    ln_bf16_kernel<<<Mm, 256, 0, stream>>>(Abuf, Xnb, lns, lnb);
    // fused QKVG projection -> combined bf16 buffer (deep-prefetch 8-phase 256x256)
    gemm13<0><<<dim3(16, 16), 512, 0, stream>>>(Xnb, Wqkvgt, nullptr, QKVGb,
                                                nullptr, 4096, Dd, LDQ);
    // merged RoPE (in-place Q,K) + V transpose
    rvt_kernel<<<12288, 256, 0, stream>>>(QKVGb, Vtb, ct, st);
    // retention -> partial Y0,Y1 (fp32)
    ret4_kernel<<<512, 256, 0, stream>>>(QKVGb, Vtb, Y0, Y1);
    // gate: Gb = swish(Graw) * GN(Y0+Y1)
    gate_kernel<<<(Mm * Hh) / 4, 256, 0, stream>>>(Y0, Y1, QKVGb, Gb,
                                                   gns + (size_t)l * Dd, gnb + (size_t)l * Dd);
    // A = (Gb @ Wo) + A : 128x128 ring-3 2-phase
    gemm12<1><<<256, 512, 0, stream>>>(Gb, Wot, Abuf, nullptr, Abuf,
                                       Dd, Dd, Dd, Dd, 8);
    // FFN
    ln_bf16_kernel<<<Mm, 256, 0, stream>>>(Abuf, Xnb, lns, lnb);
    gemm11<2><<<256, 512, 0, stream>>>(Xnb, W1t, nullptr, Hb, nullptr,
                                       Dd, Dd, Dd, Ff, 16);
    float* dst = (l == LAYERS - 1) ? out : Abuf;
    gemm12<1><<<256, 512, 0, stream>>>(Hb, W2t, dst, nullptr, Abuf,
                                       Ff, Ff, Ff, Dd, 8);
  }
}

// Round 15
// 746.694 us; speedup vs baseline: 1.5482x; 1.0143x over previous
//
#include <hip/hip_runtime.h>
#include <hip/hip_bf16.h>
#include <cmath>

#define LAYERS 4
#define Bb 4
#define Ss 1024
#define Dd 1024
#define Ff 2048
#define Hh 8
#define DHd 128
#define Mm (Bb * Ss)   // 4096 rows
#define EPSf 1e-5f
#define LDQ 4096       // combined QKVG row stride

typedef __attribute__((ext_vector_type(8))) short short8v;
typedef __attribute__((ext_vector_type(4))) float f32x4;
typedef __attribute__((ext_vector_type(4))) unsigned int u32x4;

__device__ __forceinline__ float swish_f(float x) { return x / (1.f + expf(-x)); }
__device__ __forceinline__ float gelu_f(float x) {
  return 0.5f * x * (1.f + tanhf(0.7978845608028654f * (x + 0.044715f * x * x * x)));
}
__device__ __forceinline__ unsigned short f2bfu(float f) {
  __hip_bfloat16 h = __float2bfloat16(f);
  return __builtin_bit_cast(unsigned short, h);
}
__device__ __forceinline__ float bfu2f(unsigned short u) {
  unsigned v = ((unsigned)u) << 16;
  return __builtin_bit_cast(float, v);
}
__device__ __forceinline__ void gl_lds16(const void* g, void* l) {
  __builtin_amdgcn_global_load_lds((__attribute__((address_space(1))) void*)g,
                                   (__attribute__((address_space(3))) void*)l, 16, 0, 0);
}
__device__ __forceinline__ f32x4 mfma16(short8v a, short8v b, f32x4 c) {
  return __builtin_amdgcn_mfma_f32_16x16x32_bf16(a, b, c, 0, 0, 0);
}

// ---------------- LayerNorm fp32 -> bf16 ----------------
__global__ __launch_bounds__(256) void ln_bf16_kernel(const float* __restrict__ x,
                                                      short* __restrict__ outb,
                                                      const float* __restrict__ sc,
                                                      const float* __restrict__ bi) {
  const int row = blockIdx.x;
  const int t = threadIdx.x;
  const float4 v = *(const float4*)(x + (size_t)row * Dd + t * 4);
  float s = v.x + v.y + v.z + v.w;
  float s2 = v.x * v.x + v.y * v.y + v.z * v.z + v.w * v.w;
#pragma unroll
  for (int o = 32; o > 0; o >>= 1) { s += __shfl_down(s, o); s2 += __shfl_down(s2, o); }
  __shared__ float ps[4], ps2[4];
  if ((t & 63) == 0) { ps[t >> 6] = s; ps2[t >> 6] = s2; }
  __syncthreads();
  s = ps[0] + ps[1] + ps[2] + ps[3];
  s2 = ps2[0] + ps2[1] + ps2[2] + ps2[3];
  const float mu = s * (1.f / Dd);
  const float var = s2 * (1.f / Dd) - mu * mu;
  const float rstd = rsqrtf(var + EPSf);
  const float4 g = *(const float4*)(sc + t * 4);
  const float4 b = *(const float4*)(bi + t * 4);
  const float o0 = (v.x - mu) * rstd * g.x + b.x;
  const float o1 = (v.y - mu) * rstd * g.y + b.y;
  const float o2 = (v.z - mu) * rstd * g.z + b.z;
  const float o3 = (v.w - mu) * rstd * g.w + b.w;
  unsigned p0 = (unsigned)f2bfu(o0) | ((unsigned)f2bfu(o1) << 16);
  unsigned p1 = (unsigned)f2bfu(o2) | ((unsigned)f2bfu(o3) << 16);
  uint2 pk; pk.x = p0; pk.y = p1;
  *(uint2*)(outb + (size_t)row * Dd + t * 4) = pk;
}

// ---------------- RoPE tables ----------------
__global__ void rope_table_kernel(float* __restrict__ ct, float* __restrict__ st) {
  const int i = blockIdx.x * 256 + threadIdx.x;  // < Ss*64
  const int s = i >> 6, f = i & 63;
  const float inv = powf(10000.f, -(float)f / 64.f);
  const float a = (float)s * inv;
  ct[i] = cosf(a);
  st[i] = sinf(a);
}

// ---------------- merged weight transpose: one dispatch per layer (9216 blocks) ----------
__global__ __launch_bounds__(256) void wtrans_all_kernel(
    const float* __restrict__ Wq, const float* __restrict__ Wk,
    const float* __restrict__ Wv, const float* __restrict__ Wg,
    const float* __restrict__ Wo, const float* __restrict__ W1,
    const float* __restrict__ W2,
    short* __restrict__ Wqkvgt, short* __restrict__ Wot,
    short* __restrict__ W1t, short* __restrict__ W2t) {
  __shared__ float tile[32][33];
  const int t = threadIdx.x;
  const int tc = t & 31, tr8 = t >> 5;
  const int blk = blockIdx.x;
  const float* src; short* dst; int K, N, n0, k0, nl;
  if (blk < 4096) {                       // QKVG concat: 128 x 32 tiles
    const int bx = blk & 127, ky = blk >> 7;
    n0 = bx * 32; k0 = ky * 32;
    const int which = n0 >> 10;
    src = (which == 0) ? Wq : (which == 1) ? Wk : (which == 2) ? Wv : Wg;
    nl = n0 & 1023; N = 1024; K = 1024; dst = Wqkvgt;
  } else if (blk < 5120) {                // Wo: 32 x 32
    const int b2 = blk - 4096;
    n0 = (b2 & 31) * 32; k0 = (b2 >> 5) * 32; nl = n0;
    src = Wo; N = 1024; K = 1024; dst = Wot;
  } else if (blk < 7168) {                // W1 [1024][2048] -> [2048][1024]: 64 x 32
    const int b2 = blk - 5120;
    n0 = (b2 & 63) * 32; k0 = (b2 >> 6) * 32; nl = n0;
    src = W1; N = 2048; K = 1024; dst = W1t;
  } else {                                // W2 [2048][1024] -> [1024][2048]: 32 x 64
    const int b2 = blk - 7168;
    n0 = (b2 & 31) * 32; k0 = (b2 >> 5) * 32; nl = n0;
    src = W2; N = 1024; K = 2048; dst = W2t;
  }
#pragma unroll
  for (int i = 0; i < 4; ++i) {
    const int r = tr8 + i * 8;
    tile[r][tc] = src[(size_t)(k0 + r) * N + nl + tc];
  }
  __syncthreads();
#pragma unroll
  for (int i = 0; i < 4; ++i) {
    const int r = tr8 + i * 8;
    dst[(size_t)(n0 + r) * K + k0 + tc] = (short)f2bfu(tile[tc][r]);
  }
}

// ---------------- merged RoPE (in-place Q,K) + V transpose: 12288 blocks -----------------
__global__ __launch_bounds__(256) void rvt_kernel(short* __restrict__ QKVGb,
                                                  short* __restrict__ Vt,
                                                  const float* __restrict__ ct,
                                                  const float* __restrict__ st) {
  __shared__ short tile[32][33];
  const int blk = blockIdx.x, t = threadIdx.x;
  if (blk < 8192) {
    const int idx = blk * 256 + t;
    const int f = idx & 63;
    const int h = (idx >> 6) & 7;
    const int r = idx >> 9;            // b*S+s
    const int s = r & (Ss - 1);
    const float c = ct[(s << 6) + f], sn = st[(s << 6) + f];
    const size_t qo = (size_t)r * LDQ + h * DHd + 2 * f;
    const unsigned qp = *(const unsigned*)(QKVGb + qo);
    const unsigned kp = *(const unsigned*)(QKVGb + qo + 1024);
    const float qx = bfu2f((unsigned short)(qp & 0xffff)), qy = bfu2f((unsigned short)(qp >> 16));
    const float kx = bfu2f((unsigned short)(kp & 0xffff)), ky = bfu2f((unsigned short)(kp >> 16));
    const unsigned qn = (unsigned)f2bfu(qx * c - qy * sn) |
                        ((unsigned)f2bfu(qx * sn + qy * c) << 16);
    const unsigned kn = (unsigned)f2bfu(kx * c + ky * sn) |
                        ((unsigned)f2bfu(-kx * sn + ky * c) << 16);
    *(unsigned*)(QKVGb + qo) = qn;
    *(unsigned*)(QKVGb + qo + 1024) = kn;
  } else {
    const int vb = blk - 8192;
    const int s0 = (vb & 31) * 32, d0 = ((vb >> 5) & 3) * 32, bh = vb >> 7;
    const int bb = bh >> 3, h = bh & 7;
    const int tc = t & 31, tr8 = t >> 5;
#pragma unroll
    for (int i = 0; i < 4; ++i) {
      const int r = tr8 + i * 8;
      tile[r][tc] = QKVGb[(size_t)(bb * Ss + s0 + r) * LDQ + 2048 + h * DHd + d0 + tc];
    }
    __syncthreads();
#pragma unroll
    for (int i = 0; i < 4; ++i) {
      const int r = tr8 + i * 8;
      Vt[(size_t)(bh * DHd + d0 + r) * Ss + s0 + tc] = tile[tc][r];
    }
  }
}

// ---------------- bf16 MFMA GEMM v14: 256x256 8-phase, ks-balanced reads (8/8/4/4) --------
// Quadrants split by (m-half, k-slice): b[4][2] live all K-tile. Stage A(kt+1) in phA/phB
// (targets As[db^1], last read kt-1 phD, barrier-safe), B(kt+2) in phC (B-reads end phB).
// vmcnt(4) at phD drains A(kt+1)+B(kt), leaves B(kt+1) flying. Tail: vmcnt(0) at kt+2>=NT.
template <int EPI>
__global__ __launch_bounds__(512, 2) void gemm14(const short* __restrict__ A,
                                                 const short* __restrict__ Bt,
                                                 float* __restrict__ Cf,
                                                 short* __restrict__ Cb,
                                                 const float* __restrict__ Res,
                                                 int N, int K, int ldc) {
  __shared__ __align__(16) short As[2][2][128 * 64];  // [dbuf][half] 64 KB
  __shared__ __align__(16) short Bs[2][2][128 * 64];  // 64 KB
  const int t = threadIdx.x;
  const int w = t >> 6, l = t & 63;
  const int lq = l >> 4, lr = l & 15;
  const int wr = w >> 2, wc = w & 3;
  const int bhalf = wc >> 1, brow0 = (wc & 1) * 64;
  const int nwg = gridDim.x * gridDim.y;
  const int bid0 = blockIdx.x + blockIdx.y * gridDim.x;
  const int lgid = (bid0 & 7) * (nwg >> 3) + (bid0 >> 3);
  const int bx = lgid % gridDim.x, by = lgid / gridDim.x;
  const int row0 = by * 256, col0 = bx * 256;
  const int NT = K >> 6;

  f32x4 acc[8][4] = {};
  short8v a[4][2], b[4][2];

  auto stageA = [&](int kt, int hf) {
    const int db = kt & 1;
#pragma unroll
    for (int i = 0; i < 2; ++i) {
      const int c = t + i * 512;
      const int row = c >> 3, slot = c & 7;
      gl_lds16(A + (size_t)(row0 + hf * 128 + row) * K + kt * 64 + ((slot ^ (row & 7)) << 3),
               &As[db][hf][c * 8]);
    }
  };
  auto stageB = [&](int kt, int hf) {
    const int db = kt & 1;
#pragma unroll
    for (int i = 0; i < 2; ++i) {
      const int c = t + i * 512;
      const int row = c >> 3, slot = c & 7;
      gl_lds16(Bt + (size_t)(col0 + hf * 128 + row) * K + kt * 64 + ((slot ^ (row & 7)) << 3),
               &Bs[db][hf][c * 8]);
    }
  };
  auto rdA = [&](int db, int m, int ks) -> short8v {
    const int row = m * 16 + lr;
    return *(const short8v*)&As[db][wr][row * 64 + (((ks << 2) + lq) ^ (row & 7)) * 8];
  };
  auto rdB = [&](int db, int n, int ks) -> short8v {
    const int row = brow0 + n * 16 + lr;
    return *(const short8v*)&Bs[db][bhalf][row * 64 + (((ks << 2) + lq) ^ (row & 7)) * 8];
  };

  // prologue: A(0) + B(0) + B(1); drain A(0),B(0), leave B(1)'s 4 flying
  stageA(0, 0); stageA(0, 1); stageB(0, 0); stageB(0, 1);
  if (NT > 1) { stageB(1, 0); stageB(1, 1); }
  if (NT > 1) { asm volatile("s_waitcnt vmcnt(4)" ::: "memory"); }
  else        { asm volatile("s_waitcnt vmcnt(0)" ::: "memory"); }
  asm volatile("s_barrier" ::: "memory");

  for (int kt = 0; kt < NT; ++kt) {
    const int db = kt & 1;
    // ---- phA: read a(m0-3,ks0)+b(all,ks0); stage A0(kt+1); MFMA 16 (ks0, m-low) ----
#pragma unroll
    for (int m = 0; m < 4; ++m) a[m][0] = rdA(db, m, 0);
#pragma unroll
    for (int n = 0; n < 4; ++n) b[n][0] = rdB(db, n, 0);
    if (kt + 1 < NT) stageA(kt + 1, 0);
    __builtin_amdgcn_s_setprio(1);
#pragma unroll
    for (int m = 0; m < 4; ++m)
#pragma unroll
      for (int n = 0; n < 4; ++n) acc[m][n] = mfma16(a[m][0], b[n][0], acc[m][n]);
    __builtin_amdgcn_s_setprio(0);
    asm volatile("s_barrier" ::: "memory");
    // ---- phB: read a(m0-3,ks1)+b(all,ks1); stage A1(kt+1); MFMA 16 (ks1, m-low) ----
#pragma unroll
    for (int m = 0; m < 4; ++m) a[m][1] = rdA(db, m, 1);
#pragma unroll
    for (int n = 0; n < 4; ++n) b[n][1] = rdB(db, n, 1);
    if (kt + 1 < NT) stageA(kt + 1, 1);
    __builtin_amdgcn_s_setprio(1);
#pragma unroll
    for (int m = 0; m < 4; ++m)
#pragma unroll
      for (int n = 0; n < 4; ++n) acc[m][n] = mfma16(a[m][1], b[n][1], acc[m][n]);
    __builtin_amdgcn_s_setprio(0);
    asm volatile("s_barrier" ::: "memory");
    // ---- phC: read a(m4-7,ks0); stage B(kt+2) both; MFMA 16 (ks0, m-high) ----
#pragma unroll
    for (int m = 0; m < 4; ++m) a[m][0] = rdA(db, m + 4, 0);
    if (kt + 2 < NT) { stageB(kt + 2, 0); stageB(kt + 2, 1); }
    __builtin_amdgcn_s_setprio(1);
#pragma unroll
    for (int m = 0; m < 4; ++m)
#pragma unroll
      for (int n = 0; n < 4; ++n) acc[m + 4][n] = mfma16(a[m][0], b[n][0], acc[m + 4][n]);
    __builtin_amdgcn_s_setprio(0);
    asm volatile("s_barrier" ::: "memory");
    // ---- phD: read a(m4-7,ks1); MFMA 16 (ks1, m-high); vmcnt; barrier ----
#pragma unroll
    for (int m = 0; m < 4; ++m) a[m][1] = rdA(db, m + 4, 1);
    __builtin_amdgcn_s_setprio(1);
#pragma unroll
    for (int m = 0; m < 4; ++m)
#pragma unroll
      for (int n = 0; n < 4; ++n) acc[m + 4][n] = mfma16(a[m][1], b[n][1], acc[m + 4][n]);
    __builtin_amdgcn_s_setprio(0);
    if (kt + 2 < NT) { asm volatile("s_waitcnt vmcnt(4)" ::: "memory"); }
    else             { asm volatile("s_waitcnt vmcnt(0)" ::: "memory"); }
    asm volatile("s_barrier" ::: "memory");
  }

#pragma unroll
  for (int m = 0; m < 8; ++m) {
#pragma unroll
    for (int n = 0; n < 4; ++n) {
#pragma unroll
      for (int r = 0; r < 4; ++r) {
        const int row = row0 + wr * 128 + m * 16 + lq * 4 + r;
        const int col = col0 + wc * 64 + n * 16 + lr;
        const size_t o = (size_t)row * ldc + col;
        float v = acc[m][n][r];
        if (EPI == 0) Cb[o] = (short)f2bfu(v);
        else if (EPI == 1) Cf[o] = v + Res[o];
        else Cb[o] = (short)f2bfu(gelu_f(v));
      }
    }
  }
}

// ---------------- bf16 MFMA GEMM v11: 256x128 2-phase/K-tile, ring-3 LDS, vmcnt(6) --------
template <int EPI>
__global__ __launch_bounds__(512) void gemm11(const short* __restrict__ A,
                                              const short* __restrict__ Bt,
                                              float* __restrict__ Cf,
                                              short* __restrict__ Cb,
                                              const float* __restrict__ Res,
                                              int K, int lda, int ldb, int ldc, int nxt) {
  __shared__ __align__(16) short As[3][256 * 64];  // 96 KB ring-3
  __shared__ __align__(16) short Bs[3][128 * 64];  // 48 KB ring-3
  const int t = threadIdx.x;
  const int w = t >> 6, l = t & 63;
  const int lq = l >> 4, lr = l & 15;
  const int wr = w >> 2, wc = w & 3;
  const int nwg = gridDim.x;
  const int lgid = (blockIdx.x & 7) * (nwg >> 3) + (blockIdx.x >> 3);
  const int mt = lgid / nxt, nt_ = lgid % nxt;
  const int row0 = mt * 256, col0 = nt_ * 128;
  const int NT = K >> 6;
  f32x4 acc[8][2] = {};
  short8v a[4][2], b[2][2];

  auto stageA = [&](int kt, int hf) {
    const int s = kt % 3;
#pragma unroll
    for (int i = 0; i < 2; ++i) {
      const int c = t + i * 512;
      const int row = c >> 3, slot = c & 7;
      gl_lds16(A + (size_t)(row0 + hf * 128 + row) * lda + kt * 64 + ((slot ^ (row & 7)) << 3),
               &As[s][hf * 8192 + c * 8]);
    }
  };
  auto stageB = [&](int kt) {
    const int s = kt % 3;
#pragma unroll
    for (int i = 0; i < 2; ++i) {
      const int c = t + i * 512;
      const int row = c >> 3, slot = c & 7;
      gl_lds16(Bt + (size_t)(col0 + row) * ldb + kt * 64 + ((slot ^ (row & 7)) << 3),
               &Bs[s][c * 8]);
    }
  };
  auto rdA = [&](int s, int m, int ks) -> short8v {
    const int row = wr * 128 + m * 16 + lr;
    return *(const short8v*)&As[s][row * 64 + (((ks << 2) + lq) ^ (row & 7)) * 8];
  };
  auto rdB = [&](int s, int n, int ks) -> short8v {
    const int row = wc * 32 + n * 16 + lr;
    return *(const short8v*)&Bs[s][row * 64 + (((ks << 2) + lq) ^ (row & 7)) * 8];
  };

  stageA(0, 0); stageA(0, 1); stageB(0);
  stageA(1, 0); stageA(1, 1); stageB(1);
  asm volatile("s_waitcnt vmcnt(6)" ::: "memory");
  asm volatile("s_barrier" ::: "memory");

  for (int kt = 0; kt < NT; ++kt) {
    const int s = kt % 3;
#pragma unroll
    for (int m = 0; m < 4; ++m) { a[m][0] = rdA(s, m, 0); a[m][1] = rdA(s, m, 1); }
#pragma unroll
    for (int n = 0; n < 2; ++n) { b[n][0] = rdB(s, n, 0); b[n][1] = rdB(s, n, 1); }
    if (kt + 2 < NT) stageA(kt + 2, 0);
    __builtin_amdgcn_s_setprio(1);
#pragma unroll
    for (int m = 0; m < 4; ++m)
#pragma unroll
      for (int n = 0; n < 2; ++n) {
        acc[m][n] = mfma16(a[m][0], b[n][0], acc[m][n]);
        acc[m][n] = mfma16(a[m][1], b[n][1], acc[m][n]);
      }
    __builtin_amdgcn_s_setprio(0);
    asm volatile("s_barrier" ::: "memory");
#pragma unroll
    for (int m = 0; m < 4; ++m) { a[m][0] = rdA(s, m + 4, 0); a[m][1] = rdA(s, m + 4, 1); }
    if (kt + 2 < NT) { stageA(kt + 2, 1); stageB(kt + 2); }
    __builtin_amdgcn_s_setprio(1);
#pragma unroll
    for (int m = 0; m < 4; ++m)
#pragma unroll
      for (int n = 0; n < 2; ++n) {
        acc[m + 4][n] = mfma16(a[m][0], b[n][0], acc[m + 4][n]);
        acc[m + 4][n] = mfma16(a[m][1], b[n][1], acc[m + 4][n]);
      }
    __builtin_amdgcn_s_setprio(0);
    if (kt + 2 < NT) { asm volatile("s_waitcnt vmcnt(6)" ::: "memory"); }
    else             { asm volatile("s_waitcnt vmcnt(0)" ::: "memory"); }
    asm volatile("s_barrier" ::: "memory");
  }

#pragma unroll
  for (int m = 0; m < 8; ++m) {
#pragma unroll
    for (int n = 0; n < 2; ++n) {
#pragma unroll
      for (int r = 0; r < 4; ++r) {
        const int row = row0 + wr * 128 + m * 16 + lq * 4 + r;
        const int col = col0 + wc * 32 + n * 16 + lr;
        const size_t o = (size_t)row * ldc + col;
        float v = acc[m][n][r];
        if (EPI == 0) Cb[o] = (short)f2bfu(v);
        else if (EPI == 1) Cf[o] = v + Res[o];
        else Cb[o] = (short)f2bfu(gelu_f(v));
      }
    }
  }
}

// ---------------- bf16 MFMA GEMM v12: 128x128 2-phase/K-tile, ring-3 LDS, vmcnt(4) --------
template <int EPI>
__global__ __launch_bounds__(512) void gemm12(const short* __restrict__ A,
                                              const short* __restrict__ Bt,
                                              float* __restrict__ Cf,
                                              short* __restrict__ Cb,
                                              const float* __restrict__ Res,
                                              int K, int lda, int ldb, int ldc, int nxt) {
  __shared__ __align__(16) short As[3][128 * 64];  // 48 KB ring-3
  __shared__ __align__(16) short Bs[3][128 * 64];  // 48 KB ring-3
  const int t = threadIdx.x;
  const int w = t >> 6, l = t & 63;
  const int lq = l >> 4, lr = l & 15;
  const int wr = w >> 2, wc = w & 3;
  const int nwg = gridDim.x;
  const int lgid = (blockIdx.x & 7) * (nwg >> 3) + (blockIdx.x >> 3);
  const int mt = lgid / nxt, nt_ = lgid % nxt;
  const int row0 = mt * 128, col0 = nt_ * 128;
  const int NT = K >> 6;
  f32x4 acc[4][2] = {};
  short8v a[4][2], b[2][2];

  auto stageA = [&](int kt) {
    const int s = kt % 3;
#pragma unroll
    for (int i = 0; i < 2; ++i) {
      const int c = t + i * 512;
      const int row = c >> 3, slot = c & 7;
      gl_lds16(A + (size_t)(row0 + row) * lda + kt * 64 + ((slot ^ (row & 7)) << 3),
               &As[s][c * 8]);
    }
  };
  auto stageB = [&](int kt) {
    const int s = kt % 3;
#pragma unroll
    for (int i = 0; i < 2; ++i) {
      const int c = t + i * 512;
      const int row = c >> 3, slot = c & 7;
      gl_lds16(Bt + (size_t)(col0 + row) * ldb + kt * 64 + ((slot ^ (row & 7)) << 3),
               &Bs[s][c * 8]);
    }
  };
  auto rdA = [&](int s, int m, int ks) -> short8v {
    const int row = wr * 64 + m * 16 + lr;
    return *(const short8v*)&As[s][row * 64 + (((ks << 2) + lq) ^ (row & 7)) * 8];
  };
  auto rdB = [&](int s, int n, int ks) -> short8v {
    const int row = wc * 32 + n * 16 + lr;
    return *(const short8v*)&Bs[s][row * 64 + (((ks << 2) + lq) ^ (row & 7)) * 8];
  };

  stageA(0); stageB(0);
  stageA(1); stageB(1);
  asm volatile("s_waitcnt vmcnt(4)" ::: "memory");
  asm volatile("s_barrier" ::: "memory");

  for (int kt = 0; kt < NT; ++kt) {
    const int s = kt % 3;
#pragma unroll
    for (int m = 0; m < 4; ++m) { a[m][0] = rdA(s, m, 0); a[m][1] = rdA(s, m, 1); }
#pragma unroll
    for (int n = 0; n < 2; ++n) { b[n][0] = rdB(s, n, 0); b[n][1] = rdB(s, n, 1); }
    if (kt + 2 < NT) stageA(kt + 2);
    __builtin_amdgcn_s_setprio(1);
#pragma unroll
    for (int m = 0; m < 2; ++m)
#pragma unroll
      for (int n = 0; n < 2; ++n) {
        acc[m][n] = mfma16(a[m][0], b[n][0], acc[m][n]);
        acc[m][n] = mfma16(a[m][1], b[n][1], acc[m][n]);
      }
    __builtin_amdgcn_s_setprio(0);
    asm volatile("s_barrier" ::: "memory");
    if (kt + 2 < NT) stageB(kt + 2);
    __builtin_amdgcn_s_setprio(1);
#pragma unroll
    for (int m = 2; m < 4; ++m)
#pragma unroll
      for (int n = 0; n < 2; ++n) {
        acc[m][n] = mfma16(a[m][0], b[n][0], acc[m][n]);
        acc[m][n] = mfma16(a[m][1], b[n][1], acc[m][n]);
      }
    __builtin_amdgcn_s_setprio(0);
    if (kt + 2 < NT) { asm volatile("s_waitcnt vmcnt(4)" ::: "memory"); }
    else             { asm volatile("s_waitcnt vmcnt(0)" ::: "memory"); }
    asm volatile("s_barrier" ::: "memory");
  }

#pragma unroll
  for (int m = 0; m < 4; ++m) {
#pragma unroll
    for (int n = 0; n < 2; ++n) {
#pragma unroll
      for (int r = 0; r < 4; ++r) {
        const int row = row0 + wr * 64 + m * 16 + lq * 4 + r;
        const int col = col0 + wc * 32 + n * 16 + lr;
        const size_t o = (size_t)row * ldc + col;
        float v = acc[m][n][r];
        if (EPI == 0) Cb[o] = (short)f2bfu(v);
        else if (EPI == 1) Cf[o] = v + Res[o];
        else Cb[o] = (short)f2bfu(gelu_f(v));
      }
    }
  }
}

// ---------------- Retention v4: dbuf K/V, 1 barrier/tile, setprio, XCD-local bh ----------
__global__ __launch_bounds__(256) void ret4_kernel(const short* __restrict__ QKb,
                                                   const short* __restrict__ Vt,
                                                   float* __restrict__ Y0,
                                                   float* __restrict__ Y1) {
  __shared__ __align__(16) short Ks[2][64 * 128];
  __shared__ __align__(16) short Vs[2][128 * 64];
  const int t = threadIdx.x, w = t >> 6, l = t & 63;
  const int lq = l >> 4, lr = l & 15;
  const int u = blockIdx.x;                 // 0..511
  const int lgid = (u & 7) * 64 + (u >> 3);
  const int half = lgid >> 8;
  const int rest = lgid & 255;
  const int bh = rest >> 3, j = rest & 7;
  const int qb = half ? j : 7 - j;
  const int b = bh >> 3, h = bh & 7;
  const int q0 = qb * 128;
  const float lstep = (logf(1.f / 512.f) - logf(1.f / 32.f)) * (1.f / 7.f);
  const float gamma = 1.f - expf(logf(1.f / 32.f) + (float)h * lstep);
  const float l2g = logf(gamma) * 1.44269504f;
  const short* Qp = QKb;
  const short* Kp = QKb + 1024;

  short8v qf[2][4];
#pragma unroll
  for (int qn = 0; qn < 2; ++qn)
#pragma unroll
    for (int ks = 0; ks < 4; ++ks)
      qf[qn][ks] = *(const short8v*)(Qp + (size_t)(b * Ss + q0 + w * 32 + qn * 16 + lr) * LDQ +
                                     h * DHd + ks * 32 + lq * 8);

  float cmf[4], csr[4];
#pragma unroll
  for (int mf = 0; mf < 4; ++mf) cmf[mf] = exp2f(l2g * (float)(-16 * mf));
#pragma unroll
  for (int r = 0; r < 4; ++r) csr[r] = exp2f(l2g * (float)(63 - 4 * lq - r));

  f32x4 yacc[2][8] = {};
  const int nt = 2 * qb + 2;
  const int sb = ((lq & 1) * 2) * 16 + lr;

  auto stageKV = [&](int m0, int buf) {
#pragma unroll
    for (int i = 0; i < 4; ++i) {
      const int c = (w * 4 + i) * 64 + l;
      const int row = c >> 4, slot = c & 15;
      gl_lds16(Kp + (size_t)(b * Ss + m0 + row) * LDQ + h * DHd + ((slot ^ (row & 7)) * 8),
               &Ks[buf][(w * 4 + i) * 512]);
    }
#pragma unroll
    for (int i = 0; i < 4; ++i) {
      const int c = (w * 4 + i) * 64 + l;
      const int row = c >> 3, slot = c & 7;
      gl_lds16(Vt + (size_t)(bh * DHd + row) * Ss + m0 + ((slot ^ (row & 7)) * 8),
               &Vs[buf][(w * 4 + i) * 512]);
    }
  };

  stageKV(half * 64, 0);
  __syncthreads();
  int cur = 0;
  for (int tt = half; tt < nt; tt += 2) {
    const int m0 = tt * 64;
    if (tt + 2 < nt) stageKV((tt + 2) * 64, cur ^ 1);

    f32x4 st[4][2] = {};
    __builtin_amdgcn_s_setprio(1);
#pragma unroll
    for (int mf = 0; mf < 4; ++mf) {
      const int row = mf * 16 + lr;
#pragma unroll
      for (int ks = 0; ks < 4; ++ks) {
        short8v kf = *(const short8v*)&Ks[cur][row * 128 + (((4 * ks + lq) ^ (row & 7)) * 8)];
        st[mf][0] = mfma16(kf, qf[0][ks], st[mf][0]);
        st[mf][1] = mfma16(kf, qf[1][ks], st[mf][1]);
      }
    }
    __builtin_amdgcn_s_setprio(0);
    float rs[2];
#pragma unroll
    for (int qn = 0; qn < 2; ++qn)
      rs[qn] = exp2f(l2g * (float)(q0 + w * 32 + qn * 16 + lr - m0 - 63));
#pragma unroll
    for (int mf = 0; mf < 4; ++mf)
#pragma unroll
      for (int qn = 0; qn < 2; ++qn)
#pragma unroll
        for (int r = 0; r < 4; ++r) {
          const int qg = q0 + w * 32 + qn * 16 + lr;
          const int kvg = m0 + mf * 16 + lq * 4 + r;
          const float wgt = (qg >= kvg) ? rs[qn] * cmf[mf] * csr[r] : 0.f;
          st[mf][qn][r] *= wgt;
        }
    unsigned pk[4][2][2];
#pragma unroll
    for (int mf = 0; mf < 4; ++mf)
#pragma unroll
      for (int qn = 0; qn < 2; ++qn)
#pragma unroll
        for (int p = 0; p < 2; ++p)
          pk[mf][qn][p] = (unsigned)f2bfu(st[mf][qn][2 * p]) |
                          ((unsigned)f2bfu(st[mf][qn][2 * p + 1]) << 16);
    short8v afr[2][2];
#pragma unroll
    for (int qn = 0; qn < 2; ++qn)
#pragma unroll
      for (int ks2 = 0; ks2 < 2; ++ks2) {
        u32x4 wd;
#pragma unroll
        for (int wj = 0; wj < 4; ++wj) {
          const int src = sb + (wj >> 1) * 16;
          const unsigned v0 = __shfl(pk[2 * ks2 + 0][qn][wj & 1], src);
          const unsigned v1 = __shfl(pk[2 * ks2 + 1][qn][wj & 1], src);
          wd[wj] = (lq >= 2) ? v1 : v0;
        }
        afr[qn][ks2] = __builtin_bit_cast(short8v, wd);
      }
    __builtin_amdgcn_s_setprio(1);
#pragma unroll
    for (int nd = 0; nd < 8; ++nd) {
      const int row = nd * 16 + lr;
#pragma unroll
      for (int ks2 = 0; ks2 < 2; ++ks2) {
        short8v vf = *(const short8v*)&Vs[cur][row * 64 + (((4 * ks2 + lq) ^ (row & 7)) * 8)];
        yacc[0][nd] = mfma16(afr[0][ks2], vf, yacc[0][nd]);
        yacc[1][nd] = mfma16(afr[1][ks2], vf, yacc[1][nd]);
      }
    }
    __builtin_amdgcn_s_setprio(0);
    __syncthreads();
    cur ^= 1;
  }
  float* Y = half ? Y1 : Y0;
#pragma unroll
  for (int qn = 0; qn < 2; ++qn)
#pragma unroll
    for (int r = 0; r < 4; ++r) {
      const int q = q0 + w * 32 + qn * 16 + lq * 4 + r;
#pragma unroll
      for (int nd = 0; nd < 8; ++nd)
        Y[(size_t)(b * Ss + q) * Dd + h * DHd + nd * 16 + lr] = yacc[qn][nd][r];
    }
}

// ---------------- gate: Gb = bf16( swish(Graw) * GN(Y0+Y1) ) ----------------
__global__ __launch_bounds__(256) void gate_kernel(const float* __restrict__ Y0,
                                                   const float* __restrict__ Y1,
                                                   const short* __restrict__ Graw,
                                                   short* __restrict__ Gb,
                                                   const float* __restrict__ gs,
                                                   const float* __restrict__ gb) {
  const int lane = threadIdx.x & 63;
  const int rowh = blockIdx.x * 4 + (threadIdx.x >> 6);  // (b*S+s)*H + h
  const int h = rowh & 7;
  const int row = rowh >> 3;
  const size_t ybase = (size_t)row * Dd + (size_t)h * DHd + lane * 2;
  float2 a = *(const float2*)(Y0 + ybase);
  const float2 c = *(const float2*)(Y1 + ybase);
  a.x += c.x; a.y += c.y;
  float s = a.x + a.y, s2 = a.x * a.x + a.y * a.y;
#pragma unroll
  for (int o = 32; o > 0; o >>= 1) { s += __shfl_down(s, o); s2 += __shfl_down(s2, o); }
  s = __shfl(s, 0);
  s2 = __shfl(s2, 0);
  const float mu = s * (1.f / DHd);
  const float rstd = rsqrtf(s2 * (1.f / DHd) - mu * mu + EPSf);
  const int d = h * DHd + lane * 2;
  const float2 g = *(const float2*)(gs + d);
  const float2 bbv = *(const float2*)(gb + d);
  const float y0 = (a.x - mu) * rstd * g.x + bbv.x;
  const float y1 = (a.y - mu) * rstd * g.y + bbv.y;
  const unsigned gr = *(const unsigned*)(Graw + (size_t)row * LDQ + 3072 + h * DHd + lane * 2);
  const float gx = bfu2f((unsigned short)(gr & 0xffff));
  const float gy = bfu2f((unsigned short)(gr >> 16));
  const unsigned o01 = (unsigned)f2bfu(swish_f(gx) * y0) |
                       ((unsigned)f2bfu(swish_f(gy) * y1) << 16);
  *(unsigned*)(Gb + ybase) = o01;
}

extern "C" void kernel_launch(void* const* d_in, const int* in_sizes, int n_in,
                              void* d_out, int out_size, void* d_ws, size_t ws_size,
                              hipStream_t stream) {
  const float* X = (const float*)d_in[0];
  const float* Wq = (const float*)d_in[1];
  const float* Wk = (const float*)d_in[2];
  const float* Wv = (const float*)d_in[3];
  const float* Wg = (const float*)d_in[4];
  const float* Wo = (const float*)d_in[5];
  const float* W1 = (const float*)d_in[6];
  const float* W2 = (const float*)d_in[7];
  const float* lns = (const float*)d_in[8];
  const float* lnb = (const float*)d_in[9];
  const float* gns = (const float*)d_in[10];
  const float* gnb = (const float*)d_in[11];
  float* out = (float*)d_out;

  char* W = (char*)d_ws;
  const size_t MB = 1u << 20;
  float* Abuf  = (float*)(W);             // 16 MB fp32
  short* Xnb   = (short*)(W + 16 * MB);   // 8 MB bf16
  short* QKVGb = (short*)(W + 24 * MB);   // 32 MB bf16 [4096][4096]; Hb aliases first 16 MB
  float* Y0    = (float*)(W + 56 * MB);   // 16 MB fp32
  float* Y1    = (float*)(W + 72 * MB);   // 16 MB fp32
  short* Vtb   = (short*)(W + 88 * MB);   // 8 MB bf16
  short* Gb    = (short*)(W + 96 * MB);   // 8 MB bf16
  short* Wqkvgt= (short*)(W + 104 * MB);  // 8 MB
  short* Wot   = (short*)(W + 112 * MB);  // 2 MB
  short* W1t   = (short*)(W + 114 * MB);  // 4 MB
  short* W2t   = (short*)(W + 118 * MB);  // 4 MB
  float* ct    = (float*)(W + 122 * MB);  // 256 KB
  float* st    = ct + Ss * 64;            // 256 KB
  short* Hb = QKVGb;  // FFN hidden 4096x2048 bf16 (16 MB)

  rope_table_kernel<<<(Ss * 64) / 256, 256, 0, stream>>>(ct, st);

  for (int l = 0; l < LAYERS; ++l) {
    const size_t DD = (size_t)Dd * Dd;
    const float* Acur = (l == 0) ? X : Abuf;  // residual stream input for this layer
    wtrans_all_kernel<<<9216, 256, 0, stream>>>(Wq + l * DD, Wk + l * DD, Wv + l * DD,
                                                Wg + l * DD, Wo + l * DD,
                                                W1 + (size_t)l * Dd * Ff,
                                                W2 + (size_t)l * Ff * Dd,
                                                Wqkvgt, Wot, W1t, W2t);
    // Xn = LN(A) -> bf16
    ln_bf16_kernel<<<Mm, 256, 0, stream>>>(Acur, Xnb, lns, lnb);
    // fused QKVG projection -> combined bf16 buffer (ks-balanced 8-phase 256x256)
    gemm14<0><<<dim3(16, 16), 512, 0, stream>>>(Xnb, Wqkvgt, nullptr, QKVGb,
                                                nullptr, 4096, Dd, LDQ);
    // merged RoPE (in-place Q,K) + V transpose
    rvt_kernel<<<12288, 256, 0, stream>>>(QKVGb, Vtb, ct, st);
    // retention -> partial Y0,Y1 (fp32)
    ret4_kernel<<<512, 256, 0, stream>>>(QKVGb, Vtb, Y0, Y1);
    // gate: Gb = swish(Graw) * GN(Y0+Y1)
    gate_kernel<<<(Mm * Hh) / 4, 256, 0, stream>>>(Y0, Y1, QKVGb, Gb,
                                                   gns + (size_t)l * Dd, gnb + (size_t)l * Dd);
    // A = (Gb @ Wo) + Acur : 128x128 ring-3 2-phase (writes Abuf)
    gemm12<1><<<256, 512, 0, stream>>>(Gb, Wot, Abuf, nullptr, Acur,
                                       Dd, Dd, Dd, Dd, 8);
    // FFN
    ln_bf16_kernel<<<Mm, 256, 0, stream>>>(Abuf, Xnb, lns, lnb);
    gemm11<2><<<256, 512, 0, stream>>>(Xnb, W1t, nullptr, Hb, nullptr,
                                       Dd, Dd, Dd, Ff, 16);
    float* dst = (l == LAYERS - 1) ? out : Abuf;
    gemm12<1><<<256, 512, 0, stream>>>(Hb, W2t, dst, nullptr, Abuf,
                                       Ff, Ff, Ff, Dd, 8);
  }
}

// Round 16
// 721.945 us; speedup vs baseline: 1.6013x; 1.0343x over previous
//
#include <hip/hip_runtime.h>
#include <hip/hip_bf16.h>
#include <cmath>

#define LAYERS 4
#define Bb 4
#define Ss 1024
#define Dd 1024
#define Ff 2048
#define Hh 8
#define DHd 128
#define Mm (Bb * Ss)   // 4096 rows
#define EPSf 1e-5f
#define LDQ 4096       // combined QKVG row stride

typedef __attribute__((ext_vector_type(8))) short short8v;
typedef __attribute__((ext_vector_type(4))) float f32x4;
typedef __attribute__((ext_vector_type(4))) unsigned int u32x4;

__device__ __forceinline__ float swish_f(float x) { return x / (1.f + expf(-x)); }
__device__ __forceinline__ float gelu_f(float x) {
  return 0.5f * x * (1.f + tanhf(0.7978845608028654f * (x + 0.044715f * x * x * x)));
}
__device__ __forceinline__ unsigned short f2bfu(float f) {
  __hip_bfloat16 h = __float2bfloat16(f);
  return __builtin_bit_cast(unsigned short, h);
}
__device__ __forceinline__ float bfu2f(unsigned short u) {
  unsigned v = ((unsigned)u) << 16;
  return __builtin_bit_cast(float, v);
}
__device__ __forceinline__ void gl_lds16(const void* g, void* l) {
  __builtin_amdgcn_global_load_lds((__attribute__((address_space(1))) void*)g,
                                   (__attribute__((address_space(3))) void*)l, 16, 0, 0);
}
__device__ __forceinline__ f32x4 mfma16(short8v a, short8v b, f32x4 c) {
  return __builtin_amdgcn_mfma_f32_16x16x32_bf16(a, b, c, 0, 0, 0);
}

// ---------------- LayerNorm fp32 -> bf16 ----------------
__global__ __launch_bounds__(256) void ln_bf16_kernel(const float* __restrict__ x,
                                                      short* __restrict__ outb,
                                                      const float* __restrict__ sc,
                                                      const float* __restrict__ bi) {
  const int row = blockIdx.x;
  const int t = threadIdx.x;
  const float4 v = *(const float4*)(x + (size_t)row * Dd + t * 4);
  float s = v.x + v.y + v.z + v.w;
  float s2 = v.x * v.x + v.y * v.y + v.z * v.z + v.w * v.w;
#pragma unroll
  for (int o = 32; o > 0; o >>= 1) { s += __shfl_down(s, o); s2 += __shfl_down(s2, o); }
  __shared__ float ps[4], ps2[4];
  if ((t & 63) == 0) { ps[t >> 6] = s; ps2[t >> 6] = s2; }
  __syncthreads();
  s = ps[0] + ps[1] + ps[2] + ps[3];
  s2 = ps2[0] + ps2[1] + ps2[2] + ps2[3];
  const float mu = s * (1.f / Dd);
  const float var = s2 * (1.f / Dd) - mu * mu;
  const float rstd = rsqrtf(var + EPSf);
  const float4 g = *(const float4*)(sc + t * 4);
  const float4 b = *(const float4*)(bi + t * 4);
  const float o0 = (v.x - mu) * rstd * g.x + b.x;
  const float o1 = (v.y - mu) * rstd * g.y + b.y;
  const float o2 = (v.z - mu) * rstd * g.z + b.z;
  const float o3 = (v.w - mu) * rstd * g.w + b.w;
  unsigned p0 = (unsigned)f2bfu(o0) | ((unsigned)f2bfu(o1) << 16);
  unsigned p1 = (unsigned)f2bfu(o2) | ((unsigned)f2bfu(o3) << 16);
  uint2 pk; pk.x = p0; pk.y = p1;
  *(uint2*)(outb + (size_t)row * Dd + t * 4) = pk;
}

// ---------------- RoPE tables ----------------
__global__ void rope_table_kernel(float* __restrict__ ct, float* __restrict__ st) {
  const int i = blockIdx.x * 256 + threadIdx.x;  // < Ss*64
  const int s = i >> 6, f = i & 63;
  const float inv = powf(10000.f, -(float)f / 64.f);
  const float a = (float)s * inv;
  ct[i] = cosf(a);
  st[i] = sinf(a);
}

// ---------------- merged weight transpose: one dispatch per layer (9216 blocks) ----------
__global__ __launch_bounds__(256) void wtrans_all_kernel(
    const float* __restrict__ Wq, const float* __restrict__ Wk,
    const float* __restrict__ Wv, const float* __restrict__ Wg,
    const float* __restrict__ Wo, const float* __restrict__ W1,
    const float* __restrict__ W2,
    short* __restrict__ Wqkvgt, short* __restrict__ Wot,
    short* __restrict__ W1t, short* __restrict__ W2t) {
  __shared__ float tile[32][33];
  const int t = threadIdx.x;
  const int tc = t & 31, tr8 = t >> 5;
  const int blk = blockIdx.x;
  const float* src; short* dst; int K, N, n0, k0, nl;
  if (blk < 4096) {
    const int bx = blk & 127, ky = blk >> 7;
    n0 = bx * 32; k0 = ky * 32;
    const int which = n0 >> 10;
    src = (which == 0) ? Wq : (which == 1) ? Wk : (which == 2) ? Wv : Wg;
    nl = n0 & 1023; N = 1024; K = 1024; dst = Wqkvgt;
  } else if (blk < 5120) {
    const int b2 = blk - 4096;
    n0 = (b2 & 31) * 32; k0 = (b2 >> 5) * 32; nl = n0;
    src = Wo; N = 1024; K = 1024; dst = Wot;
  } else if (blk < 7168) {
    const int b2 = blk - 5120;
    n0 = (b2 & 63) * 32; k0 = (b2 >> 6) * 32; nl = n0;
    src = W1; N = 2048; K = 1024; dst = W1t;
  } else {
    const int b2 = blk - 7168;
    n0 = (b2 & 31) * 32; k0 = (b2 >> 5) * 32; nl = n0;
    src = W2; N = 1024; K = 2048; dst = W2t;
  }
#pragma unroll
  for (int i = 0; i < 4; ++i) {
    const int r = tr8 + i * 8;
    tile[r][tc] = src[(size_t)(k0 + r) * N + nl + tc];
  }
  __syncthreads();
#pragma unroll
  for (int i = 0; i < 4; ++i) {
    const int r = tr8 + i * 8;
    dst[(size_t)(n0 + r) * K + k0 + tc] = (short)f2bfu(tile[tc][r]);
  }
}

// ---------------- merged RoPE (in-place Q,K) + V transpose: 12288 blocks -----------------
__global__ __launch_bounds__(256) void rvt_kernel(short* __restrict__ QKVGb,
                                                  short* __restrict__ Vt,
                                                  const float* __restrict__ ct,
                                                  const float* __restrict__ st) {
  __shared__ short tile[32][33];
  const int blk = blockIdx.x, t = threadIdx.x;
  if (blk < 8192) {
    const int idx = blk * 256 + t;
    const int f = idx & 63;
    const int h = (idx >> 6) & 7;
    const int r = idx >> 9;            // b*S+s
    const int s = r & (Ss - 1);
    const float c = ct[(s << 6) + f], sn = st[(s << 6) + f];
    const size_t qo = (size_t)r * LDQ + h * DHd + 2 * f;
    const unsigned qp = *(const unsigned*)(QKVGb + qo);
    const unsigned kp = *(const unsigned*)(QKVGb + qo + 1024);
    const float qx = bfu2f((unsigned short)(qp & 0xffff)), qy = bfu2f((unsigned short)(qp >> 16));
    const float kx = bfu2f((unsigned short)(kp & 0xffff)), ky = bfu2f((unsigned short)(kp >> 16));
    const unsigned qn = (unsigned)f2bfu(qx * c - qy * sn) |
                        ((unsigned)f2bfu(qx * sn + qy * c) << 16);
    const unsigned kn = (unsigned)f2bfu(kx * c + ky * sn) |
                        ((unsigned)f2bfu(-kx * sn + ky * c) << 16);
    *(unsigned*)(QKVGb + qo) = qn;
    *(unsigned*)(QKVGb + qo + 1024) = kn;
  } else {
    const int vb = blk - 8192;
    const int s0 = (vb & 31) * 32, d0 = ((vb >> 5) & 3) * 32, bh = vb >> 7;
    const int bb = bh >> 3, h = bh & 7;
    const int tc = t & 31, tr8 = t >> 5;
#pragma unroll
    for (int i = 0; i < 4; ++i) {
      const int r = tr8 + i * 8;
      tile[r][tc] = QKVGb[(size_t)(bb * Ss + s0 + r) * LDQ + 2048 + h * DHd + d0 + tc];
    }
    __syncthreads();
#pragma unroll
    for (int i = 0; i < 4; ++i) {
      const int r = tr8 + i * 8;
      Vt[(size_t)(bh * DHd + d0 + r) * Ss + s0 + tc] = tile[tc][r];
    }
  }
}

// ---------------- bf16 MFMA GEMM v14b: 256x256, m201 dual-barrier phases ------------------
// Per phase: {ds_reads; stage; s_barrier; lgkmcnt(0)+sched_barrier; setprio MFMA; s_barrier}
// Quadrants by (m-half, k-slice). Stage A(kt+1) phA/phB, B(kt+2) phC. vmcnt(4) at phD only.
template <int EPI>
__global__ __launch_bounds__(512, 2) void gemm14(const short* __restrict__ A,
                                                 const short* __restrict__ Bt,
                                                 float* __restrict__ Cf,
                                                 short* __restrict__ Cb,
                                                 const float* __restrict__ Res,
                                                 int N, int K, int ldc) {
  __shared__ __align__(16) short As[2][2][128 * 64];  // [dbuf][half] 64 KB
  __shared__ __align__(16) short Bs[2][2][128 * 64];  // 64 KB
  const int t = threadIdx.x;
  const int w = t >> 6, l = t & 63;
  const int lq = l >> 4, lr = l & 15;
  const int wr = w >> 2, wc = w & 3;
  const int bhalf = wc >> 1, brow0 = (wc & 1) * 64;
  const int nwg = gridDim.x * gridDim.y;
  const int bid0 = blockIdx.x + blockIdx.y * gridDim.x;
  const int lgid = (bid0 & 7) * (nwg >> 3) + (bid0 >> 3);
  const int bx = lgid % gridDim.x, by = lgid / gridDim.x;
  const int row0 = by * 256, col0 = bx * 256;
  const int NT = K >> 6;

  f32x4 acc[8][4] = {};
  short8v a[4][2], b[4][2];

  auto stageA = [&](int kt, int hf) {
    const int db = kt & 1;
#pragma unroll
    for (int i = 0; i < 2; ++i) {
      const int c = t + i * 512;
      const int row = c >> 3, slot = c & 7;
      gl_lds16(A + (size_t)(row0 + hf * 128 + row) * K + kt * 64 + ((slot ^ (row & 7)) << 3),
               &As[db][hf][c * 8]);
    }
  };
  auto stageB = [&](int kt, int hf) {
    const int db = kt & 1;
#pragma unroll
    for (int i = 0; i < 2; ++i) {
      const int c = t + i * 512;
      const int row = c >> 3, slot = c & 7;
      gl_lds16(Bt + (size_t)(col0 + hf * 128 + row) * K + kt * 64 + ((slot ^ (row & 7)) << 3),
               &Bs[db][hf][c * 8]);
    }
  };
  auto rdA = [&](int db, int m, int ks) -> short8v {
    const int row = m * 16 + lr;
    return *(const short8v*)&As[db][wr][row * 64 + (((ks << 2) + lq) ^ (row & 7)) * 8];
  };
  auto rdB = [&](int db, int n, int ks) -> short8v {
    const int row = brow0 + n * 16 + lr;
    return *(const short8v*)&Bs[db][bhalf][row * 64 + (((ks << 2) + lq) ^ (row & 7)) * 8];
  };

  stageA(0, 0); stageA(0, 1); stageB(0, 0); stageB(0, 1);
  if (NT > 1) { stageB(1, 0); stageB(1, 1); }
  if (NT > 1) { asm volatile("s_waitcnt vmcnt(4)" ::: "memory"); }
  else        { asm volatile("s_waitcnt vmcnt(0)" ::: "memory"); }
  asm volatile("s_barrier" ::: "memory");

  for (int kt = 0; kt < NT; ++kt) {
    const int db = kt & 1;
    // ---- phA ----
#pragma unroll
    for (int m = 0; m < 4; ++m) a[m][0] = rdA(db, m, 0);
#pragma unroll
    for (int n = 0; n < 4; ++n) b[n][0] = rdB(db, n, 0);
    if (kt + 1 < NT) stageA(kt + 1, 0);
    asm volatile("s_barrier" ::: "memory");
    asm volatile("s_waitcnt lgkmcnt(0)" ::: "memory");
    __builtin_amdgcn_sched_barrier(0);
    __builtin_amdgcn_s_setprio(1);
#pragma unroll
    for (int m = 0; m < 4; ++m)
#pragma unroll
      for (int n = 0; n < 4; ++n) acc[m][n] = mfma16(a[m][0], b[n][0], acc[m][n]);
    __builtin_amdgcn_s_setprio(0);
    asm volatile("s_barrier" ::: "memory");
    // ---- phB ----
#pragma unroll
    for (int m = 0; m < 4; ++m) a[m][1] = rdA(db, m, 1);
#pragma unroll
    for (int n = 0; n < 4; ++n) b[n][1] = rdB(db, n, 1);
    if (kt + 1 < NT) stageA(kt + 1, 1);
    asm volatile("s_barrier" ::: "memory");
    asm volatile("s_waitcnt lgkmcnt(0)" ::: "memory");
    __builtin_amdgcn_sched_barrier(0);
    __builtin_amdgcn_s_setprio(1);
#pragma unroll
    for (int m = 0; m < 4; ++m)
#pragma unroll
      for (int n = 0; n < 4; ++n) acc[m][n] = mfma16(a[m][1], b[n][1], acc[m][n]);
    __builtin_amdgcn_s_setprio(0);
    asm volatile("s_barrier" ::: "memory");
    // ---- phC ----
#pragma unroll
    for (int m = 0; m < 4; ++m) a[m][0] = rdA(db, m + 4, 0);
    if (kt + 2 < NT) { stageB(kt + 2, 0); stageB(kt + 2, 1); }
    asm volatile("s_barrier" ::: "memory");
    asm volatile("s_waitcnt lgkmcnt(0)" ::: "memory");
    __builtin_amdgcn_sched_barrier(0);
    __builtin_amdgcn_s_setprio(1);
#pragma unroll
    for (int m = 0; m < 4; ++m)
#pragma unroll
      for (int n = 0; n < 4; ++n) acc[m + 4][n] = mfma16(a[m][0], b[n][0], acc[m + 4][n]);
    __builtin_amdgcn_s_setprio(0);
    asm volatile("s_barrier" ::: "memory");
    // ---- phD ----
#pragma unroll
    for (int m = 0; m < 4; ++m) a[m][1] = rdA(db, m + 4, 1);
    asm volatile("s_barrier" ::: "memory");
    asm volatile("s_waitcnt lgkmcnt(0)" ::: "memory");
    __builtin_amdgcn_sched_barrier(0);
    __builtin_amdgcn_s_setprio(1);
#pragma unroll
    for (int m = 0; m < 4; ++m)
#pragma unroll
      for (int n = 0; n < 4; ++n) acc[m + 4][n] = mfma16(a[m][1], b[n][1], acc[m + 4][n]);
    __builtin_amdgcn_s_setprio(0);
    if (kt + 2 < NT) { asm volatile("s_waitcnt vmcnt(4)" ::: "memory"); }
    else             { asm volatile("s_waitcnt vmcnt(0)" ::: "memory"); }
    asm volatile("s_barrier" ::: "memory");
  }

#pragma unroll
  for (int m = 0; m < 8; ++m) {
#pragma unroll
    for (int n = 0; n < 4; ++n) {
#pragma unroll
      for (int r = 0; r < 4; ++r) {
        const int row = row0 + wr * 128 + m * 16 + lq * 4 + r;
        const int col = col0 + wc * 64 + n * 16 + lr;
        const size_t o = (size_t)row * ldc + col;
        float v = acc[m][n][r];
        if (EPI == 0) Cb[o] = (short)f2bfu(v);
        else if (EPI == 1) Cf[o] = v + Res[o];
        else Cb[o] = (short)f2bfu(gelu_f(v));
      }
    }
  }
}

// ---------------- bf16 MFMA GEMM v11: 256x128 2-phase/K-tile, ring-3 LDS, vmcnt(6) --------
template <int EPI>
__global__ __launch_bounds__(512) void gemm11(const short* __restrict__ A,
                                              const short* __restrict__ Bt,
                                              float* __restrict__ Cf,
                                              short* __restrict__ Cb,
                                              const float* __restrict__ Res,
                                              int K, int lda, int ldb, int ldc, int nxt) {
  __shared__ __align__(16) short As[3][256 * 64];  // 96 KB ring-3
  __shared__ __align__(16) short Bs[3][128 * 64];  // 48 KB ring-3
  const int t = threadIdx.x;
  const int w = t >> 6, l = t & 63;
  const int lq = l >> 4, lr = l & 15;
  const int wr = w >> 2, wc = w & 3;
  const int nwg = gridDim.x;
  const int lgid = (blockIdx.x & 7) * (nwg >> 3) + (blockIdx.x >> 3);
  const int mt = lgid / nxt, nt_ = lgid % nxt;
  const int row0 = mt * 256, col0 = nt_ * 128;
  const int NT = K >> 6;
  f32x4 acc[8][2] = {};
  short8v a[4][2], b[2][2];

  auto stageA = [&](int kt, int hf) {
    const int s = kt % 3;
#pragma unroll
    for (int i = 0; i < 2; ++i) {
      const int c = t + i * 512;
      const int row = c >> 3, slot = c & 7;
      gl_lds16(A + (size_t)(row0 + hf * 128 + row) * lda + kt * 64 + ((slot ^ (row & 7)) << 3),
               &As[s][hf * 8192 + c * 8]);
    }
  };
  auto stageB = [&](int kt) {
    const int s = kt % 3;
#pragma unroll
    for (int i = 0; i < 2; ++i) {
      const int c = t + i * 512;
      const int row = c >> 3, slot = c & 7;
      gl_lds16(Bt + (size_t)(col0 + row) * ldb + kt * 64 + ((slot ^ (row & 7)) << 3),
               &Bs[s][c * 8]);
    }
  };
  auto rdA = [&](int s, int m, int ks) -> short8v {
    const int row = wr * 128 + m * 16 + lr;
    return *(const short8v*)&As[s][row * 64 + (((ks << 2) + lq) ^ (row & 7)) * 8];
  };
  auto rdB = [&](int s, int n, int ks) -> short8v {
    const int row = wc * 32 + n * 16 + lr;
    return *(const short8v*)&Bs[s][row * 64 + (((ks << 2) + lq) ^ (row & 7)) * 8];
  };

  stageA(0, 0); stageA(0, 1); stageB(0);
  stageA(1, 0); stageA(1, 1); stageB(1);
  asm volatile("s_waitcnt vmcnt(6)" ::: "memory");
  asm volatile("s_barrier" ::: "memory");

  for (int kt = 0; kt < NT; ++kt) {
    const int s = kt % 3;
#pragma unroll
    for (int m = 0; m < 4; ++m) { a[m][0] = rdA(s, m, 0); a[m][1] = rdA(s, m, 1); }
#pragma unroll
    for (int n = 0; n < 2; ++n) { b[n][0] = rdB(s, n, 0); b[n][1] = rdB(s, n, 1); }
    if (kt + 2 < NT) stageA(kt + 2, 0);
    __builtin_amdgcn_s_setprio(1);
#pragma unroll
    for (int m = 0; m < 4; ++m)
#pragma unroll
      for (int n = 0; n < 2; ++n) {
        acc[m][n] = mfma16(a[m][0], b[n][0], acc[m][n]);
        acc[m][n] = mfma16(a[m][1], b[n][1], acc[m][n]);
      }
    __builtin_amdgcn_s_setprio(0);
    asm volatile("s_barrier" ::: "memory");
#pragma unroll
    for (int m = 0; m < 4; ++m) { a[m][0] = rdA(s, m + 4, 0); a[m][1] = rdA(s, m + 4, 1); }
    if (kt + 2 < NT) { stageA(kt + 2, 1); stageB(kt + 2); }
    __builtin_amdgcn_s_setprio(1);
#pragma unroll
    for (int m = 0; m < 4; ++m)
#pragma unroll
      for (int n = 0; n < 2; ++n) {
        acc[m + 4][n] = mfma16(a[m][0], b[n][0], acc[m + 4][n]);
        acc[m + 4][n] = mfma16(a[m][1], b[n][1], acc[m + 4][n]);
      }
    __builtin_amdgcn_s_setprio(0);
    if (kt + 2 < NT) { asm volatile("s_waitcnt vmcnt(6)" ::: "memory"); }
    else             { asm volatile("s_waitcnt vmcnt(0)" ::: "memory"); }
    asm volatile("s_barrier" ::: "memory");
  }

#pragma unroll
  for (int m = 0; m < 8; ++m) {
#pragma unroll
    for (int n = 0; n < 2; ++n) {
#pragma unroll
      for (int r = 0; r < 4; ++r) {
        const int row = row0 + wr * 128 + m * 16 + lq * 4 + r;
        const int col = col0 + wc * 32 + n * 16 + lr;
        const size_t o = (size_t)row * ldc + col;
        float v = acc[m][n][r];
        if (EPI == 0) Cb[o] = (short)f2bfu(v);
        else if (EPI == 1) Cf[o] = v + Res[o];
        else Cb[o] = (short)f2bfu(gelu_f(v));
      }
    }
  }
}

// ---------------- bf16 MFMA GEMM v12: 128x128 2-phase/K-tile, ring-3 LDS, vmcnt(4) --------
template <int EPI>
__global__ __launch_bounds__(512) void gemm12(const short* __restrict__ A,
                                              const short* __restrict__ Bt,
                                              float* __restrict__ Cf,
                                              short* __restrict__ Cb,
                                              const float* __restrict__ Res,
                                              int K, int lda, int ldb, int ldc, int nxt) {
  __shared__ __align__(16) short As[3][128 * 64];  // 48 KB ring-3
  __shared__ __align__(16) short Bs[3][128 * 64];  // 48 KB ring-3
  const int t = threadIdx.x;
  const int w = t >> 6, l = t & 63;
  const int lq = l >> 4, lr = l & 15;
  const int wr = w >> 2, wc = w & 3;
  const int nwg = gridDim.x;
  const int lgid = (blockIdx.x & 7) * (nwg >> 3) + (blockIdx.x >> 3);
  const int mt = lgid / nxt, nt_ = lgid % nxt;
  const int row0 = mt * 128, col0 = nt_ * 128;
  const int NT = K >> 6;
  f32x4 acc[4][2] = {};
  short8v a[4][2], b[2][2];

  auto stageA = [&](int kt) {
    const int s = kt % 3;
#pragma unroll
    for (int i = 0; i < 2; ++i) {
      const int c = t + i * 512;
      const int row = c >> 3, slot = c & 7;
      gl_lds16(A + (size_t)(row0 + row) * lda + kt * 64 + ((slot ^ (row & 7)) << 3),
               &As[s][c * 8]);
    }
  };
  auto stageB = [&](int kt) {
    const int s = kt % 3;
#pragma unroll
    for (int i = 0; i < 2; ++i) {
      const int c = t + i * 512;
      const int row = c >> 3, slot = c & 7;
      gl_lds16(Bt + (size_t)(col0 + row) * ldb + kt * 64 + ((slot ^ (row & 7)) << 3),
               &Bs[s][c * 8]);
    }
  };
  auto rdA = [&](int s, int m, int ks) -> short8v {
    const int row = wr * 64 + m * 16 + lr;
    return *(const short8v*)&As[s][row * 64 + (((ks << 2) + lq) ^ (row & 7)) * 8];
  };
  auto rdB = [&](int s, int n, int ks) -> short8v {
    const int row = wc * 32 + n * 16 + lr;
    return *(const short8v*)&Bs[s][row * 64 + (((ks << 2) + lq) ^ (row & 7)) * 8];
  };

  stageA(0); stageB(0);
  stageA(1); stageB(1);
  asm volatile("s_waitcnt vmcnt(4)" ::: "memory");
  asm volatile("s_barrier" ::: "memory");

  for (int kt = 0; kt < NT; ++kt) {
    const int s = kt % 3;
#pragma unroll
    for (int m = 0; m < 4; ++m) { a[m][0] = rdA(s, m, 0); a[m][1] = rdA(s, m, 1); }
#pragma unroll
    for (int n = 0; n < 2; ++n) { b[n][0] = rdB(s, n, 0); b[n][1] = rdB(s, n, 1); }
    if (kt + 2 < NT) stageA(kt + 2);
    __builtin_amdgcn_s_setprio(1);
#pragma unroll
    for (int m = 0; m < 2; ++m)
#pragma unroll
      for (int n = 0; n < 2; ++n) {
        acc[m][n] = mfma16(a[m][0], b[n][0], acc[m][n]);
        acc[m][n] = mfma16(a[m][1], b[n][1], acc[m][n]);
      }
    __builtin_amdgcn_s_setprio(0);
    asm volatile("s_barrier" ::: "memory");
    if (kt + 2 < NT) stageB(kt + 2);
    __builtin_amdgcn_s_setprio(1);
#pragma unroll
    for (int m = 2; m < 4; ++m)
#pragma unroll
      for (int n = 0; n < 2; ++n) {
        acc[m][n] = mfma16(a[m][0], b[n][0], acc[m][n]);
        acc[m][n] = mfma16(a[m][1], b[n][1], acc[m][n]);
      }
    __builtin_amdgcn_s_setprio(0);
    if (kt + 2 < NT) { asm volatile("s_waitcnt vmcnt(4)" ::: "memory"); }
    else             { asm volatile("s_waitcnt vmcnt(0)" ::: "memory"); }
    asm volatile("s_barrier" ::: "memory");
  }

#pragma unroll
  for (int m = 0; m < 4; ++m) {
#pragma unroll
    for (int n = 0; n < 2; ++n) {
#pragma unroll
      for (int r = 0; r < 4; ++r) {
        const int row = row0 + wr * 64 + m * 16 + lq * 4 + r;
        const int col = col0 + wc * 32 + n * 16 + lr;
        const size_t o = (size_t)row * ldc + col;
        float v = acc[m][n][r];
        if (EPI == 0) Cb[o] = (short)f2bfu(v);
        else if (EPI == 1) Cf[o] = v + Res[o];
        else Cb[o] = (short)f2bfu(gelu_f(v));
      }
    }
  }
}

// ---------------- Retention v5: fused GN+gate, paired q-blocks (qb,15-qb), QBLK=64 --------
// 256 blocks (1/CU), 256 threads (4 waves, wave owns 16 q-rows). nt = 17 tiles balanced.
// Writes Gb = bf16(swish(G) * GN(Y)) directly; no Y0/Y1, no gate kernel.
__global__ __launch_bounds__(256) void ret5_kernel(const short* __restrict__ QKVGb,
                                                   const short* __restrict__ Vt,
                                                   short* __restrict__ Gb,
                                                   const float* __restrict__ gs,
                                                   const float* __restrict__ gb) {
  __shared__ __align__(16) short Ks[2][64 * 128];
  __shared__ __align__(16) short Vs[2][128 * 64];
  const int t = threadIdx.x, w = t >> 6, l = t & 63;
  const int lq = l >> 4, lr = l & 15;
  const int u = blockIdx.x;                     // 0..255
  const int lgid = (u & 7) * 32 + (u >> 3);     // XCD-contiguous
  const int bh = lgid >> 3, pr = lgid & 7;
  const int b = bh >> 3, h = bh & 7;
  const float lstep = (logf(1.f / 512.f) - logf(1.f / 32.f)) * (1.f / 7.f);
  const float gamma = 1.f - expf(logf(1.f / 32.f) + (float)h * lstep);
  const float l2g = logf(gamma) * 1.44269504f;
  const short* Qp = QKVGb;
  const short* Kp = QKVGb + 1024;

  float cmf[4], csr[4];
#pragma unroll
  for (int mf = 0; mf < 4; ++mf) cmf[mf] = exp2f(l2g * (float)(-16 * mf));
#pragma unroll
  for (int r = 0; r < 4; ++r) csr[r] = exp2f(l2g * (float)(63 - 4 * lq - r));
  float gsv[8], gbv[8];
#pragma unroll
  for (int nd = 0; nd < 8; ++nd) {
    gsv[nd] = gs[h * DHd + nd * 16 + lr];
    gbv[nd] = gb[h * DHd + nd * 16 + lr];
  }
  const int sb = ((lq & 1) * 2) * 16 + lr;

  auto stageKV = [&](int m0, int buf) {
#pragma unroll
    for (int i = 0; i < 4; ++i) {
      const int c = (w * 4 + i) * 64 + l;
      const int row = c >> 4, slot = c & 15;
      gl_lds16(Kp + (size_t)(b * Ss + m0 + row) * LDQ + h * DHd + ((slot ^ (row & 7)) * 8),
               &Ks[buf][(w * 4 + i) * 512]);
    }
#pragma unroll
    for (int i = 0; i < 4; ++i) {
      const int c = (w * 4 + i) * 64 + l;
      const int row = c >> 3, slot = c & 7;
      gl_lds16(Vt + (size_t)(bh * DHd + row) * Ss + m0 + ((slot ^ (row & 7)) * 8),
               &Vs[buf][(w * 4 + i) * 512]);
    }
  };

  for (int pass = 0; pass < 2; ++pass) {
    const int qb = pass ? (15 - pr) : pr;
    const int q0 = qb * 64;
    const int nt = qb + 1;
    short8v qf[4];
#pragma unroll
    for (int ks = 0; ks < 4; ++ks)
      qf[ks] = *(const short8v*)(Qp + (size_t)(b * Ss + q0 + w * 16 + lr) * LDQ +
                                 h * DHd + ks * 32 + lq * 8);
    f32x4 yacc[8] = {};
    stageKV(0, 0);
    __syncthreads();
    int cur = 0;
    for (int tt = 0; tt < nt; ++tt) {
      const int m0 = tt * 64;
      if (tt + 1 < nt) stageKV((tt + 1) * 64, cur ^ 1);

      f32x4 st[4] = {};
      __builtin_amdgcn_s_setprio(1);
#pragma unroll
      for (int mf = 0; mf < 4; ++mf) {
        const int row = mf * 16 + lr;
#pragma unroll
        for (int ks = 0; ks < 4; ++ks) {
          short8v kf = *(const short8v*)&Ks[cur][row * 128 + (((4 * ks + lq) ^ (row & 7)) * 8)];
          st[mf] = mfma16(kf, qf[ks], st[mf]);
        }
      }
      __builtin_amdgcn_s_setprio(0);
      const int qg = q0 + w * 16 + lr;
      const float rs = exp2f(l2g * (float)(qg - m0 - 63));
#pragma unroll
      for (int mf = 0; mf < 4; ++mf)
#pragma unroll
        for (int r = 0; r < 4; ++r) {
          const int kvg = m0 + mf * 16 + lq * 4 + r;
          const float wgt = (qg >= kvg) ? rs * cmf[mf] * csr[r] : 0.f;
          st[mf][r] *= wgt;
        }
      unsigned pk[4][2];
#pragma unroll
      for (int mf = 0; mf < 4; ++mf)
#pragma unroll
        for (int p = 0; p < 2; ++p)
          pk[mf][p] = (unsigned)f2bfu(st[mf][2 * p]) |
                      ((unsigned)f2bfu(st[mf][2 * p + 1]) << 16);
      short8v afr[2];
#pragma unroll
      for (int ks2 = 0; ks2 < 2; ++ks2) {
        u32x4 wd;
#pragma unroll
        for (int wj = 0; wj < 4; ++wj) {
          const int src = sb + (wj >> 1) * 16;
          const unsigned v0 = __shfl(pk[2 * ks2 + 0][wj & 1], src);
          const unsigned v1 = __shfl(pk[2 * ks2 + 1][wj & 1], src);
          wd[wj] = (lq >= 2) ? v1 : v0;
        }
        afr[ks2] = __builtin_bit_cast(short8v, wd);
      }
      __builtin_amdgcn_s_setprio(1);
#pragma unroll
      for (int nd = 0; nd < 8; ++nd) {
        const int row = nd * 16 + lr;
#pragma unroll
        for (int ks2 = 0; ks2 < 2; ++ks2) {
          short8v vf = *(const short8v*)&Vs[cur][row * 64 + (((4 * ks2 + lq) ^ (row & 7)) * 8)];
          yacc[nd] = mfma16(afr[ks2], vf, yacc[nd]);
        }
      }
      __builtin_amdgcn_s_setprio(0);
      __syncthreads();
      cur ^= 1;
    }
    // fused GroupNorm + gate epilogue
#pragma unroll
    for (int r = 0; r < 4; ++r) {
      float s1 = 0.f, s2 = 0.f;
#pragma unroll
      for (int nd = 0; nd < 8; ++nd) { const float v = yacc[nd][r]; s1 += v; s2 += v * v; }
#pragma unroll
      for (int msk = 1; msk < 16; msk <<= 1) {
        s1 += __shfl_xor(s1, msk);
        s2 += __shfl_xor(s2, msk);
      }
      const float mu = s1 * (1.f / 128.f);
      const float rstd = rsqrtf(s2 * (1.f / 128.f) - mu * mu + EPSf);
      const int q = q0 + w * 16 + lq * 4 + r;
      const size_t gbase = (size_t)(b * Ss + q) * LDQ + 3072 + h * DHd;
      const size_t obase = (size_t)(b * Ss + q) * Dd + h * DHd;
#pragma unroll
      for (int nd = 0; nd < 8; ++nd) {
        const int d = nd * 16 + lr;
        const float yv = (yacc[nd][r] - mu) * rstd * gsv[nd] + gbv[nd];
        const float gvx = bfu2f((unsigned short)QKVGb[gbase + d]);
        Gb[obase + d] = (short)f2bfu(swish_f(gvx) * yv);
      }
    }
  }
}

extern "C" void kernel_launch(void* const* d_in, const int* in_sizes, int n_in,
                              void* d_out, int out_size, void* d_ws, size_t ws_size,
                              hipStream_t stream) {
  const float* X = (const float*)d_in[0];
  const float* Wq = (const float*)d_in[1];
  const float* Wk = (const float*)d_in[2];
  const float* Wv = (const float*)d_in[3];
  const float* Wg = (const float*)d_in[4];
  const float* Wo = (const float*)d_in[5];
  const float* W1 = (const float*)d_in[6];
  const float* W2 = (const float*)d_in[7];
  const float* lns = (const float*)d_in[8];
  const float* lnb = (const float*)d_in[9];
  const float* gns = (const float*)d_in[10];
  const float* gnb = (const float*)d_in[11];
  float* out = (float*)d_out;

  char* W = (char*)d_ws;
  const size_t MB = 1u << 20;
  float* Abuf  = (float*)(W);             // 16 MB fp32
  short* Xnb   = (short*)(W + 16 * MB);   // 8 MB bf16
  short* QKVGb = (short*)(W + 24 * MB);   // 32 MB bf16 [4096][4096]; Hb aliases first 16 MB
  short* Vtb   = (short*)(W + 88 * MB);   // 8 MB bf16
  short* Gb    = (short*)(W + 96 * MB);   // 8 MB bf16
  short* Wqkvgt= (short*)(W + 104 * MB);  // 8 MB
  short* Wot   = (short*)(W + 112 * MB);  // 2 MB
  short* W1t   = (short*)(W + 114 * MB);  // 4 MB
  short* W2t   = (short*)(W + 118 * MB);  // 4 MB
  float* ct    = (float*)(W + 122 * MB);  // 256 KB
  float* st    = ct + Ss * 64;            // 256 KB
  short* Hb = QKVGb;  // FFN hidden 4096x2048 bf16 (16 MB)

  rope_table_kernel<<<(Ss * 64) / 256, 256, 0, stream>>>(ct, st);

  for (int l = 0; l < LAYERS; ++l) {
    const size_t DD = (size_t)Dd * Dd;
    const float* Acur = (l == 0) ? X : Abuf;  // residual stream input for this layer
    wtrans_all_kernel<<<9216, 256, 0, stream>>>(Wq + l * DD, Wk + l * DD, Wv + l * DD,
                                                Wg + l * DD, Wo + l * DD,
                                                W1 + (size_t)l * Dd * Ff,
                                                W2 + (size_t)l * Ff * Dd,
                                                Wqkvgt, Wot, W1t, W2t);
    // Xn = LN(A) -> bf16
    ln_bf16_kernel<<<Mm, 256, 0, stream>>>(Acur, Xnb, lns, lnb);
    // fused QKVG projection (dual-barrier 8-phase 256x256)
    gemm14<0><<<dim3(16, 16), 512, 0, stream>>>(Xnb, Wqkvgt, nullptr, QKVGb,
                                                nullptr, 4096, Dd, LDQ);
    // merged RoPE (in-place Q,K) + V transpose
    rvt_kernel<<<12288, 256, 0, stream>>>(QKVGb, Vtb, ct, st);
    // retention + fused GN/gate -> Gb (bf16)
    ret5_kernel<<<256, 256, 0, stream>>>(QKVGb, Vtb, Gb,
                                         gns + (size_t)l * Dd, gnb + (size_t)l * Dd);
    // A = (Gb @ Wo) + Acur
    gemm12<1><<<256, 512, 0, stream>>>(Gb, Wot, Abuf, nullptr, Acur,
                                       Dd, Dd, Dd, Dd, 8);
    // FFN
    ln_bf16_kernel<<<Mm, 256, 0, stream>>>(Abuf, Xnb, lns, lnb);
    gemm11<2><<<256, 512, 0, stream>>>(Xnb, W1t, nullptr, Hb, nullptr,
                                       Dd, Dd, Dd, Ff, 16);
    float* dst = (l == LAYERS - 1) ? out : Abuf;
    gemm12<1><<<256, 512, 0, stream>>>(Hb, W2t, dst, nullptr, Abuf,
                                       Ff, Ff, Ff, Dd, 8);
  }
}

// Round 17
// 710.743 us; speedup vs baseline: 1.6265x; 1.0158x over previous
//
#include <hip/hip_runtime.h>
#include <hip/hip_bf16.h>
#include <cmath>

#define LAYERS 4
#define Bb 4
#define Ss 1024
#define Dd 1024
#define Ff 2048
#define Hh 8
#define DHd 128
#define Mm (Bb * Ss)   // 4096 rows
#define EPSf 1e-5f
#define LDQ 4096       // combined QKVG row stride

typedef __attribute__((ext_vector_type(8))) short short8v;
typedef __attribute__((ext_vector_type(4))) float f32x4;
typedef __attribute__((ext_vector_type(4))) unsigned int u32x4;

__device__ __forceinline__ float swish_f(float x) { return x / (1.f + expf(-x)); }
__device__ __forceinline__ float gelu_f(float x) {
  return 0.5f * x * (1.f + tanhf(0.7978845608028654f * (x + 0.044715f * x * x * x)));
}
__device__ __forceinline__ unsigned short f2bfu(float f) {
  __hip_bfloat16 h = __float2bfloat16(f);
  return __builtin_bit_cast(unsigned short, h);
}
__device__ __forceinline__ float bfu2f(unsigned short u) {
  unsigned v = ((unsigned)u) << 16;
  return __builtin_bit_cast(float, v);
}
__device__ __forceinline__ void gl_lds16(const void* g, void* l) {
  __builtin_amdgcn_global_load_lds((__attribute__((address_space(1))) void*)g,
                                   (__attribute__((address_space(3))) void*)l, 16, 0, 0);
}
__device__ __forceinline__ f32x4 mfma16(short8v a, short8v b, f32x4 c) {
  return __builtin_amdgcn_mfma_f32_16x16x32_bf16(a, b, c, 0, 0, 0);
}

// ---------------- LayerNorm fp32 -> bf16 ----------------
__global__ __launch_bounds__(256) void ln_bf16_kernel(const float* __restrict__ x,
                                                      short* __restrict__ outb,
                                                      const float* __restrict__ sc,
                                                      const float* __restrict__ bi) {
  const int row = blockIdx.x;
  const int t = threadIdx.x;
  const float4 v = *(const float4*)(x + (size_t)row * Dd + t * 4);
  float s = v.x + v.y + v.z + v.w;
  float s2 = v.x * v.x + v.y * v.y + v.z * v.z + v.w * v.w;
#pragma unroll
  for (int o = 32; o > 0; o >>= 1) { s += __shfl_down(s, o); s2 += __shfl_down(s2, o); }
  __shared__ float ps[4], ps2[4];
  if ((t & 63) == 0) { ps[t >> 6] = s; ps2[t >> 6] = s2; }
  __syncthreads();
  s = ps[0] + ps[1] + ps[2] + ps[3];
  s2 = ps2[0] + ps2[1] + ps2[2] + ps2[3];
  const float mu = s * (1.f / Dd);
  const float var = s2 * (1.f / Dd) - mu * mu;
  const float rstd = rsqrtf(var + EPSf);
  const float4 g = *(const float4*)(sc + t * 4);
  const float4 b = *(const float4*)(bi + t * 4);
  const float o0 = (v.x - mu) * rstd * g.x + b.x;
  const float o1 = (v.y - mu) * rstd * g.y + b.y;
  const float o2 = (v.z - mu) * rstd * g.z + b.z;
  const float o3 = (v.w - mu) * rstd * g.w + b.w;
  unsigned p0 = (unsigned)f2bfu(o0) | ((unsigned)f2bfu(o1) << 16);
  unsigned p1 = (unsigned)f2bfu(o2) | ((unsigned)f2bfu(o3) << 16);
  uint2 pk; pk.x = p0; pk.y = p1;
  *(uint2*)(outb + (size_t)row * Dd + t * 4) = pk;
}

// ---------------- RoPE tables ----------------
__global__ void rope_table_kernel(float* __restrict__ ct, float* __restrict__ st) {
  const int i = blockIdx.x * 256 + threadIdx.x;  // < Ss*64
  const int s = i >> 6, f = i & 63;
  const float inv = powf(10000.f, -(float)f / 64.f);
  const float a = (float)s * inv;
  ct[i] = cosf(a);
  st[i] = sinf(a);
}

// ---------------- merged weight transpose: one dispatch per layer (9216 blocks) ----------
__global__ __launch_bounds__(256) void wtrans_all_kernel(
    const float* __restrict__ Wq, const float* __restrict__ Wk,
    const float* __restrict__ Wv, const float* __restrict__ Wg,
    const float* __restrict__ Wo, const float* __restrict__ W1,
    const float* __restrict__ W2,
    short* __restrict__ Wqkvgt, short* __restrict__ Wot,
    short* __restrict__ W1t, short* __restrict__ W2t) {
  __shared__ float tile[32][33];
  const int t = threadIdx.x;
  const int tc = t & 31, tr8 = t >> 5;
  const int blk = blockIdx.x;
  const float* src; short* dst; int K, N, n0, k0, nl;
  if (blk < 4096) {
    const int bx = blk & 127, ky = blk >> 7;
    n0 = bx * 32; k0 = ky * 32;
    const int which = n0 >> 10;
    src = (which == 0) ? Wq : (which == 1) ? Wk : (which == 2) ? Wv : Wg;
    nl = n0 & 1023; N = 1024; K = 1024; dst = Wqkvgt;
  } else if (blk < 5120) {
    const int b2 = blk - 4096;
    n0 = (b2 & 31) * 32; k0 = (b2 >> 5) * 32; nl = n0;
    src = Wo; N = 1024; K = 1024; dst = Wot;
  } else if (blk < 7168) {
    const int b2 = blk - 5120;
    n0 = (b2 & 63) * 32; k0 = (b2 >> 6) * 32; nl = n0;
    src = W1; N = 2048; K = 1024; dst = W1t;
  } else {
    const int b2 = blk - 7168;
    n0 = (b2 & 31) * 32; k0 = (b2 >> 5) * 32; nl = n0;
    src = W2; N = 1024; K = 2048; dst = W2t;
  }
#pragma unroll
  for (int i = 0; i < 4; ++i) {
    const int r = tr8 + i * 8;
    tile[r][tc] = src[(size_t)(k0 + r) * N + nl + tc];
  }
  __syncthreads();
#pragma unroll
  for (int i = 0; i < 4; ++i) {
    const int r = tr8 + i * 8;
    dst[(size_t)(n0 + r) * K + k0 + tc] = (short)f2bfu(tile[tc][r]);
  }
}

// ---------------- merged RoPE (in-place Q,K) + V transpose: 12288 blocks -----------------
__global__ __launch_bounds__(256) void rvt_kernel(short* __restrict__ QKVGb,
                                                  short* __restrict__ Vt,
                                                  const float* __restrict__ ct,
                                                  const float* __restrict__ st) {
  __shared__ short tile[32][33];
  const int blk = blockIdx.x, t = threadIdx.x;
  if (blk < 8192) {
    const int idx = blk * 256 + t;
    const int f = idx & 63;
    const int h = (idx >> 6) & 7;
    const int r = idx >> 9;            // b*S+s
    const int s = r & (Ss - 1);
    const float c = ct[(s << 6) + f], sn = st[(s << 6) + f];
    const size_t qo = (size_t)r * LDQ + h * DHd + 2 * f;
    const unsigned qp = *(const unsigned*)(QKVGb + qo);
    const unsigned kp = *(const unsigned*)(QKVGb + qo + 1024);
    const float qx = bfu2f((unsigned short)(qp & 0xffff)), qy = bfu2f((unsigned short)(qp >> 16));
    const float kx = bfu2f((unsigned short)(kp & 0xffff)), ky = bfu2f((unsigned short)(kp >> 16));
    const unsigned qn = (unsigned)f2bfu(qx * c - qy * sn) |
                        ((unsigned)f2bfu(qx * sn + qy * c) << 16);
    const unsigned kn = (unsigned)f2bfu(kx * c + ky * sn) |
                        ((unsigned)f2bfu(-kx * sn + ky * c) << 16);
    *(unsigned*)(QKVGb + qo) = qn;
    *(unsigned*)(QKVGb + qo + 1024) = kn;
  } else {
    const int vb = blk - 8192;
    const int s0 = (vb & 31) * 32, d0 = ((vb >> 5) & 3) * 32, bh = vb >> 7;
    const int bb = bh >> 3, h = bh & 7;
    const int tc = t & 31, tr8 = t >> 5;
#pragma unroll
    for (int i = 0; i < 4; ++i) {
      const int r = tr8 + i * 8;
      tile[r][tc] = QKVGb[(size_t)(bb * Ss + s0 + r) * LDQ + 2048 + h * DHd + d0 + tc];
    }
    __syncthreads();
#pragma unroll
    for (int i = 0; i < 4; ++i) {
      const int r = tr8 + i * 8;
      Vt[(size_t)(bh * DHd + d0 + r) * Ss + s0 + tc] = tile[tc][r];
    }
  }
}

// ---------------- bf16 MFMA GEMM v10: 256x256 8-phase schedule, counted vmcnt (R13 best) --
template <int EPI>
__global__ __launch_bounds__(512, 2) void gemm10(const short* __restrict__ A,
                                                 const short* __restrict__ Bt,
                                                 float* __restrict__ Cf,
                                                 short* __restrict__ Cb,
                                                 const float* __restrict__ Res,
                                                 int N, int K, int ldc) {
  __shared__ __align__(16) short As[2][2][128 * 64];  // [dbuf][half] 64 KB
  __shared__ __align__(16) short Bs[2][2][128 * 64];  // 64 KB
  const int t = threadIdx.x;
  const int w = t >> 6, l = t & 63;
  const int lq = l >> 4, lr = l & 15;
  const int wr = w >> 2, wc = w & 3;
  const int bhalf = wc >> 1, brow0 = (wc & 1) * 64;
  const int nwg = gridDim.x * gridDim.y;
  const int bid0 = blockIdx.x + blockIdx.y * gridDim.x;
  const int lgid = (bid0 & 7) * (nwg >> 3) + (bid0 >> 3);
  const int bx = lgid % gridDim.x, by = lgid / gridDim.x;
  const int row0 = by * 256, col0 = bx * 256;
  const int NT = K >> 6;

  f32x4 acc[8][4] = {};
  short8v a[4][2], b[4][2];

  auto stageA = [&](int kt, int hf) {
    const int db = kt & 1;
#pragma unroll
    for (int i = 0; i < 2; ++i) {
      const int c = t + i * 512;
      const int row = c >> 3, slot = c & 7;
      gl_lds16(A + (size_t)(row0 + hf * 128 + row) * K + kt * 64 + ((slot ^ (row & 7)) << 3),
               &As[db][hf][c * 8]);
    }
  };
  auto stageB = [&](int kt, int hf) {
    const int db = kt & 1;
#pragma unroll
    for (int i = 0; i < 2; ++i) {
      const int c = t + i * 512;
      const int row = c >> 3, slot = c & 7;
      gl_lds16(Bt + (size_t)(col0 + hf * 128 + row) * K + kt * 64 + ((slot ^ (row & 7)) << 3),
               &Bs[db][hf][c * 8]);
    }
  };
  auto rdA = [&](int db, int m, int ks) -> short8v {
    const int row = m * 16 + lr;
    return *(const short8v*)&As[db][wr][row * 64 + (((ks << 2) + lq) ^ (row & 7)) * 8];
  };
  auto rdB = [&](int db, int n, int ks) -> short8v {
    const int row = brow0 + n * 16 + lr;
    return *(const short8v*)&Bs[db][bhalf][row * 64 + (((ks << 2) + lq) ^ (row & 7)) * 8];
  };

  stageA(0, 0); stageA(0, 1); stageB(0, 0); stageB(0, 1);
  if (NT > 1) { stageB(1, 0); stageB(1, 1); }
  if (NT > 1) { asm volatile("s_waitcnt vmcnt(4)" ::: "memory"); }
  else        { asm volatile("s_waitcnt vmcnt(0)" ::: "memory"); }
  asm volatile("s_barrier" ::: "memory");

  for (int kt = 0; kt < NT; ++kt) {
    const int db = kt & 1;
#pragma unroll
    for (int m = 0; m < 4; ++m) { a[m][0] = rdA(db, m, 0); a[m][1] = rdA(db, m, 1); }
#pragma unroll
    for (int n = 0; n < 2; ++n) { b[n][0] = rdB(db, n, 0); b[n][1] = rdB(db, n, 1); }
    if (kt + 1 < NT) stageA(kt + 1, 0);
    __builtin_amdgcn_s_setprio(1);
#pragma unroll
    for (int m = 0; m < 4; ++m)
#pragma unroll
      for (int n = 0; n < 2; ++n) {
        acc[m][n] = mfma16(a[m][0], b[n][0], acc[m][n]);
        acc[m][n] = mfma16(a[m][1], b[n][1], acc[m][n]);
      }
    __builtin_amdgcn_s_setprio(0);
    asm volatile("s_barrier" ::: "memory");
#pragma unroll
    for (int n = 2; n < 4; ++n) { b[n][0] = rdB(db, n, 0); b[n][1] = rdB(db, n, 1); }
    if (kt + 1 < NT) stageA(kt + 1, 1);
    __builtin_amdgcn_s_setprio(1);
#pragma unroll
    for (int m = 0; m < 4; ++m)
#pragma unroll
      for (int n = 2; n < 4; ++n) {
        acc[m][n] = mfma16(a[m][0], b[n][0], acc[m][n]);
        acc[m][n] = mfma16(a[m][1], b[n][1], acc[m][n]);
      }
    __builtin_amdgcn_s_setprio(0);
    asm volatile("s_barrier" ::: "memory");
#pragma unroll
    for (int m = 0; m < 4; ++m) { a[m][0] = rdA(db, m + 4, 0); a[m][1] = rdA(db, m + 4, 1); }
    if (kt + 2 < NT) stageB(kt + 2, 0);
    __builtin_amdgcn_s_setprio(1);
#pragma unroll
    for (int m = 0; m < 4; ++m)
#pragma unroll
      for (int n = 0; n < 2; ++n) {
        acc[m + 4][n] = mfma16(a[m][0], b[n][0], acc[m + 4][n]);
        acc[m + 4][n] = mfma16(a[m][1], b[n][1], acc[m + 4][n]);
      }
    __builtin_amdgcn_s_setprio(0);
    asm volatile("s_barrier" ::: "memory");
    if (kt + 2 < NT) stageB(kt + 2, 1);
    __builtin_amdgcn_s_setprio(1);
#pragma unroll
    for (int m = 0; m < 4; ++m)
#pragma unroll
      for (int n = 2; n < 4; ++n) {
        acc[m + 4][n] = mfma16(a[m][0], b[n][0], acc[m + 4][n]);
        acc[m + 4][n] = mfma16(a[m][1], b[n][1], acc[m + 4][n]);
      }
    __builtin_amdgcn_s_setprio(0);
    if (kt + 2 < NT) { asm volatile("s_waitcnt vmcnt(4)" ::: "memory"); }
    else             { asm volatile("s_waitcnt vmcnt(0)" ::: "memory"); }
    asm volatile("s_barrier" ::: "memory");
  }

#pragma unroll
  for (int m = 0; m < 8; ++m) {
#pragma unroll
    for (int n = 0; n < 4; ++n) {
#pragma unroll
      for (int r = 0; r < 4; ++r) {
        const int row = row0 + wr * 128 + m * 16 + lq * 4 + r;
        const int col = col0 + wc * 64 + n * 16 + lr;
        const size_t o = (size_t)row * ldc + col;
        float v = acc[m][n][r];
        if (EPI == 0) Cb[o] = (short)f2bfu(v);
        else if (EPI == 1) Cf[o] = v + Res[o];
        else Cb[o] = (short)f2bfu(gelu_f(v));
      }
    }
  }
}

// ---------------- bf16 MFMA GEMM v11: 256x128 2-phase/K-tile, ring-3 LDS, vmcnt(6) --------
template <int EPI>
__global__ __launch_bounds__(512) void gemm11(const short* __restrict__ A,
                                              const short* __restrict__ Bt,
                                              float* __restrict__ Cf,
                                              short* __restrict__ Cb,
                                              const float* __restrict__ Res,
                                              int K, int lda, int ldb, int ldc, int nxt) {
  __shared__ __align__(16) short As[3][256 * 64];  // 96 KB ring-3
  __shared__ __align__(16) short Bs[3][128 * 64];  // 48 KB ring-3
  const int t = threadIdx.x;
  const int w = t >> 6, l = t & 63;
  const int lq = l >> 4, lr = l & 15;
  const int wr = w >> 2, wc = w & 3;
  const int nwg = gridDim.x;
  const int lgid = (blockIdx.x & 7) * (nwg >> 3) + (blockIdx.x >> 3);
  const int mt = lgid / nxt, nt_ = lgid % nxt;
  const int row0 = mt * 256, col0 = nt_ * 128;
  const int NT = K >> 6;
  f32x4 acc[8][2] = {};
  short8v a[4][2], b[2][2];

  auto stageA = [&](int kt, int hf) {
    const int s = kt % 3;
#pragma unroll
    for (int i = 0; i < 2; ++i) {
      const int c = t + i * 512;
      const int row = c >> 3, slot = c & 7;
      gl_lds16(A + (size_t)(row0 + hf * 128 + row) * lda + kt * 64 + ((slot ^ (row & 7)) << 3),
               &As[s][hf * 8192 + c * 8]);
    }
  };
  auto stageB = [&](int kt) {
    const int s = kt % 3;
#pragma unroll
    for (int i = 0; i < 2; ++i) {
      const int c = t + i * 512;
      const int row = c >> 3, slot = c & 7;
      gl_lds16(Bt + (size_t)(col0 + row) * ldb + kt * 64 + ((slot ^ (row & 7)) << 3),
               &Bs[s][c * 8]);
    }
  };
  auto rdA = [&](int s, int m, int ks) -> short8v {
    const int row = wr * 128 + m * 16 + lr;
    return *(const short8v*)&As[s][row * 64 + (((ks << 2) + lq) ^ (row & 7)) * 8];
  };
  auto rdB = [&](int s, int n, int ks) -> short8v {
    const int row = wc * 32 + n * 16 + lr;
    return *(const short8v*)&Bs[s][row * 64 + (((ks << 2) + lq) ^ (row & 7)) * 8];
  };

  stageA(0, 0); stageA(0, 1); stageB(0);
  stageA(1, 0); stageA(1, 1); stageB(1);
  asm volatile("s_waitcnt vmcnt(6)" ::: "memory");
  asm volatile("s_barrier" ::: "memory");

  for (int kt = 0; kt < NT; ++kt) {
    const int s = kt % 3;
#pragma unroll
    for (int m = 0; m < 4; ++m) { a[m][0] = rdA(s, m, 0); a[m][1] = rdA(s, m, 1); }
#pragma unroll
    for (int n = 0; n < 2; ++n) { b[n][0] = rdB(s, n, 0); b[n][1] = rdB(s, n, 1); }
    if (kt + 2 < NT) stageA(kt + 2, 0);
    __builtin_amdgcn_s_setprio(1);
#pragma unroll
    for (int m = 0; m < 4; ++m)
#pragma unroll
      for (int n = 0; n < 2; ++n) {
        acc[m][n] = mfma16(a[m][0], b[n][0], acc[m][n]);
        acc[m][n] = mfma16(a[m][1], b[n][1], acc[m][n]);
      }
    __builtin_amdgcn_s_setprio(0);
    asm volatile("s_barrier" ::: "memory");
#pragma unroll
    for (int m = 0; m < 4; ++m) { a[m][0] = rdA(s, m + 4, 0); a[m][1] = rdA(s, m + 4, 1); }
    if (kt + 2 < NT) { stageA(kt + 2, 1); stageB(kt + 2); }
    __builtin_amdgcn_s_setprio(1);
#pragma unroll
    for (int m = 0; m < 4; ++m)
#pragma unroll
      for (int n = 0; n < 2; ++n) {
        acc[m + 4][n] = mfma16(a[m][0], b[n][0], acc[m + 4][n]);
        acc[m + 4][n] = mfma16(a[m][1], b[n][1], acc[m + 4][n]);
      }
    __builtin_amdgcn_s_setprio(0);
    if (kt + 2 < NT) { asm volatile("s_waitcnt vmcnt(6)" ::: "memory"); }
    else             { asm volatile("s_waitcnt vmcnt(0)" ::: "memory"); }
    asm volatile("s_barrier" ::: "memory");
  }

#pragma unroll
  for (int m = 0; m < 8; ++m) {
#pragma unroll
    for (int n = 0; n < 2; ++n) {
#pragma unroll
      for (int r = 0; r < 4; ++r) {
        const int row = row0 + wr * 128 + m * 16 + lq * 4 + r;
        const int col = col0 + wc * 32 + n * 16 + lr;
        const size_t o = (size_t)row * ldc + col;
        float v = acc[m][n][r];
        if (EPI == 0) Cb[o] = (short)f2bfu(v);
        else if (EPI == 1) Cf[o] = v + Res[o];
        else Cb[o] = (short)f2bfu(gelu_f(v));
      }
    }
  }
}

// ---------------- bf16 MFMA GEMM v12: 128x128 2-phase/K-tile, ring-3 LDS, vmcnt(4) --------
template <int EPI>
__global__ __launch_bounds__(512) void gemm12(const short* __restrict__ A,
                                              const short* __restrict__ Bt,
                                              float* __restrict__ Cf,
                                              short* __restrict__ Cb,
                                              const float* __restrict__ Res,
                                              int K, int lda, int ldb, int ldc, int nxt) {
  __shared__ __align__(16) short As[3][128 * 64];  // 48 KB ring-3
  __shared__ __align__(16) short Bs[3][128 * 64];  // 48 KB ring-3
  const int t = threadIdx.x;
  const int w = t >> 6, l = t & 63;
  const int lq = l >> 4, lr = l & 15;
  const int wr = w >> 2, wc = w & 3;
  const int nwg = gridDim.x;
  const int lgid = (blockIdx.x & 7) * (nwg >> 3) + (blockIdx.x >> 3);
  const int mt = lgid / nxt, nt_ = lgid % nxt;
  const int row0 = mt * 128, col0 = nt_ * 128;
  const int NT = K >> 6;
  f32x4 acc[4][2] = {};
  short8v a[4][2], b[2][2];

  auto stageA = [&](int kt) {
    const int s = kt % 3;
#pragma unroll
    for (int i = 0; i < 2; ++i) {
      const int c = t + i * 512;
      const int row = c >> 3, slot = c & 7;
      gl_lds16(A + (size_t)(row0 + row) * lda + kt * 64 + ((slot ^ (row & 7)) << 3),
               &As[s][c * 8]);
    }
  };
  auto stageB = [&](int kt) {
    const int s = kt % 3;
#pragma unroll
    for (int i = 0; i < 2; ++i) {
      const int c = t + i * 512;
      const int row = c >> 3, slot = c & 7;
      gl_lds16(Bt + (size_t)(col0 + row) * ldb + kt * 64 + ((slot ^ (row & 7)) << 3),
               &Bs[s][c * 8]);
    }
  };
  auto rdA = [&](int s, int m, int ks) -> short8v {
    const int row = wr * 64 + m * 16 + lr;
    return *(const short8v*)&As[s][row * 64 + (((ks << 2) + lq) ^ (row & 7)) * 8];
  };
  auto rdB = [&](int s, int n, int ks) -> short8v {
    const int row = wc * 32 + n * 16 + lr;
    return *(const short8v*)&Bs[s][row * 64 + (((ks << 2) + lq) ^ (row & 7)) * 8];
  };

  stageA(0); stageB(0);
  stageA(1); stageB(1);
  asm volatile("s_waitcnt vmcnt(4)" ::: "memory");
  asm volatile("s_barrier" ::: "memory");

  for (int kt = 0; kt < NT; ++kt) {
    const int s = kt % 3;
#pragma unroll
    for (int m = 0; m < 4; ++m) { a[m][0] = rdA(s, m, 0); a[m][1] = rdA(s, m, 1); }
#pragma unroll
    for (int n = 0; n < 2; ++n) { b[n][0] = rdB(s, n, 0); b[n][1] = rdB(s, n, 1); }
    if (kt + 2 < NT) stageA(kt + 2);
    __builtin_amdgcn_s_setprio(1);
#pragma unroll
    for (int m = 0; m < 2; ++m)
#pragma unroll
      for (int n = 0; n < 2; ++n) {
        acc[m][n] = mfma16(a[m][0], b[n][0], acc[m][n]);
        acc[m][n] = mfma16(a[m][1], b[n][1], acc[m][n]);
      }
    __builtin_amdgcn_s_setprio(0);
    asm volatile("s_barrier" ::: "memory");
    if (kt + 2 < NT) stageB(kt + 2);
    __builtin_amdgcn_s_setprio(1);
#pragma unroll
    for (int m = 2; m < 4; ++m)
#pragma unroll
      for (int n = 0; n < 2; ++n) {
        acc[m][n] = mfma16(a[m][0], b[n][0], acc[m][n]);
        acc[m][n] = mfma16(a[m][1], b[n][1], acc[m][n]);
      }
    __builtin_amdgcn_s_setprio(0);
    if (kt + 2 < NT) { asm volatile("s_waitcnt vmcnt(4)" ::: "memory"); }
    else             { asm volatile("s_waitcnt vmcnt(0)" ::: "memory"); }
    asm volatile("s_barrier" ::: "memory");
  }

#pragma unroll
  for (int m = 0; m < 4; ++m) {
#pragma unroll
    for (int n = 0; n < 2; ++n) {
#pragma unroll
      for (int r = 0; r < 4; ++r) {
        const int row = row0 + wr * 64 + m * 16 + lq * 4 + r;
        const int col = col0 + wc * 32 + n * 16 + lr;
        const size_t o = (size_t)row * ldc + col;
        float v = acc[m][n][r];
        if (EPI == 0) Cb[o] = (short)f2bfu(v);
        else if (EPI == 1) Cf[o] = v + Res[o];
        else Cb[o] = (short)f2bfu(gelu_f(v));
      }
    }
  }
}

// ---------------- Retention v5: fused GN+gate, paired q-blocks (qb,15-qb), QBLK=64 --------
__global__ __launch_bounds__(256) void ret5_kernel(const short* __restrict__ QKVGb,
                                                   const short* __restrict__ Vt,
                                                   short* __restrict__ Gb,
                                                   const float* __restrict__ gs,
                                                   const float* __restrict__ gb) {
  __shared__ __align__(16) short Ks[2][64 * 128];
  __shared__ __align__(16) short Vs[2][128 * 64];
  const int t = threadIdx.x, w = t >> 6, l = t & 63;
  const int lq = l >> 4, lr = l & 15;
  const int u = blockIdx.x;                     // 0..255
  const int lgid = (u & 7) * 32 + (u >> 3);     // XCD-contiguous
  const int bh = lgid >> 3, pr = lgid & 7;
  const int b = bh >> 3, h = bh & 7;
  const float lstep = (logf(1.f / 512.f) - logf(1.f / 32.f)) * (1.f / 7.f);
  const float gamma = 1.f - expf(logf(1.f / 32.f) + (float)h * lstep);
  const float l2g = logf(gamma) * 1.44269504f;
  const short* Qp = QKVGb;
  const short* Kp = QKVGb + 1024;

  float cmf[4], csr[4];
#pragma unroll
  for (int mf = 0; mf < 4; ++mf) cmf[mf] = exp2f(l2g * (float)(-16 * mf));
#pragma unroll
  for (int r = 0; r < 4; ++r) csr[r] = exp2f(l2g * (float)(63 - 4 * lq - r));
  float gsv[8], gbv[8];
#pragma unroll
  for (int nd = 0; nd < 8; ++nd) {
    gsv[nd] = gs[h * DHd + nd * 16 + lr];
    gbv[nd] = gb[h * DHd + nd * 16 + lr];
  }
  const int sb = ((lq & 1) * 2) * 16 + lr;

  auto stageKV = [&](int m0, int buf) {
#pragma unroll
    for (int i = 0; i < 4; ++i) {
      const int c = (w * 4 + i) * 64 + l;
      const int row = c >> 4, slot = c & 15;
      gl_lds16(Kp + (size_t)(b * Ss + m0 + row) * LDQ + h * DHd + ((slot ^ (row & 7)) * 8),
               &Ks[buf][(w * 4 + i) * 512]);
    }
#pragma unroll
    for (int i = 0; i < 4; ++i) {
      const int c = (w * 4 + i) * 64 + l;
      const int row = c >> 3, slot = c & 7;
      gl_lds16(Vt + (size_t)(bh * DHd + row) * Ss + m0 + ((slot ^ (row & 7)) * 8),
               &Vs[buf][(w * 4 + i) * 512]);
    }
  };

  for (int pass = 0; pass < 2; ++pass) {
    const int qb = pass ? (15 - pr) : pr;
    const int q0 = qb * 64;
    const int nt = qb + 1;
    short8v qf[4];
#pragma unroll
    for (int ks = 0; ks < 4; ++ks)
      qf[ks] = *(const short8v*)(Qp + (size_t)(b * Ss + q0 + w * 16 + lr) * LDQ +
                                 h * DHd + ks * 32 + lq * 8);
    f32x4 yacc[8] = {};
    stageKV(0, 0);
    __syncthreads();
    int cur = 0;
    for (int tt = 0; tt < nt; ++tt) {
      const int m0 = tt * 64;
      if (tt + 1 < nt) stageKV((tt + 1) * 64, cur ^ 1);

      f32x4 st[4] = {};
      __builtin_amdgcn_s_setprio(1);
#pragma unroll
      for (int mf = 0; mf < 4; ++mf) {
        const int row = mf * 16 + lr;
#pragma unroll
        for (int ks = 0; ks < 4; ++ks) {
          short8v kf = *(const short8v*)&Ks[cur][row * 128 + (((4 * ks + lq) ^ (row & 7)) * 8)];
          st[mf] = mfma16(kf, qf[ks], st[mf]);
        }
      }
      __builtin_amdgcn_s_setprio(0);
      const int qg = q0 + w * 16 + lr;
      const float rs = exp2f(l2g * (float)(qg - m0 - 63));
#pragma unroll
      for (int mf = 0; mf < 4; ++mf)
#pragma unroll
        for (int r = 0; r < 4; ++r) {
          const int kvg = m0 + mf * 16 + lq * 4 + r;
          const float wgt = (qg >= kvg) ? rs * cmf[mf] * csr[r] : 0.f;
          st[mf][r] *= wgt;
        }
      unsigned pk[4][2];
#pragma unroll
      for (int mf = 0; mf < 4; ++mf)
#pragma unroll
        for (int p = 0; p < 2; ++p)
          pk[mf][p] = (unsigned)f2bfu(st[mf][2 * p]) |
                      ((unsigned)f2bfu(st[mf][2 * p + 1]) << 16);
      short8v afr[2];
#pragma unroll
      for (int ks2 = 0; ks2 < 2; ++ks2) {
        u32x4 wd;
#pragma unroll
        for (int wj = 0; wj < 4; ++wj) {
          const int src = sb + (wj >> 1) * 16;
          const unsigned v0 = __shfl(pk[2 * ks2 + 0][wj & 1], src);
          const unsigned v1 = __shfl(pk[2 * ks2 + 1][wj & 1], src);
          wd[wj] = (lq >= 2) ? v1 : v0;
        }
        afr[ks2] = __builtin_bit_cast(short8v, wd);
      }
      __builtin_amdgcn_s_setprio(1);
#pragma unroll
      for (int nd = 0; nd < 8; ++nd) {
        const int row = nd * 16 + lr;
#pragma unroll
        for (int ks2 = 0; ks2 < 2; ++ks2) {
          short8v vf = *(const short8v*)&Vs[cur][row * 64 + (((4 * ks2 + lq) ^ (row & 7)) * 8)];
          yacc[nd] = mfma16(afr[ks2], vf, yacc[nd]);
        }
      }
      __builtin_amdgcn_s_setprio(0);
      __syncthreads();
      cur ^= 1;
    }
    // fused GroupNorm + gate epilogue
#pragma unroll
    for (int r = 0; r < 4; ++r) {
      float s1 = 0.f, s2 = 0.f;
#pragma unroll
      for (int nd = 0; nd < 8; ++nd) { const float v = yacc[nd][r]; s1 += v; s2 += v * v; }
#pragma unroll
      for (int msk = 1; msk < 16; msk <<= 1) {
        s1 += __shfl_xor(s1, msk);
        s2 += __shfl_xor(s2, msk);
      }
      const float mu = s1 * (1.f / 128.f);
      const float rstd = rsqrtf(s2 * (1.f / 128.f) - mu * mu + EPSf);
      const int q = q0 + w * 16 + lq * 4 + r;
      const size_t gbase = (size_t)(b * Ss + q) * LDQ + 3072 + h * DHd;
      const size_t obase = (size_t)(b * Ss + q) * Dd + h * DHd;
#pragma unroll
      for (int nd = 0; nd < 8; ++nd) {
        const int d = nd * 16 + lr;
        const float yv = (yacc[nd][r] - mu) * rstd * gsv[nd] + gbv[nd];
        const float gvx = bfu2f((unsigned short)QKVGb[gbase + d]);
        Gb[obase + d] = (short)f2bfu(swish_f(gvx) * yv);
      }
    }
  }
}

extern "C" void kernel_launch(void* const* d_in, const int* in_sizes, int n_in,
                              void* d_out, int out_size, void* d_ws, size_t ws_size,
                              hipStream_t stream) {
  const float* X = (const float*)d_in[0];
  const float* Wq = (const float*)d_in[1];
  const float* Wk = (const float*)d_in[2];
  const float* Wv = (const float*)d_in[3];
  const float* Wg = (const float*)d_in[4];
  const float* Wo = (const float*)d_in[5];
  const float* W1 = (const float*)d_in[6];
  const float* W2 = (const float*)d_in[7];
  const float* lns = (const float*)d_in[8];
  const float* lnb = (const float*)d_in[9];
  const float* gns = (const float*)d_in[10];
  const float* gnb = (const float*)d_in[11];
  float* out = (float*)d_out;

  char* W = (char*)d_ws;
  const size_t MB = 1u << 20;
  float* Abuf  = (float*)(W);             // 16 MB fp32
  short* Xnb   = (short*)(W + 16 * MB);   // 8 MB bf16
  short* QKVGb = (short*)(W + 24 * MB);   // 32 MB bf16 [4096][4096]; Hb aliases first 16 MB
  short* Vtb   = (short*)(W + 88 * MB);   // 8 MB bf16
  short* Gb    = (short*)(W + 96 * MB);   // 8 MB bf16
  short* Wqkvgt= (short*)(W + 104 * MB);  // 8 MB
  short* Wot   = (short*)(W + 112 * MB);  // 2 MB
  short* W1t   = (short*)(W + 114 * MB);  // 4 MB
  short* W2t   = (short*)(W + 118 * MB);  // 4 MB
  float* ct    = (float*)(W + 122 * MB);  // 256 KB
  float* st    = ct + Ss * 64;            // 256 KB
  short* Hb = QKVGb;  // FFN hidden 4096x2048 bf16 (16 MB)

  rope_table_kernel<<<(Ss * 64) / 256, 256, 0, stream>>>(ct, st);

  for (int l = 0; l < LAYERS; ++l) {
    const size_t DD = (size_t)Dd * Dd;
    const float* Acur = (l == 0) ? X : Abuf;  // residual stream input for this layer
    wtrans_all_kernel<<<9216, 256, 0, stream>>>(Wq + l * DD, Wk + l * DD, Wv + l * DD,
                                                Wg + l * DD, Wo + l * DD,
                                                W1 + (size_t)l * Dd * Ff,
                                                W2 + (size_t)l * Ff * Dd,
                                                Wqkvgt, Wot, W1t, W2t);
    // Xn = LN(A) -> bf16
    ln_bf16_kernel<<<Mm, 256, 0, stream>>>(Acur, Xnb, lns, lnb);
    // fused QKVG projection (8-phase 256x256, R13 schedule)
    gemm10<0><<<dim3(16, 16), 512, 0, stream>>>(Xnb, Wqkvgt, nullptr, QKVGb,
                                                nullptr, 4096, Dd, LDQ);
    // merged RoPE (in-place Q,K) + V transpose
    rvt_kernel<<<12288, 256, 0, stream>>>(QKVGb, Vtb, ct, st);
    // retention + fused GN/gate -> Gb (bf16)
    ret5_kernel<<<256, 256, 0, stream>>>(QKVGb, Vtb, Gb,
                                         gns + (size_t)l * Dd, gnb + (size_t)l * Dd);
    // A = (Gb @ Wo) + Acur
    gemm12<1><<<256, 512, 0, stream>>>(Gb, Wot, Abuf, nullptr, Acur,
                                       Dd, Dd, Dd, Dd, 8);
    // FFN
    ln_bf16_kernel<<<Mm, 256, 0, stream>>>(Abuf, Xnb, lns, lnb);
    gemm11<2><<<256, 512, 0, stream>>>(Xnb, W1t, nullptr, Hb, nullptr,
                                       Dd, Dd, Dd, Ff, 16);
    float* dst = (l == LAYERS - 1) ? out : Abuf;
    gemm12<1><<<256, 512, 0, stream>>>(Hb, W2t, dst, nullptr, Abuf,
                                       Ff, Ff, Ff, Dd, 8);
  }
}

// Round 18
// 701.351 us; speedup vs baseline: 1.6483x; 1.0134x over previous
//
#include <hip/hip_runtime.h>
#include <hip/hip_bf16.h>
#include <cmath>

#define LAYERS 4
#define Bb 4
#define Ss 1024
#define Dd 1024
#define Ff 2048
#define Hh 8
#define DHd 128
#define Mm (Bb * Ss)   // 4096 rows
#define EPSf 1e-5f
#define LDQ 4096       // combined QKVG row stride

typedef __attribute__((ext_vector_type(8))) short short8v;
typedef __attribute__((ext_vector_type(4))) float f32x4;
typedef __attribute__((ext_vector_type(4))) unsigned int u32x4;

__device__ __forceinline__ float swish_f(float x) { return x / (1.f + expf(-x)); }
__device__ __forceinline__ float gelu_f(float x) {
  return 0.5f * x * (1.f + tanhf(0.7978845608028654f * (x + 0.044715f * x * x * x)));
}
__device__ __forceinline__ unsigned short f2bfu(float f) {
  __hip_bfloat16 h = __float2bfloat16(f);
  return __builtin_bit_cast(unsigned short, h);
}
__device__ __forceinline__ float bfu2f(unsigned short u) {
  unsigned v = ((unsigned)u) << 16;
  return __builtin_bit_cast(float, v);
}
__device__ __forceinline__ void gl_lds16(const void* g, void* l) {
  __builtin_amdgcn_global_load_lds((__attribute__((address_space(1))) void*)g,
                                   (__attribute__((address_space(3))) void*)l, 16, 0, 0);
}
__device__ __forceinline__ f32x4 mfma16(short8v a, short8v b, f32x4 c) {
  return __builtin_amdgcn_mfma_f32_16x16x32_bf16(a, b, c, 0, 0, 0);
}

// ---------------- LayerNorm fp32 -> bf16 (standalone, used for FFN LN) ----------------
__global__ __launch_bounds__(256) void ln_bf16_kernel(const float* __restrict__ x,
                                                      short* __restrict__ outb,
                                                      const float* __restrict__ sc,
                                                      const float* __restrict__ bi) {
  const int row = blockIdx.x;
  const int t = threadIdx.x;
  const float4 v = *(const float4*)(x + (size_t)row * Dd + t * 4);
  float s = v.x + v.y + v.z + v.w;
  float s2 = v.x * v.x + v.y * v.y + v.z * v.z + v.w * v.w;
#pragma unroll
  for (int o = 32; o > 0; o >>= 1) { s += __shfl_down(s, o); s2 += __shfl_down(s2, o); }
  __shared__ float ps[4], ps2[4];
  if ((t & 63) == 0) { ps[t >> 6] = s; ps2[t >> 6] = s2; }
  __syncthreads();
  s = ps[0] + ps[1] + ps[2] + ps[3];
  s2 = ps2[0] + ps2[1] + ps2[2] + ps2[3];
  const float mu = s * (1.f / Dd);
  const float var = s2 * (1.f / Dd) - mu * mu;
  const float rstd = rsqrtf(var + EPSf);
  const float4 g = *(const float4*)(sc + t * 4);
  const float4 b = *(const float4*)(bi + t * 4);
  const float o0 = (v.x - mu) * rstd * g.x + b.x;
  const float o1 = (v.y - mu) * rstd * g.y + b.y;
  const float o2 = (v.z - mu) * rstd * g.z + b.z;
  const float o3 = (v.w - mu) * rstd * g.w + b.w;
  unsigned p0 = (unsigned)f2bfu(o0) | ((unsigned)f2bfu(o1) << 16);
  unsigned p1 = (unsigned)f2bfu(o2) | ((unsigned)f2bfu(o3) << 16);
  uint2 pk; pk.x = p0; pk.y = p1;
  *(uint2*)(outb + (size_t)row * Dd + t * 4) = pk;
}

// ---------------- RoPE tables ----------------
__global__ void rope_table_kernel(float* __restrict__ ct, float* __restrict__ st) {
  const int i = blockIdx.x * 256 + threadIdx.x;  // < Ss*64
  const int s = i >> 6, f = i & 63;
  const float inv = powf(10000.f, -(float)f / 64.f);
  const float a = (float)s * inv;
  ct[i] = cosf(a);
  st[i] = sinf(a);
}

// ---------------- merged weight transpose + LN(Acur): one dispatch (13312 blocks) --------
// blocks 0..9215: weight transposes; 9216..13311: LN rows (independent inputs/outputs).
__global__ __launch_bounds__(256) void wtrans_ln_kernel(
    const float* __restrict__ Wq, const float* __restrict__ Wk,
    const float* __restrict__ Wv, const float* __restrict__ Wg,
    const float* __restrict__ Wo, const float* __restrict__ W1,
    const float* __restrict__ W2,
    short* __restrict__ Wqkvgt, short* __restrict__ Wot,
    short* __restrict__ W1t, short* __restrict__ W2t,
    const float* __restrict__ x, short* __restrict__ outb,
    const float* __restrict__ sc, const float* __restrict__ bi) {
  __shared__ float tile[32][33];
  __shared__ float ps[4], ps2[4];
  const int t = threadIdx.x;
  const int blk = blockIdx.x;
  if (blk >= 9216) {
    // ---- LN path ----
    const int row = blk - 9216;
    const float4 v = *(const float4*)(x + (size_t)row * Dd + t * 4);
    float s = v.x + v.y + v.z + v.w;
    float s2 = v.x * v.x + v.y * v.y + v.z * v.z + v.w * v.w;
#pragma unroll
    for (int o = 32; o > 0; o >>= 1) { s += __shfl_down(s, o); s2 += __shfl_down(s2, o); }
    if ((t & 63) == 0) { ps[t >> 6] = s; ps2[t >> 6] = s2; }
    __syncthreads();
    s = ps[0] + ps[1] + ps[2] + ps[3];
    s2 = ps2[0] + ps2[1] + ps2[2] + ps2[3];
    const float mu = s * (1.f / Dd);
    const float var = s2 * (1.f / Dd) - mu * mu;
    const float rstd = rsqrtf(var + EPSf);
    const float4 g = *(const float4*)(sc + t * 4);
    const float4 b = *(const float4*)(bi + t * 4);
    const float o0 = (v.x - mu) * rstd * g.x + b.x;
    const float o1 = (v.y - mu) * rstd * g.y + b.y;
    const float o2 = (v.z - mu) * rstd * g.z + b.z;
    const float o3 = (v.w - mu) * rstd * g.w + b.w;
    unsigned p0 = (unsigned)f2bfu(o0) | ((unsigned)f2bfu(o1) << 16);
    unsigned p1 = (unsigned)f2bfu(o2) | ((unsigned)f2bfu(o3) << 16);
    uint2 pk; pk.x = p0; pk.y = p1;
    *(uint2*)(outb + (size_t)row * Dd + t * 4) = pk;
    return;
  }
  // ---- weight transpose path ----
  const int tc = t & 31, tr8 = t >> 5;
  const float* src; short* dst; int K, N, n0, k0, nl;
  if (blk < 4096) {
    const int bx = blk & 127, ky = blk >> 7;
    n0 = bx * 32; k0 = ky * 32;
    const int which = n0 >> 10;
    src = (which == 0) ? Wq : (which == 1) ? Wk : (which == 2) ? Wv : Wg;
    nl = n0 & 1023; N = 1024; K = 1024; dst = Wqkvgt;
  } else if (blk < 5120) {
    const int b2 = blk - 4096;
    n0 = (b2 & 31) * 32; k0 = (b2 >> 5) * 32; nl = n0;
    src = Wo; N = 1024; K = 1024; dst = Wot;
  } else if (blk < 7168) {
    const int b2 = blk - 5120;
    n0 = (b2 & 63) * 32; k0 = (b2 >> 6) * 32; nl = n0;
    src = W1; N = 2048; K = 1024; dst = W1t;
  } else {
    const int b2 = blk - 7168;
    n0 = (b2 & 31) * 32; k0 = (b2 >> 5) * 32; nl = n0;
    src = W2; N = 1024; K = 2048; dst = W2t;
  }
#pragma unroll
  for (int i = 0; i < 4; ++i) {
    const int r = tr8 + i * 8;
    tile[r][tc] = src[(size_t)(k0 + r) * N + nl + tc];
  }
  __syncthreads();
#pragma unroll
  for (int i = 0; i < 4; ++i) {
    const int r = tr8 + i * 8;
    dst[(size_t)(n0 + r) * K + k0 + tc] = (short)f2bfu(tile[tc][r]);
  }
}

// ---------------- merged RoPE (in-place Q,K) + V transpose: 12288 blocks -----------------
__global__ __launch_bounds__(256) void rvt_kernel(short* __restrict__ QKVGb,
                                                  short* __restrict__ Vt,
                                                  const float* __restrict__ ct,
                                                  const float* __restrict__ st) {
  __shared__ short tile[32][33];
  const int blk = blockIdx.x, t = threadIdx.x;
  if (blk < 8192) {
    const int idx = blk * 256 + t;
    const int f = idx & 63;
    const int h = (idx >> 6) & 7;
    const int r = idx >> 9;            // b*S+s
    const int s = r & (Ss - 1);
    const float c = ct[(s << 6) + f], sn = st[(s << 6) + f];
    const size_t qo = (size_t)r * LDQ + h * DHd + 2 * f;
    const unsigned qp = *(const unsigned*)(QKVGb + qo);
    const unsigned kp = *(const unsigned*)(QKVGb + qo + 1024);
    const float qx = bfu2f((unsigned short)(qp & 0xffff)), qy = bfu2f((unsigned short)(qp >> 16));
    const float kx = bfu2f((unsigned short)(kp & 0xffff)), ky = bfu2f((unsigned short)(kp >> 16));
    const unsigned qn = (unsigned)f2bfu(qx * c - qy * sn) |
                        ((unsigned)f2bfu(qx * sn + qy * c) << 16);
    const unsigned kn = (unsigned)f2bfu(kx * c + ky * sn) |
                        ((unsigned)f2bfu(-kx * sn + ky * c) << 16);
    *(unsigned*)(QKVGb + qo) = qn;
    *(unsigned*)(QKVGb + qo + 1024) = kn;
  } else {
    const int vb = blk - 8192;
    const int s0 = (vb & 31) * 32, d0 = ((vb >> 5) & 3) * 32, bh = vb >> 7;
    const int bb = bh >> 3, h = bh & 7;
    const int tc = t & 31, tr8 = t >> 5;
#pragma unroll
    for (int i = 0; i < 4; ++i) {
      const int r = tr8 + i * 8;
      tile[r][tc] = QKVGb[(size_t)(bb * Ss + s0 + r) * LDQ + 2048 + h * DHd + d0 + tc];
    }
    __syncthreads();
#pragma unroll
    for (int i = 0; i < 4; ++i) {
      const int r = tr8 + i * 8;
      Vt[(size_t)(bh * DHd + d0 + r) * Ss + s0 + tc] = tile[tc][r];
    }
  }
}

// ---------------- bf16 MFMA GEMM v10: 256x256 8-phase schedule, counted vmcnt (best) ------
template <int EPI>
__global__ __launch_bounds__(512, 2) void gemm10(const short* __restrict__ A,
                                                 const short* __restrict__ Bt,
                                                 float* __restrict__ Cf,
                                                 short* __restrict__ Cb,
                                                 const float* __restrict__ Res,
                                                 int N, int K, int ldc) {
  __shared__ __align__(16) short As[2][2][128 * 64];  // [dbuf][half] 64 KB
  __shared__ __align__(16) short Bs[2][2][128 * 64];  // 64 KB
  const int t = threadIdx.x;
  const int w = t >> 6, l = t & 63;
  const int lq = l >> 4, lr = l & 15;
  const int wr = w >> 2, wc = w & 3;
  const int bhalf = wc >> 1, brow0 = (wc & 1) * 64;
  const int nwg = gridDim.x * gridDim.y;
  const int bid0 = blockIdx.x + blockIdx.y * gridDim.x;
  const int lgid = (bid0 & 7) * (nwg >> 3) + (bid0 >> 3);
  const int bx = lgid % gridDim.x, by = lgid / gridDim.x;
  const int row0 = by * 256, col0 = bx * 256;
  const int NT = K >> 6;

  f32x4 acc[8][4] = {};
  short8v a[4][2], b[4][2];

  auto stageA = [&](int kt, int hf) {
    const int db = kt & 1;
#pragma unroll
    for (int i = 0; i < 2; ++i) {
      const int c = t + i * 512;
      const int row = c >> 3, slot = c & 7;
      gl_lds16(A + (size_t)(row0 + hf * 128 + row) * K + kt * 64 + ((slot ^ (row & 7)) << 3),
               &As[db][hf][c * 8]);
    }
  };
  auto stageB = [&](int kt, int hf) {
    const int db = kt & 1;
#pragma unroll
    for (int i = 0; i < 2; ++i) {
      const int c = t + i * 512;
      const int row = c >> 3, slot = c & 7;
      gl_lds16(Bt + (size_t)(col0 + hf * 128 + row) * K + kt * 64 + ((slot ^ (row & 7)) << 3),
               &Bs[db][hf][c * 8]);
    }
  };
  auto rdA = [&](int db, int m, int ks) -> short8v {
    const int row = m * 16 + lr;
    return *(const short8v*)&As[db][wr][row * 64 + (((ks << 2) + lq) ^ (row & 7)) * 8];
  };
  auto rdB = [&](int db, int n, int ks) -> short8v {
    const int row = brow0 + n * 16 + lr;
    return *(const short8v*)&Bs[db][bhalf][row * 64 + (((ks << 2) + lq) ^ (row & 7)) * 8];
  };

  stageA(0, 0); stageA(0, 1); stageB(0, 0); stageB(0, 1);
  if (NT > 1) { stageB(1, 0); stageB(1, 1); }
  if (NT > 1) { asm volatile("s_waitcnt vmcnt(4)" ::: "memory"); }
  else        { asm volatile("s_waitcnt vmcnt(0)" ::: "memory"); }
  asm volatile("s_barrier" ::: "memory");

  for (int kt = 0; kt < NT; ++kt) {
    const int db = kt & 1;
#pragma unroll
    for (int m = 0; m < 4; ++m) { a[m][0] = rdA(db, m, 0); a[m][1] = rdA(db, m, 1); }
#pragma unroll
    for (int n = 0; n < 2; ++n) { b[n][0] = rdB(db, n, 0); b[n][1] = rdB(db, n, 1); }
    if (kt + 1 < NT) stageA(kt + 1, 0);
    __builtin_amdgcn_s_setprio(1);
#pragma unroll
    for (int m = 0; m < 4; ++m)
#pragma unroll
      for (int n = 0; n < 2; ++n) {
        acc[m][n] = mfma16(a[m][0], b[n][0], acc[m][n]);
        acc[m][n] = mfma16(a[m][1], b[n][1], acc[m][n]);
      }
    __builtin_amdgcn_s_setprio(0);
    asm volatile("s_barrier" ::: "memory");
#pragma unroll
    for (int n = 2; n < 4; ++n) { b[n][0] = rdB(db, n, 0); b[n][1] = rdB(db, n, 1); }
    if (kt + 1 < NT) stageA(kt + 1, 1);
    __builtin_amdgcn_s_setprio(1);
#pragma unroll
    for (int m = 0; m < 4; ++m)
#pragma unroll
      for (int n = 2; n < 4; ++n) {
        acc[m][n] = mfma16(a[m][0], b[n][0], acc[m][n]);
        acc[m][n] = mfma16(a[m][1], b[n][1], acc[m][n]);
      }
    __builtin_amdgcn_s_setprio(0);
    asm volatile("s_barrier" ::: "memory");
#pragma unroll
    for (int m = 0; m < 4; ++m) { a[m][0] = rdA(db, m + 4, 0); a[m][1] = rdA(db, m + 4, 1); }
    if (kt + 2 < NT) stageB(kt + 2, 0);
    __builtin_amdgcn_s_setprio(1);
#pragma unroll
    for (int m = 0; m < 4; ++m)
#pragma unroll
      for (int n = 0; n < 2; ++n) {
        acc[m + 4][n] = mfma16(a[m][0], b[n][0], acc[m + 4][n]);
        acc[m + 4][n] = mfma16(a[m][1], b[n][1], acc[m + 4][n]);
      }
    __builtin_amdgcn_s_setprio(0);
    asm volatile("s_barrier" ::: "memory");
    if (kt + 2 < NT) stageB(kt + 2, 1);
    __builtin_amdgcn_s_setprio(1);
#pragma unroll
    for (int m = 0; m < 4; ++m)
#pragma unroll
      for (int n = 2; n < 4; ++n) {
        acc[m + 4][n] = mfma16(a[m][0], b[n][0], acc[m + 4][n]);
        acc[m + 4][n] = mfma16(a[m][1], b[n][1], acc[m + 4][n]);
      }
    __builtin_amdgcn_s_setprio(0);
    if (kt + 2 < NT) { asm volatile("s_waitcnt vmcnt(4)" ::: "memory"); }
    else             { asm volatile("s_waitcnt vmcnt(0)" ::: "memory"); }
    asm volatile("s_barrier" ::: "memory");
  }

#pragma unroll
  for (int m = 0; m < 8; ++m) {
#pragma unroll
    for (int n = 0; n < 4; ++n) {
#pragma unroll
      for (int r = 0; r < 4; ++r) {
        const int row = row0 + wr * 128 + m * 16 + lq * 4 + r;
        const int col = col0 + wc * 64 + n * 16 + lr;
        const size_t o = (size_t)row * ldc + col;
        float v = acc[m][n][r];
        if (EPI == 0) Cb[o] = (short)f2bfu(v);
        else if (EPI == 1) Cf[o] = v + Res[o];
        else Cb[o] = (short)f2bfu(gelu_f(v));
      }
    }
  }
}

// ---------------- bf16 MFMA GEMM v11: 256x128 2-phase/K-tile, ring-3 LDS, vmcnt(6) --------
template <int EPI>
__global__ __launch_bounds__(512) void gemm11(const short* __restrict__ A,
                                              const short* __restrict__ Bt,
                                              float* __restrict__ Cf,
                                              short* __restrict__ Cb,
                                              const float* __restrict__ Res,
                                              int K, int lda, int ldb, int ldc, int nxt) {
  __shared__ __align__(16) short As[3][256 * 64];  // 96 KB ring-3
  __shared__ __align__(16) short Bs[3][128 * 64];  // 48 KB ring-3
  const int t = threadIdx.x;
  const int w = t >> 6, l = t & 63;
  const int lq = l >> 4, lr = l & 15;
  const int wr = w >> 2, wc = w & 3;
  const int nwg = gridDim.x;
  const int lgid = (blockIdx.x & 7) * (nwg >> 3) + (blockIdx.x >> 3);
  const int mt = lgid / nxt, nt_ = lgid % nxt;
  const int row0 = mt * 256, col0 = nt_ * 128;
  const int NT = K >> 6;
  f32x4 acc[8][2] = {};
  short8v a[4][2], b[2][2];

  auto stageA = [&](int kt, int hf) {
    const int s = kt % 3;
#pragma unroll
    for (int i = 0; i < 2; ++i) {
      const int c = t + i * 512;
      const int row = c >> 3, slot = c & 7;
      gl_lds16(A + (size_t)(row0 + hf * 128 + row) * lda + kt * 64 + ((slot ^ (row & 7)) << 3),
               &As[s][hf * 8192 + c * 8]);
    }
  };
  auto stageB = [&](int kt) {
    const int s = kt % 3;
#pragma unroll
    for (int i = 0; i < 2; ++i) {
      const int c = t + i * 512;
      const int row = c >> 3, slot = c & 7;
      gl_lds16(Bt + (size_t)(col0 + row) * ldb + kt * 64 + ((slot ^ (row & 7)) << 3),
               &Bs[s][c * 8]);
    }
  };
  auto rdA = [&](int s, int m, int ks) -> short8v {
    const int row = wr * 128 + m * 16 + lr;
    return *(const short8v*)&As[s][row * 64 + (((ks << 2) + lq) ^ (row & 7)) * 8];
  };
  auto rdB = [&](int s, int n, int ks) -> short8v {
    const int row = wc * 32 + n * 16 + lr;
    return *(const short8v*)&Bs[s][row * 64 + (((ks << 2) + lq) ^ (row & 7)) * 8];
  };

  stageA(0, 0); stageA(0, 1); stageB(0);
  stageA(1, 0); stageA(1, 1); stageB(1);
  asm volatile("s_waitcnt vmcnt(6)" ::: "memory");
  asm volatile("s_barrier" ::: "memory");

  for (int kt = 0; kt < NT; ++kt) {
    const int s = kt % 3;
#pragma unroll
    for (int m = 0; m < 4; ++m) { a[m][0] = rdA(s, m, 0); a[m][1] = rdA(s, m, 1); }
#pragma unroll
    for (int n = 0; n < 2; ++n) { b[n][0] = rdB(s, n, 0); b[n][1] = rdB(s, n, 1); }
    if (kt + 2 < NT) stageA(kt + 2, 0);
    __builtin_amdgcn_s_setprio(1);
#pragma unroll
    for (int m = 0; m < 4; ++m)
#pragma unroll
      for (int n = 0; n < 2; ++n) {
        acc[m][n] = mfma16(a[m][0], b[n][0], acc[m][n]);
        acc[m][n] = mfma16(a[m][1], b[n][1], acc[m][n]);
      }
    __builtin_amdgcn_s_setprio(0);
    asm volatile("s_barrier" ::: "memory");
#pragma unroll
    for (int m = 0; m < 4; ++m) { a[m][0] = rdA(s, m + 4, 0); a[m][1] = rdA(s, m + 4, 1); }
    if (kt + 2 < NT) { stageA(kt + 2, 1); stageB(kt + 2); }
    __builtin_amdgcn_s_setprio(1);
#pragma unroll
    for (int m = 0; m < 4; ++m)
#pragma unroll
      for (int n = 0; n < 2; ++n) {
        acc[m + 4][n] = mfma16(a[m][0], b[n][0], acc[m + 4][n]);
        acc[m + 4][n] = mfma16(a[m][1], b[n][1], acc[m + 4][n]);
      }
    __builtin_amdgcn_s_setprio(0);
    if (kt + 2 < NT) { asm volatile("s_waitcnt vmcnt(6)" ::: "memory"); }
    else             { asm volatile("s_waitcnt vmcnt(0)" ::: "memory"); }
    asm volatile("s_barrier" ::: "memory");
  }

#pragma unroll
  for (int m = 0; m < 8; ++m) {
#pragma unroll
    for (int n = 0; n < 2; ++n) {
#pragma unroll
      for (int r = 0; r < 4; ++r) {
        const int row = row0 + wr * 128 + m * 16 + lq * 4 + r;
        const int col = col0 + wc * 32 + n * 16 + lr;
        const size_t o = (size_t)row * ldc + col;
        float v = acc[m][n][r];
        if (EPI == 0) Cb[o] = (short)f2bfu(v);
        else if (EPI == 1) Cf[o] = v + Res[o];
        else Cb[o] = (short)f2bfu(gelu_f(v));
      }
    }
  }
}

// ---------------- bf16 MFMA GEMM v12: 128x128 2-phase/K-tile, ring-3 LDS, vmcnt(4) --------
template <int EPI>
__global__ __launch_bounds__(512) void gemm12(const short* __restrict__ A,
                                              const short* __restrict__ Bt,
                                              float* __restrict__ Cf,
                                              short* __restrict__ Cb,
                                              const float* __restrict__ Res,
                                              int K, int lda, int ldb, int ldc, int nxt) {
  __shared__ __align__(16) short As[3][128 * 64];  // 48 KB ring-3
  __shared__ __align__(16) short Bs[3][128 * 64];  // 48 KB ring-3
  const int t = threadIdx.x;
  const int w = t >> 6, l = t & 63;
  const int lq = l >> 4, lr = l & 15;
  const int wr = w >> 2, wc = w & 3;
  const int nwg = gridDim.x;
  const int lgid = (blockIdx.x & 7) * (nwg >> 3) + (blockIdx.x >> 3);
  const int mt = lgid / nxt, nt_ = lgid % nxt;
  const int row0 = mt * 128, col0 = nt_ * 128;
  const int NT = K >> 6;
  f32x4 acc[4][2] = {};
  short8v a[4][2], b[2][2];

  auto stageA = [&](int kt) {
    const int s = kt % 3;
#pragma unroll
    for (int i = 0; i < 2; ++i) {
      const int c = t + i * 512;
      const int row = c >> 3, slot = c & 7;
      gl_lds16(A + (size_t)(row0 + row) * lda + kt * 64 + ((slot ^ (row & 7)) << 3),
               &As[s][c * 8]);
    }
  };
  auto stageB = [&](int kt) {
    const int s = kt % 3;
#pragma unroll
    for (int i = 0; i < 2; ++i) {
      const int c = t + i * 512;
      const int row = c >> 3, slot = c & 7;
      gl_lds16(Bt + (size_t)(col0 + row) * ldb + kt * 64 + ((slot ^ (row & 7)) << 3),
               &Bs[s][c * 8]);
    }
  };
  auto rdA = [&](int s, int m, int ks) -> short8v {
    const int row = wr * 64 + m * 16 + lr;
    return *(const short8v*)&As[s][row * 64 + (((ks << 2) + lq) ^ (row & 7)) * 8];
  };
  auto rdB = [&](int s, int n, int ks) -> short8v {
    const int row = wc * 32 + n * 16 + lr;
    return *(const short8v*)&Bs[s][row * 64 + (((ks << 2) + lq) ^ (row & 7)) * 8];
  };

  stageA(0); stageB(0);
  stageA(1); stageB(1);
  asm volatile("s_waitcnt vmcnt(4)" ::: "memory");
  asm volatile("s_barrier" ::: "memory");

  for (int kt = 0; kt < NT; ++kt) {
    const int s = kt % 3;
#pragma unroll
    for (int m = 0; m < 4; ++m) { a[m][0] = rdA(s, m, 0); a[m][1] = rdA(s, m, 1); }
#pragma unroll
    for (int n = 0; n < 2; ++n) { b[n][0] = rdB(s, n, 0); b[n][1] = rdB(s, n, 1); }
    if (kt + 2 < NT) stageA(kt + 2);
    __builtin_amdgcn_s_setprio(1);
#pragma unroll
    for (int m = 0; m < 2; ++m)
#pragma unroll
      for (int n = 0; n < 2; ++n) {
        acc[m][n] = mfma16(a[m][0], b[n][0], acc[m][n]);
        acc[m][n] = mfma16(a[m][1], b[n][1], acc[m][n]);
      }
    __builtin_amdgcn_s_setprio(0);
    asm volatile("s_barrier" ::: "memory");
    if (kt + 2 < NT) stageB(kt + 2);
    __builtin_amdgcn_s_setprio(1);
#pragma unroll
    for (int m = 2; m < 4; ++m)
#pragma unroll
      for (int n = 0; n < 2; ++n) {
        acc[m][n] = mfma16(a[m][0], b[n][0], acc[m][n]);
        acc[m][n] = mfma16(a[m][1], b[n][1], acc[m][n]);
      }
    __builtin_amdgcn_s_setprio(0);
    if (kt + 2 < NT) { asm volatile("s_waitcnt vmcnt(4)" ::: "memory"); }
    else             { asm volatile("s_waitcnt vmcnt(0)" ::: "memory"); }
    asm volatile("s_barrier" ::: "memory");
  }

#pragma unroll
  for (int m = 0; m < 4; ++m) {
#pragma unroll
    for (int n = 0; n < 2; ++n) {
#pragma unroll
      for (int r = 0; r < 4; ++r) {
        const int row = row0 + wr * 64 + m * 16 + lq * 4 + r;
        const int col = col0 + wc * 32 + n * 16 + lr;
        const size_t o = (size_t)row * ldc + col;
        float v = acc[m][n][r];
        if (EPI == 0) Cb[o] = (short)f2bfu(v);
        else if (EPI == 1) Cf[o] = v + Res[o];
        else Cb[o] = (short)f2bfu(gelu_f(v));
      }
    }
  }
}

// ---------------- Retention v5: fused GN+gate, paired q-blocks (qb,15-qb), QBLK=64 --------
__global__ __launch_bounds__(256) void ret5_kernel(const short* __restrict__ QKVGb,
                                                   const short* __restrict__ Vt,
                                                   short* __restrict__ Gb,
                                                   const float* __restrict__ gs,
                                                   const float* __restrict__ gb) {
  __shared__ __align__(16) short Ks[2][64 * 128];
  __shared__ __align__(16) short Vs[2][128 * 64];
  const int t = threadIdx.x, w = t >> 6, l = t & 63;
  const int lq = l >> 4, lr = l & 15;
  const int u = blockIdx.x;                     // 0..255
  const int lgid = (u & 7) * 32 + (u >> 3);     // XCD-contiguous
  const int bh = lgid >> 3, pr = lgid & 7;
  const int b = bh >> 3, h = bh & 7;
  const float lstep = (logf(1.f / 512.f) - logf(1.f / 32.f)) * (1.f / 7.f);
  const float gamma = 1.f - expf(logf(1.f / 32.f) + (float)h * lstep);
  const float l2g = logf(gamma) * 1.44269504f;
  const short* Qp = QKVGb;
  const short* Kp = QKVGb + 1024;

  float cmf[4], csr[4];
#pragma unroll
  for (int mf = 0; mf < 4; ++mf) cmf[mf] = exp2f(l2g * (float)(-16 * mf));
#pragma unroll
  for (int r = 0; r < 4; ++r) csr[r] = exp2f(l2g * (float)(63 - 4 * lq - r));
  float gsv[8], gbv[8];
#pragma unroll
  for (int nd = 0; nd < 8; ++nd) {
    gsv[nd] = gs[h * DHd + nd * 16 + lr];
    gbv[nd] = gb[h * DHd + nd * 16 + lr];
  }
  const int sb = ((lq & 1) * 2) * 16 + lr;

  auto stageKV = [&](int m0, int buf) {
#pragma unroll
    for (int i = 0; i < 4; ++i) {
      const int c = (w * 4 + i) * 64 + l;
      const int row = c >> 4, slot = c & 15;
      gl_lds16(Kp + (size_t)(b * Ss + m0 + row) * LDQ + h * DHd + ((slot ^ (row & 7)) * 8),
               &Ks[buf][(w * 4 + i) * 512]);
    }
#pragma unroll
    for (int i = 0; i < 4; ++i) {
      const int c = (w * 4 + i) * 64 + l;
      const int row = c >> 3, slot = c & 7;
      gl_lds16(Vt + (size_t)(bh * DHd + row) * Ss + m0 + ((slot ^ (row & 7)) * 8),
               &Vs[buf][(w * 4 + i) * 512]);
    }
  };

  for (int pass = 0; pass < 2; ++pass) {
    const int qb = pass ? (15 - pr) : pr;
    const int q0 = qb * 64;
    const int nt = qb + 1;
    short8v qf[4];
#pragma unroll
    for (int ks = 0; ks < 4; ++ks)
      qf[ks] = *(const short8v*)(Qp + (size_t)(b * Ss + q0 + w * 16 + lr) * LDQ +
                                 h * DHd + ks * 32 + lq * 8);
    f32x4 yacc[8] = {};
    stageKV(0, 0);
    __syncthreads();
    int cur = 0;
    for (int tt = 0; tt < nt; ++tt) {
      const int m0 = tt * 64;
      if (tt + 1 < nt) stageKV((tt + 1) * 64, cur ^ 1);

      f32x4 st[4] = {};
      __builtin_amdgcn_s_setprio(1);
#pragma unroll
      for (int mf = 0; mf < 4; ++mf) {
        const int row = mf * 16 + lr;
#pragma unroll
        for (int ks = 0; ks < 4; ++ks) {
          short8v kf = *(const short8v*)&Ks[cur][row * 128 + (((4 * ks + lq) ^ (row & 7)) * 8)];
          st[mf] = mfma16(kf, qf[ks], st[mf]);
        }
      }
      __builtin_amdgcn_s_setprio(0);
      const int qg = q0 + w * 16 + lr;
      const float rs = exp2f(l2g * (float)(qg - m0 - 63));
#pragma unroll
      for (int mf = 0; mf < 4; ++mf)
#pragma unroll
        for (int r = 0; r < 4; ++r) {
          const int kvg = m0 + mf * 16 + lq * 4 + r;
          const float wgt = (qg >= kvg) ? rs * cmf[mf] * csr[r] : 0.f;
          st[mf][r] *= wgt;
        }
      unsigned pk[4][2];
#pragma unroll
      for (int mf = 0; mf < 4; ++mf)
#pragma unroll
        for (int p = 0; p < 2; ++p)
          pk[mf][p] = (unsigned)f2bfu(st[mf][2 * p]) |
                      ((unsigned)f2bfu(st[mf][2 * p + 1]) << 16);
      short8v afr[2];
#pragma unroll
      for (int ks2 = 0; ks2 < 2; ++ks2) {
        u32x4 wd;
#pragma unroll
        for (int wj = 0; wj < 4; ++wj) {
          const int src = sb + (wj >> 1) * 16;
          const unsigned v0 = __shfl(pk[2 * ks2 + 0][wj & 1], src);
          const unsigned v1 = __shfl(pk[2 * ks2 + 1][wj & 1], src);
          wd[wj] = (lq >= 2) ? v1 : v0;
        }
        afr[ks2] = __builtin_bit_cast(short8v, wd);
      }
      __builtin_amdgcn_s_setprio(1);
#pragma unroll
      for (int nd = 0; nd < 8; ++nd) {
        const int row = nd * 16 + lr;
#pragma unroll
        for (int ks2 = 0; ks2 < 2; ++ks2) {
          short8v vf = *(const short8v*)&Vs[cur][row * 64 + (((4 * ks2 + lq) ^ (row & 7)) * 8)];
          yacc[nd] = mfma16(afr[ks2], vf, yacc[nd]);
        }
      }
      __builtin_amdgcn_s_setprio(0);
      __syncthreads();
      cur ^= 1;
    }
    // fused GroupNorm + gate epilogue
#pragma unroll
    for (int r = 0; r < 4; ++r) {
      float s1 = 0.f, s2 = 0.f;
#pragma unroll
      for (int nd = 0; nd < 8; ++nd) { const float v = yacc[nd][r]; s1 += v; s2 += v * v; }
#pragma unroll
      for (int msk = 1; msk < 16; msk <<= 1) {
        s1 += __shfl_xor(s1, msk);
        s2 += __shfl_xor(s2, msk);
      }
      const float mu = s1 * (1.f / 128.f);
      const float rstd = rsqrtf(s2 * (1.f / 128.f) - mu * mu + EPSf);
      const int q = q0 + w * 16 + lq * 4 + r;
      const size_t gbase = (size_t)(b * Ss + q) * LDQ + 3072 + h * DHd;
      const size_t obase = (size_t)(b * Ss + q) * Dd + h * DHd;
#pragma unroll
      for (int nd = 0; nd < 8; ++nd) {
        const int d = nd * 16 + lr;
        const float yv = (yacc[nd][r] - mu) * rstd * gsv[nd] + gbv[nd];
        const float gvx = bfu2f((unsigned short)QKVGb[gbase + d]);
        Gb[obase + d] = (short)f2bfu(swish_f(gvx) * yv);
      }
    }
  }
}

extern "C" void kernel_launch(void* const* d_in, const int* in_sizes, int n_in,
                              void* d_out, int out_size, void* d_ws, size_t ws_size,
                              hipStream_t stream) {
  const float* X = (const float*)d_in[0];
  const float* Wq = (const float*)d_in[1];
  const float* Wk = (const float*)d_in[2];
  const float* Wv = (const float*)d_in[3];
  const float* Wg = (const float*)d_in[4];
  const float* Wo = (const float*)d_in[5];
  const float* W1 = (const float*)d_in[6];
  const float* W2 = (const float*)d_in[7];
  const float* lns = (const float*)d_in[8];
  const float* lnb = (const float*)d_in[9];
  const float* gns = (const float*)d_in[10];
  const float* gnb = (const float*)d_in[11];
  float* out = (float*)d_out;

  char* W = (char*)d_ws;
  const size_t MB = 1u << 20;
  float* Abuf  = (float*)(W);             // 16 MB fp32
  short* Xnb   = (short*)(W + 16 * MB);   // 8 MB bf16
  short* QKVGb = (short*)(W + 24 * MB);   // 32 MB bf16 [4096][4096]; Hb aliases first 16 MB
  short* Vtb   = (short*)(W + 88 * MB);   // 8 MB bf16
  short* Gb    = (short*)(W + 96 * MB);   // 8 MB bf16
  short* Wqkvgt= (short*)(W + 104 * MB);  // 8 MB
  short* Wot   = (short*)(W + 112 * MB);  // 2 MB
  short* W1t   = (short*)(W + 114 * MB);  // 4 MB
  short* W2t   = (short*)(W + 118 * MB);  // 4 MB
  float* ct    = (float*)(W + 122 * MB);  // 256 KB
  float* st    = ct + Ss * 64;            // 256 KB
  short* Hb = QKVGb;  // FFN hidden 4096x2048 bf16 (16 MB)

  rope_table_kernel<<<(Ss * 64) / 256, 256, 0, stream>>>(ct, st);

  for (int l = 0; l < LAYERS; ++l) {
    const size_t DD = (size_t)Dd * Dd;
    const float* Acur = (l == 0) ? X : Abuf;  // residual stream input for this layer
    // merged: weight transposes + LN(Acur) in one dispatch
    wtrans_ln_kernel<<<13312, 256, 0, stream>>>(Wq + l * DD, Wk + l * DD, Wv + l * DD,
                                                Wg + l * DD, Wo + l * DD,
                                                W1 + (size_t)l * Dd * Ff,
                                                W2 + (size_t)l * Ff * Dd,
                                                Wqkvgt, Wot, W1t, W2t,
                                                Acur, Xnb, lns, lnb);
    // fused QKVG projection (8-phase 256x256)
    gemm10<0><<<dim3(16, 16), 512, 0, stream>>>(Xnb, Wqkvgt, nullptr, QKVGb,
                                                nullptr, 4096, Dd, LDQ);
    // merged RoPE (in-place Q,K) + V transpose
    rvt_kernel<<<12288, 256, 0, stream>>>(QKVGb, Vtb, ct, st);
    // retention + fused GN/gate -> Gb (bf16)
    ret5_kernel<<<256, 256, 0, stream>>>(QKVGb, Vtb, Gb,
                                         gns + (size_t)l * Dd, gnb + (size_t)l * Dd);
    // A = (Gb @ Wo) + Acur
    gemm12<1><<<256, 512, 0, stream>>>(Gb, Wot, Abuf, nullptr, Acur,
                                       Dd, Dd, Dd, Dd, 8);
    // FFN
    ln_bf16_kernel<<<Mm, 256, 0, stream>>>(Abuf, Xnb, lns, lnb);
    gemm11<2><<<256, 512, 0, stream>>>(Xnb, W1t, nullptr, Hb, nullptr,
                                       Dd, Dd, Dd, Ff, 16);
    float* dst = (l == LAYERS - 1) ? out : Abuf;
    gemm12<1><<<256, 512, 0, stream>>>(Hb, W2t, dst, nullptr, Abuf,
                                       Ff, Ff, Ff, Dd, 8);
  }
}

// Round 19
// 685.619 us; speedup vs baseline: 1.6861x; 1.0229x over previous
//
#include <hip/hip_runtime.h>
#include <hip/hip_bf16.h>
#include <cmath>

#define LAYERS 4
#define Bb 4
#define Ss 1024
#define Dd 1024
#define Ff 2048
#define Hh 8
#define DHd 128
#define Mm (Bb * Ss)   // 4096 rows
#define EPSf 1e-5f
#define LDQ 4096       // combined QKVG row stride

typedef __attribute__((ext_vector_type(8))) short short8v;
typedef __attribute__((ext_vector_type(4))) float f32x4;
typedef __attribute__((ext_vector_type(4))) unsigned int u32x4;

__device__ __forceinline__ float swish_f(float x) { return x / (1.f + expf(-x)); }
__device__ __forceinline__ float gelu_f(float x) {
  return 0.5f * x * (1.f + tanhf(0.7978845608028654f * (x + 0.044715f * x * x * x)));
}
__device__ __forceinline__ unsigned short f2bfu(float f) {
  __hip_bfloat16 h = __float2bfloat16(f);
  return __builtin_bit_cast(unsigned short, h);
}
__device__ __forceinline__ float bfu2f(unsigned short u) {
  unsigned v = ((unsigned)u) << 16;
  return __builtin_bit_cast(float, v);
}
__device__ __forceinline__ void gl_lds16(const void* g, void* l) {
  __builtin_amdgcn_global_load_lds((__attribute__((address_space(1))) void*)g,
                                   (__attribute__((address_space(3))) void*)l, 16, 0, 0);
}
__device__ __forceinline__ f32x4 mfma16(short8v a, short8v b, f32x4 c) {
  return __builtin_amdgcn_mfma_f32_16x16x32_bf16(a, b, c, 0, 0, 0);
}

// ---------------- LayerNorm fp32 -> bf16 (standalone, used for FFN LN) ----------------
__global__ __launch_bounds__(256) void ln_bf16_kernel(const float* __restrict__ x,
                                                      short* __restrict__ outb,
                                                      const float* __restrict__ sc,
                                                      const float* __restrict__ bi) {
  const int row = blockIdx.x;
  const int t = threadIdx.x;
  const float4 v = *(const float4*)(x + (size_t)row * Dd + t * 4);
  float s = v.x + v.y + v.z + v.w;
  float s2 = v.x * v.x + v.y * v.y + v.z * v.z + v.w * v.w;
#pragma unroll
  for (int o = 32; o > 0; o >>= 1) { s += __shfl_down(s, o); s2 += __shfl_down(s2, o); }
  __shared__ float ps[4], ps2[4];
  if ((t & 63) == 0) { ps[t >> 6] = s; ps2[t >> 6] = s2; }
  __syncthreads();
  s = ps[0] + ps[1] + ps[2] + ps[3];
  s2 = ps2[0] + ps2[1] + ps2[2] + ps2[3];
  const float mu = s * (1.f / Dd);
  const float var = s2 * (1.f / Dd) - mu * mu;
  const float rstd = rsqrtf(var + EPSf);
  const float4 g = *(const float4*)(sc + t * 4);
  const float4 b = *(const float4*)(bi + t * 4);
  const float o0 = (v.x - mu) * rstd * g.x + b.x;
  const float o1 = (v.y - mu) * rstd * g.y + b.y;
  const float o2 = (v.z - mu) * rstd * g.z + b.z;
  const float o3 = (v.w - mu) * rstd * g.w + b.w;
  unsigned p0 = (unsigned)f2bfu(o0) | ((unsigned)f2bfu(o1) << 16);
  unsigned p1 = (unsigned)f2bfu(o2) | ((unsigned)f2bfu(o3) << 16);
  uint2 pk; pk.x = p0; pk.y = p1;
  *(uint2*)(outb + (size_t)row * Dd + t * 4) = pk;
}

// ---------------- RoPE tables ----------------
__global__ void rope_table_kernel(float* __restrict__ ct, float* __restrict__ st) {
  const int i = blockIdx.x * 256 + threadIdx.x;  // < Ss*64
  const int s = i >> 6, f = i & 63;
  const float inv = powf(10000.f, -(float)f / 64.f);
  const float a = (float)s * inv;
  ct[i] = cosf(a);
  st[i] = sinf(a);
}

// ---------------- merged weight transpose + LN(Acur): one dispatch (13312 blocks) --------
__global__ __launch_bounds__(256) void wtrans_ln_kernel(
    const float* __restrict__ Wq, const float* __restrict__ Wk,
    const float* __restrict__ Wv, const float* __restrict__ Wg,
    const float* __restrict__ Wo, const float* __restrict__ W1,
    const float* __restrict__ W2,
    short* __restrict__ Wqkvgt, short* __restrict__ Wot,
    short* __restrict__ W1t, short* __restrict__ W2t,
    const float* __restrict__ x, short* __restrict__ outb,
    const float* __restrict__ sc, const float* __restrict__ bi) {
  __shared__ float tile[32][33];
  __shared__ float ps[4], ps2[4];
  const int t = threadIdx.x;
  const int blk = blockIdx.x;
  if (blk >= 9216) {
    const int row = blk - 9216;
    const float4 v = *(const float4*)(x + (size_t)row * Dd + t * 4);
    float s = v.x + v.y + v.z + v.w;
    float s2 = v.x * v.x + v.y * v.y + v.z * v.z + v.w * v.w;
#pragma unroll
    for (int o = 32; o > 0; o >>= 1) { s += __shfl_down(s, o); s2 += __shfl_down(s2, o); }
    if ((t & 63) == 0) { ps[t >> 6] = s; ps2[t >> 6] = s2; }
    __syncthreads();
    s = ps[0] + ps[1] + ps[2] + ps[3];
    s2 = ps2[0] + ps2[1] + ps2[2] + ps2[3];
    const float mu = s * (1.f / Dd);
    const float var = s2 * (1.f / Dd) - mu * mu;
    const float rstd = rsqrtf(var + EPSf);
    const float4 g = *(const float4*)(sc + t * 4);
    const float4 b = *(const float4*)(bi + t * 4);
    const float o0 = (v.x - mu) * rstd * g.x + b.x;
    const float o1 = (v.y - mu) * rstd * g.y + b.y;
    const float o2 = (v.z - mu) * rstd * g.z + b.z;
    const float o3 = (v.w - mu) * rstd * g.w + b.w;
    unsigned p0 = (unsigned)f2bfu(o0) | ((unsigned)f2bfu(o1) << 16);
    unsigned p1 = (unsigned)f2bfu(o2) | ((unsigned)f2bfu(o3) << 16);
    uint2 pk; pk.x = p0; pk.y = p1;
    *(uint2*)(outb + (size_t)row * Dd + t * 4) = pk;
    return;
  }
  const int tc = t & 31, tr8 = t >> 5;
  const float* src; short* dst; int K, N, n0, k0, nl;
  if (blk < 4096) {
    const int bx = blk & 127, ky = blk >> 7;
    n0 = bx * 32; k0 = ky * 32;
    const int which = n0 >> 10;
    src = (which == 0) ? Wq : (which == 1) ? Wk : (which == 2) ? Wv : Wg;
    nl = n0 & 1023; N = 1024; K = 1024; dst = Wqkvgt;
  } else if (blk < 5120) {
    const int b2 = blk - 4096;
    n0 = (b2 & 31) * 32; k0 = (b2 >> 5) * 32; nl = n0;
    src = Wo; N = 1024; K = 1024; dst = Wot;
  } else if (blk < 7168) {
    const int b2 = blk - 5120;
    n0 = (b2 & 63) * 32; k0 = (b2 >> 6) * 32; nl = n0;
    src = W1; N = 2048; K = 1024; dst = W1t;
  } else {
    const int b2 = blk - 7168;
    n0 = (b2 & 31) * 32; k0 = (b2 >> 5) * 32; nl = n0;
    src = W2; N = 1024; K = 2048; dst = W2t;
  }
#pragma unroll
  for (int i = 0; i < 4; ++i) {
    const int r = tr8 + i * 8;
    tile[r][tc] = src[(size_t)(k0 + r) * N + nl + tc];
  }
  __syncthreads();
#pragma unroll
  for (int i = 0; i < 4; ++i) {
    const int r = tr8 + i * 8;
    dst[(size_t)(n0 + r) * K + k0 + tc] = (short)f2bfu(tile[tc][r]);
  }
}

// ---------------- RoPE in-place on Q,K slices: 8192 blocks (V^T now made by gemm10) ------
__global__ __launch_bounds__(256) void rope_qk_kernel(short* __restrict__ QKVGb,
                                                      const float* __restrict__ ct,
                                                      const float* __restrict__ st) {
  const int idx = blockIdx.x * 256 + threadIdx.x;
  const int f = idx & 63;
  const int h = (idx >> 6) & 7;
  const int r = idx >> 9;            // b*S+s
  const int s = r & (Ss - 1);
  const float c = ct[(s << 6) + f], sn = st[(s << 6) + f];
  const size_t qo = (size_t)r * LDQ + h * DHd + 2 * f;
  const unsigned qp = *(const unsigned*)(QKVGb + qo);
  const unsigned kp = *(const unsigned*)(QKVGb + qo + 1024);
  const float qx = bfu2f((unsigned short)(qp & 0xffff)), qy = bfu2f((unsigned short)(qp >> 16));
  const float kx = bfu2f((unsigned short)(kp & 0xffff)), ky = bfu2f((unsigned short)(kp >> 16));
  const unsigned qn = (unsigned)f2bfu(qx * c - qy * sn) |
                      ((unsigned)f2bfu(qx * sn + qy * c) << 16);
  const unsigned kn = (unsigned)f2bfu(kx * c + ky * sn) |
                      ((unsigned)f2bfu(-kx * sn + ky * c) << 16);
  *(unsigned*)(QKVGb + qo) = qn;
  *(unsigned*)(QKVGb + qo + 1024) = kn;
}

// ---------------- bf16 MFMA GEMM v10v: 256x256 8-phase + direct V^T epilogue --------------
// V-column blocks (col0 in [2048,3072)) transpose their tile through the (dead) LDS and
// write Vt directly; V slice of QKVGb is never written (nothing reads it).
template <int EPI>
__global__ __launch_bounds__(512, 2) void gemm10(const short* __restrict__ A,
                                                 const short* __restrict__ Bt,
                                                 float* __restrict__ Cf,
                                                 short* __restrict__ Cb,
                                                 const float* __restrict__ Res,
                                                 short* __restrict__ Vt,
                                                 int N, int K, int ldc) {
  __shared__ __align__(16) short SM[65536];   // 128 KB: As = SM[0..32767], Bs = SM[32768..]
  const int t = threadIdx.x;
  const int w = t >> 6, l = t & 63;
  const int lq = l >> 4, lr = l & 15;
  const int wr = w >> 2, wc = w & 3;
  const int bhalf = wc >> 1, brow0 = (wc & 1) * 64;
  const int nwg = gridDim.x * gridDim.y;
  const int bid0 = blockIdx.x + blockIdx.y * gridDim.x;
  const int lgid = (bid0 & 7) * (nwg >> 3) + (bid0 >> 3);
  const int bx = lgid % gridDim.x, by = lgid / gridDim.x;
  const int row0 = by * 256, col0 = bx * 256;
  const int NT = K >> 6;

  f32x4 acc[8][4] = {};
  short8v a[4][2], b[4][2];

  auto stageA = [&](int kt, int hf) {
    const int db = kt & 1;
    short* dstb = SM + (db * 2 + hf) * 8192;
#pragma unroll
    for (int i = 0; i < 2; ++i) {
      const int c = t + i * 512;
      const int row = c >> 3, slot = c & 7;
      gl_lds16(A + (size_t)(row0 + hf * 128 + row) * K + kt * 64 + ((slot ^ (row & 7)) << 3),
               dstb + c * 8);
    }
  };
  auto stageB = [&](int kt, int hf) {
    const int db = kt & 1;
    short* dstb = SM + 32768 + (db * 2 + hf) * 8192;
#pragma unroll
    for (int i = 0; i < 2; ++i) {
      const int c = t + i * 512;
      const int row = c >> 3, slot = c & 7;
      gl_lds16(Bt + (size_t)(col0 + hf * 128 + row) * K + kt * 64 + ((slot ^ (row & 7)) << 3),
               dstb + c * 8);
    }
  };
  auto rdA = [&](int db, int m, int ks) -> short8v {
    const int row = m * 16 + lr;
    return *(const short8v*)(SM + (db * 2 + wr) * 8192 + row * 64 +
                             (((ks << 2) + lq) ^ (row & 7)) * 8);
  };
  auto rdB = [&](int db, int n, int ks) -> short8v {
    const int row = brow0 + n * 16 + lr;
    return *(const short8v*)(SM + 32768 + (db * 2 + bhalf) * 8192 + row * 64 +
                             (((ks << 2) + lq) ^ (row & 7)) * 8);
  };

  stageA(0, 0); stageA(0, 1); stageB(0, 0); stageB(0, 1);
  if (NT > 1) { stageB(1, 0); stageB(1, 1); }
  if (NT > 1) { asm volatile("s_waitcnt vmcnt(4)" ::: "memory"); }
  else        { asm volatile("s_waitcnt vmcnt(0)" ::: "memory"); }
  asm volatile("s_barrier" ::: "memory");

  for (int kt = 0; kt < NT; ++kt) {
    const int db = kt & 1;
#pragma unroll
    for (int m = 0; m < 4; ++m) { a[m][0] = rdA(db, m, 0); a[m][1] = rdA(db, m, 1); }
#pragma unroll
    for (int n = 0; n < 2; ++n) { b[n][0] = rdB(db, n, 0); b[n][1] = rdB(db, n, 1); }
    if (kt + 1 < NT) stageA(kt + 1, 0);
    __builtin_amdgcn_s_setprio(1);
#pragma unroll
    for (int m = 0; m < 4; ++m)
#pragma unroll
      for (int n = 0; n < 2; ++n) {
        acc[m][n] = mfma16(a[m][0], b[n][0], acc[m][n]);
        acc[m][n] = mfma16(a[m][1], b[n][1], acc[m][n]);
      }
    __builtin_amdgcn_s_setprio(0);
    asm volatile("s_barrier" ::: "memory");
#pragma unroll
    for (int n = 2; n < 4; ++n) { b[n][0] = rdB(db, n, 0); b[n][1] = rdB(db, n, 1); }
    if (kt + 1 < NT) stageA(kt + 1, 1);
    __builtin_amdgcn_s_setprio(1);
#pragma unroll
    for (int m = 0; m < 4; ++m)
#pragma unroll
      for (int n = 2; n < 4; ++n) {
        acc[m][n] = mfma16(a[m][0], b[n][0], acc[m][n]);
        acc[m][n] = mfma16(a[m][1], b[n][1], acc[m][n]);
      }
    __builtin_amdgcn_s_setprio(0);
    asm volatile("s_barrier" ::: "memory");
#pragma unroll
    for (int m = 0; m < 4; ++m) { a[m][0] = rdA(db, m + 4, 0); a[m][1] = rdA(db, m + 4, 1); }
    if (kt + 2 < NT) stageB(kt + 2, 0);
    __builtin_amdgcn_s_setprio(1);
#pragma unroll
    for (int m = 0; m < 4; ++m)
#pragma unroll
      for (int n = 0; n < 2; ++n) {
        acc[m + 4][n] = mfma16(a[m][0], b[n][0], acc[m + 4][n]);
        acc[m + 4][n] = mfma16(a[m][1], b[n][1], acc[m + 4][n]);
      }
    __builtin_amdgcn_s_setprio(0);
    asm volatile("s_barrier" ::: "memory");
    if (kt + 2 < NT) stageB(kt + 2, 1);
    __builtin_amdgcn_s_setprio(1);
#pragma unroll
    for (int m = 0; m < 4; ++m)
#pragma unroll
      for (int n = 2; n < 4; ++n) {
        acc[m + 4][n] = mfma16(a[m][0], b[n][0], acc[m + 4][n]);
        acc[m + 4][n] = mfma16(a[m][1], b[n][1], acc[m + 4][n]);
      }
    __builtin_amdgcn_s_setprio(0);
    if (kt + 2 < NT) { asm volatile("s_waitcnt vmcnt(4)" ::: "memory"); }
    else             { asm volatile("s_waitcnt vmcnt(0)" ::: "memory"); }
    asm volatile("s_barrier" ::: "memory");
  }

  if (EPI == 0 && col0 >= 2048 && col0 < 3072) {
    // V-block: transpose through (now dead) LDS, write Vt directly.
    // SM layout: Ts[d][s] bf16, chunk-XOR swizzle: elem(s) at ((s>>3)^(d&31))*8 + (s&7).
#pragma unroll
    for (int m = 0; m < 8; ++m)
#pragma unroll
      for (int n = 0; n < 4; ++n)
#pragma unroll
        for (int r = 0; r < 4; ++r) {
          const int ls = wr * 128 + m * 16 + lq * 4 + r;  // local s
          const int ld = wc * 64 + n * 16 + lr;           // local d
          SM[ld * 256 + ((((ls >> 3) ^ (ld & 31)) << 3) | (ls & 7))] =
              (short)f2bfu(acc[m][n][r]);
        }
    __syncthreads();
    const int bI = row0 >> 10;       // batch index (Ss = 1024, row0 multiple of 256)
    const int s0g = row0 & 1023;
#pragma unroll 4
    for (int rr = 0; rr < 32; ++rr) {
      const int dl = w * 32 + rr;
      const int gcol = (col0 - 2048) + dl;   // 0..1023
      const int hh = gcol >> 7, dh = gcol & 127;
      unsigned pk0, pk1;
      {
        const int s0 = l * 4;
        const unsigned short e0 =
            (unsigned short)SM[dl * 256 + ((((s0 + 0) >> 3) ^ (dl & 31)) << 3 | ((s0 + 0) & 7))];
        const unsigned short e1 =
            (unsigned short)SM[dl * 256 + ((((s0 + 1) >> 3) ^ (dl & 31)) << 3 | ((s0 + 1) & 7))];
        const unsigned short e2 =
            (unsigned short)SM[dl * 256 + ((((s0 + 2) >> 3) ^ (dl & 31)) << 3 | ((s0 + 2) & 7))];
        const unsigned short e3 =
            (unsigned short)SM[dl * 256 + ((((s0 + 3) >> 3) ^ (dl & 31)) << 3 | ((s0 + 3) & 7))];
        pk0 = (unsigned)e0 | ((unsigned)e1 << 16);
        pk1 = (unsigned)e2 | ((unsigned)e3 << 16);
      }
      uint2 pk; pk.x = pk0; pk.y = pk1;
      *(uint2*)(Vt + ((size_t)((bI * 8 + hh) * 128 + dh)) * Ss + s0g + l * 4) = pk;
    }
    return;
  }

#pragma unroll
  for (int m = 0; m < 8; ++m) {
#pragma unroll
    for (int n = 0; n < 4; ++n) {
#pragma unroll
      for (int r = 0; r < 4; ++r) {
        const int row = row0 + wr * 128 + m * 16 + lq * 4 + r;
        const int col = col0 + wc * 64 + n * 16 + lr;
        const size_t o = (size_t)row * ldc + col;
        float v = acc[m][n][r];
        if (EPI == 0) Cb[o] = (short)f2bfu(v);
        else if (EPI == 1) Cf[o] = v + Res[o];
        else Cb[o] = (short)f2bfu(gelu_f(v));
      }
    }
  }
}

// ---------------- bf16 MFMA GEMM v11: 256x128 2-phase/K-tile, ring-3 LDS, vmcnt(6) --------
template <int EPI>
__global__ __launch_bounds__(512) void gemm11(const short* __restrict__ A,
                                              const short* __restrict__ Bt,
                                              float* __restrict__ Cf,
                                              short* __restrict__ Cb,
                                              const float* __restrict__ Res,
                                              int K, int lda, int ldb, int ldc, int nxt) {
  __shared__ __align__(16) short As[3][256 * 64];  // 96 KB ring-3
  __shared__ __align__(16) short Bs[3][128 * 64];  // 48 KB ring-3
  const int t = threadIdx.x;
  const int w = t >> 6, l = t & 63;
  const int lq = l >> 4, lr = l & 15;
  const int wr = w >> 2, wc = w & 3;
  const int nwg = gridDim.x;
  const int lgid = (blockIdx.x & 7) * (nwg >> 3) + (blockIdx.x >> 3);
  const int mt = lgid / nxt, nt_ = lgid % nxt;
  const int row0 = mt * 256, col0 = nt_ * 128;
  const int NT = K >> 6;
  f32x4 acc[8][2] = {};
  short8v a[4][2], b[2][2];

  auto stageA = [&](int kt, int hf) {
    const int s = kt % 3;
#pragma unroll
    for (int i = 0; i < 2; ++i) {
      const int c = t + i * 512;
      const int row = c >> 3, slot = c & 7;
      gl_lds16(A + (size_t)(row0 + hf * 128 + row) * lda + kt * 64 + ((slot ^ (row & 7)) << 3),
               &As[s][hf * 8192 + c * 8]);
    }
  };
  auto stageB = [&](int kt) {
    const int s = kt % 3;
#pragma unroll
    for (int i = 0; i < 2; ++i) {
      const int c = t + i * 512;
      const int row = c >> 3, slot = c & 7;
      gl_lds16(Bt + (size_t)(col0 + row) * ldb + kt * 64 + ((slot ^ (row & 7)) << 3),
               &Bs[s][c * 8]);
    }
  };
  auto rdA = [&](int s, int m, int ks) -> short8v {
    const int row = wr * 128 + m * 16 + lr;
    return *(const short8v*)&As[s][row * 64 + (((ks << 2) + lq) ^ (row & 7)) * 8];
  };
  auto rdB = [&](int s, int n, int ks) -> short8v {
    const int row = wc * 32 + n * 16 + lr;
    return *(const short8v*)&Bs[s][row * 64 + (((ks << 2) + lq) ^ (row & 7)) * 8];
  };

  stageA(0, 0); stageA(0, 1); stageB(0);
  stageA(1, 0); stageA(1, 1); stageB(1);
  asm volatile("s_waitcnt vmcnt(6)" ::: "memory");
  asm volatile("s_barrier" ::: "memory");

  for (int kt = 0; kt < NT; ++kt) {
    const int s = kt % 3;
#pragma unroll
    for (int m = 0; m < 4; ++m) { a[m][0] = rdA(s, m, 0); a[m][1] = rdA(s, m, 1); }
#pragma unroll
    for (int n = 0; n < 2; ++n) { b[n][0] = rdB(s, n, 0); b[n][1] = rdB(s, n, 1); }
    if (kt + 2 < NT) stageA(kt + 2, 0);
    __builtin_amdgcn_s_setprio(1);
#pragma unroll
    for (int m = 0; m < 4; ++m)
#pragma unroll
      for (int n = 0; n < 2; ++n) {
        acc[m][n] = mfma16(a[m][0], b[n][0], acc[m][n]);
        acc[m][n] = mfma16(a[m][1], b[n][1], acc[m][n]);
      }
    __builtin_amdgcn_s_setprio(0);
    asm volatile("s_barrier" ::: "memory");
#pragma unroll
    for (int m = 0; m < 4; ++m) { a[m][0] = rdA(s, m + 4, 0); a[m][1] = rdA(s, m + 4, 1); }
    if (kt + 2 < NT) { stageA(kt + 2, 1); stageB(kt + 2); }
    __builtin_amdgcn_s_setprio(1);
#pragma unroll
    for (int m = 0; m < 4; ++m)
#pragma unroll
      for (int n = 0; n < 2; ++n) {
        acc[m + 4][n] = mfma16(a[m][0], b[n][0], acc[m + 4][n]);
        acc[m + 4][n] = mfma16(a[m][1], b[n][1], acc[m + 4][n]);
      }
    __builtin_amdgcn_s_setprio(0);
    if (kt + 2 < NT) { asm volatile("s_waitcnt vmcnt(6)" ::: "memory"); }
    else             { asm volatile("s_waitcnt vmcnt(0)" ::: "memory"); }
    asm volatile("s_barrier" ::: "memory");
  }

#pragma unroll
  for (int m = 0; m < 8; ++m) {
#pragma unroll
    for (int n = 0; n < 2; ++n) {
#pragma unroll
      for (int r = 0; r < 4; ++r) {
        const int row = row0 + wr * 128 + m * 16 + lq * 4 + r;
        const int col = col0 + wc * 32 + n * 16 + lr;
        const size_t o = (size_t)row * ldc + col;
        float v = acc[m][n][r];
        if (EPI == 0) Cb[o] = (short)f2bfu(v);
        else if (EPI == 1) Cf[o] = v + Res[o];
        else Cb[o] = (short)f2bfu(gelu_f(v));
      }
    }
  }
}

// ---------------- bf16 MFMA GEMM v12: 128x128 2-phase/K-tile, ring-3 LDS, vmcnt(4) --------
template <int EPI>
__global__ __launch_bounds__(512) void gemm12(const short* __restrict__ A,
                                              const short* __restrict__ Bt,
                                              float* __restrict__ Cf,
                                              short* __restrict__ Cb,
                                              const float* __restrict__ Res,
                                              int K, int lda, int ldb, int ldc, int nxt) {
  __shared__ __align__(16) short As[3][128 * 64];  // 48 KB ring-3
  __shared__ __align__(16) short Bs[3][128 * 64];  // 48 KB ring-3
  const int t = threadIdx.x;
  const int w = t >> 6, l = t & 63;
  const int lq = l >> 4, lr = l & 15;
  const int wr = w >> 2, wc = w & 3;
  const int nwg = gridDim.x;
  const int lgid = (blockIdx.x & 7) * (nwg >> 3) + (blockIdx.x >> 3);
  const int mt = lgid / nxt, nt_ = lgid % nxt;
  const int row0 = mt * 128, col0 = nt_ * 128;
  const int NT = K >> 6;
  f32x4 acc[4][2] = {};
  short8v a[4][2], b[2][2];

  auto stageA = [&](int kt) {
    const int s = kt % 3;
#pragma unroll
    for (int i = 0; i < 2; ++i) {
      const int c = t + i * 512;
      const int row = c >> 3, slot = c & 7;
      gl_lds16(A + (size_t)(row0 + row) * lda + kt * 64 + ((slot ^ (row & 7)) << 3),
               &As[s][c * 8]);
    }
  };
  auto stageB = [&](int kt) {
    const int s = kt % 3;
#pragma unroll
    for (int i = 0; i < 2; ++i) {
      const int c = t + i * 512;
      const int row = c >> 3, slot = c & 7;
      gl_lds16(Bt + (size_t)(col0 + row) * ldb + kt * 64 + ((slot ^ (row & 7)) << 3),
               &Bs[s][c * 8]);
    }
  };
  auto rdA = [&](int s, int m, int ks) -> short8v {
    const int row = wr * 64 + m * 16 + lr;
    return *(const short8v*)&As[s][row * 64 + (((ks << 2) + lq) ^ (row & 7)) * 8];
  };
  auto rdB = [&](int s, int n, int ks) -> short8v {
    const int row = wc * 32 + n * 16 + lr;
    return *(const short8v*)&Bs[s][row * 64 + (((ks << 2) + lq) ^ (row & 7)) * 8];
  };

  stageA(0); stageB(0);
  stageA(1); stageB(1);
  asm volatile("s_waitcnt vmcnt(4)" ::: "memory");
  asm volatile("s_barrier" ::: "memory");

  for (int kt = 0; kt < NT; ++kt) {
    const int s = kt % 3;
#pragma unroll
    for (int m = 0; m < 4; ++m) { a[m][0] = rdA(s, m, 0); a[m][1] = rdA(s, m, 1); }
#pragma unroll
    for (int n = 0; n < 2; ++n) { b[n][0] = rdB(s, n, 0); b[n][1] = rdB(s, n, 1); }
    if (kt + 2 < NT) stageA(kt + 2);
    __builtin_amdgcn_s_setprio(1);
#pragma unroll
    for (int m = 0; m < 2; ++m)
#pragma unroll
      for (int n = 0; n < 2; ++n) {
        acc[m][n] = mfma16(a[m][0], b[n][0], acc[m][n]);
        acc[m][n] = mfma16(a[m][1], b[n][1], acc[m][n]);
      }
    __builtin_amdgcn_s_setprio(0);
    asm volatile("s_barrier" ::: "memory");
    if (kt + 2 < NT) stageB(kt + 2);
    __builtin_amdgcn_s_setprio(1);
#pragma unroll
    for (int m = 2; m < 4; ++m)
#pragma unroll
      for (int n = 0; n < 2; ++n) {
        acc[m][n] = mfma16(a[m][0], b[n][0], acc[m][n]);
        acc[m][n] = mfma16(a[m][1], b[n][1], acc[m][n]);
      }
    __builtin_amdgcn_s_setprio(0);
    if (kt + 2 < NT) { asm volatile("s_waitcnt vmcnt(4)" ::: "memory"); }
    else             { asm volatile("s_waitcnt vmcnt(0)" ::: "memory"); }
    asm volatile("s_barrier" ::: "memory");
  }

#pragma unroll
  for (int m = 0; m < 4; ++m) {
#pragma unroll
    for (int n = 0; n < 2; ++n) {
#pragma unroll
      for (int r = 0; r < 4; ++r) {
        const int row = row0 + wr * 64 + m * 16 + lq * 4 + r;
        const int col = col0 + wc * 32 + n * 16 + lr;
        const size_t o = (size_t)row * ldc + col;
        float v = acc[m][n][r];
        if (EPI == 0) Cb[o] = (short)f2bfu(v);
        else if (EPI == 1) Cf[o] = v + Res[o];
        else Cb[o] = (short)f2bfu(gelu_f(v));
      }
    }
  }
}

// ---------------- Retention v5: fused GN+gate, paired q-blocks (qb,15-qb), QBLK=64 --------
__global__ __launch_bounds__(256) void ret5_kernel(const short* __restrict__ QKVGb,
                                                   const short* __restrict__ Vt,
                                                   short* __restrict__ Gb,
                                                   const float* __restrict__ gs,
                                                   const float* __restrict__ gb) {
  __shared__ __align__(16) short Ks[2][64 * 128];
  __shared__ __align__(16) short Vs[2][128 * 64];
  const int t = threadIdx.x, w = t >> 6, l = t & 63;
  const int lq = l >> 4, lr = l & 15;
  const int u = blockIdx.x;                     // 0..255
  const int lgid = (u & 7) * 32 + (u >> 3);     // XCD-contiguous
  const int bh = lgid >> 3, pr = lgid & 7;
  const int b = bh >> 3, h = bh & 7;
  const float lstep = (logf(1.f / 512.f) - logf(1.f / 32.f)) * (1.f / 7.f);
  const float gamma = 1.f - expf(logf(1.f / 32.f) + (float)h * lstep);
  const float l2g = logf(gamma) * 1.44269504f;
  const short* Qp = QKVGb;
  const short* Kp = QKVGb + 1024;

  float cmf[4], csr[4];
#pragma unroll
  for (int mf = 0; mf < 4; ++mf) cmf[mf] = exp2f(l2g * (float)(-16 * mf));
#pragma unroll
  for (int r = 0; r < 4; ++r) csr[r] = exp2f(l2g * (float)(63 - 4 * lq - r));
  float gsv[8], gbv[8];
#pragma unroll
  for (int nd = 0; nd < 8; ++nd) {
    gsv[nd] = gs[h * DHd + nd * 16 + lr];
    gbv[nd] = gb[h * DHd + nd * 16 + lr];
  }
  const int sb = ((lq & 1) * 2) * 16 + lr;

  auto stageKV = [&](int m0, int buf) {
#pragma unroll
    for (int i = 0; i < 4; ++i) {
      const int c = (w * 4 + i) * 64 + l;
      const int row = c >> 4, slot = c & 15;
      gl_lds16(Kp + (size_t)(b * Ss + m0 + row) * LDQ + h * DHd + ((slot ^ (row & 7)) * 8),
               &Ks[buf][(w * 4 + i) * 512]);
    }
#pragma unroll
    for (int i = 0; i < 4; ++i) {
      const int c = (w * 4 + i) * 64 + l;
      const int row = c >> 3, slot = c & 7;
      gl_lds16(Vt + (size_t)(bh * DHd + row) * Ss + m0 + ((slot ^ (row & 7)) * 8),
               &Vs[buf][(w * 4 + i) * 512]);
    }
  };

  for (int pass = 0; pass < 2; ++pass) {
    const int qb = pass ? (15 - pr) : pr;
    const int q0 = qb * 64;
    const int nt = qb + 1;
    short8v qf[4];
#pragma unroll
    for (int ks = 0; ks < 4; ++ks)
      qf[ks] = *(const short8v*)(Qp + (size_t)(b * Ss + q0 + w * 16 + lr) * LDQ +
                                 h * DHd + ks * 32 + lq * 8);
    f32x4 yacc[8] = {};
    stageKV(0, 0);
    __syncthreads();
    int cur = 0;
    for (int tt = 0; tt < nt; ++tt) {
      const int m0 = tt * 64;
      if (tt + 1 < nt) stageKV((tt + 1) * 64, cur ^ 1);

      f32x4 st[4] = {};
      __builtin_amdgcn_s_setprio(1);
#pragma unroll
      for (int mf = 0; mf < 4; ++mf) {
        const int row = mf * 16 + lr;
#pragma unroll
        for (int ks = 0; ks < 4; ++ks) {
          short8v kf = *(const short8v*)&Ks[cur][row * 128 + (((4 * ks + lq) ^ (row & 7)) * 8)];
          st[mf] = mfma16(kf, qf[ks], st[mf]);
        }
      }
      __builtin_amdgcn_s_setprio(0);
      const int qg = q0 + w * 16 + lr;
      const float rs = exp2f(l2g * (float)(qg - m0 - 63));
#pragma unroll
      for (int mf = 0; mf < 4; ++mf)
#pragma unroll
        for (int r = 0; r < 4; ++r) {
          const int kvg = m0 + mf * 16 + lq * 4 + r;
          const float wgt = (qg >= kvg) ? rs * cmf[mf] * csr[r] : 0.f;
          st[mf][r] *= wgt;
        }
      unsigned pk[4][2];
#pragma unroll
      for (int mf = 0; mf < 4; ++mf)
#pragma unroll
        for (int p = 0; p < 2; ++p)
          pk[mf][p] = (unsigned)f2bfu(st[mf][2 * p]) |
                      ((unsigned)f2bfu(st[mf][2 * p + 1]) << 16);
      short8v afr[2];
#pragma unroll
      for (int ks2 = 0; ks2 < 2; ++ks2) {
        u32x4 wd;
#pragma unroll
        for (int wj = 0; wj < 4; ++wj) {
          const int src = sb + (wj >> 1) * 16;
          const unsigned v0 = __shfl(pk[2 * ks2 + 0][wj & 1], src);
          const unsigned v1 = __shfl(pk[2 * ks2 + 1][wj & 1], src);
          wd[wj] = (lq >= 2) ? v1 : v0;
        }
        afr[ks2] = __builtin_bit_cast(short8v, wd);
      }
      __builtin_amdgcn_s_setprio(1);
#pragma unroll
      for (int nd = 0; nd < 8; ++nd) {
        const int row = nd * 16 + lr;
#pragma unroll
        for (int ks2 = 0; ks2 < 2; ++ks2) {
          short8v vf = *(const short8v*)&Vs[cur][row * 64 + (((4 * ks2 + lq) ^ (row & 7)) * 8)];
          yacc[nd] = mfma16(afr[ks2], vf, yacc[nd]);
        }
      }
      __builtin_amdgcn_s_setprio(0);
      __syncthreads();
      cur ^= 1;
    }
    // fused GroupNorm + gate epilogue
#pragma unroll
    for (int r = 0; r < 4; ++r) {
      float s1 = 0.f, s2 = 0.f;
#pragma unroll
      for (int nd = 0; nd < 8; ++nd) { const float v = yacc[nd][r]; s1 += v; s2 += v * v; }
#pragma unroll
      for (int msk = 1; msk < 16; msk <<= 1) {
        s1 += __shfl_xor(s1, msk);
        s2 += __shfl_xor(s2, msk);
      }
      const float mu = s1 * (1.f / 128.f);
      const float rstd = rsqrtf(s2 * (1.f / 128.f) - mu * mu + EPSf);
      const int q = q0 + w * 16 + lq * 4 + r;
      const size_t gbase = (size_t)(b * Ss + q) * LDQ + 3072 + h * DHd;
      const size_t obase = (size_t)(b * Ss + q) * Dd + h * DHd;
#pragma unroll
      for (int nd = 0; nd < 8; ++nd) {
        const int d = nd * 16 + lr;
        const float yv = (yacc[nd][r] - mu) * rstd * gsv[nd] + gbv[nd];
        const float gvx = bfu2f((unsigned short)QKVGb[gbase + d]);
        Gb[obase + d] = (short)f2bfu(swish_f(gvx) * yv);
      }
    }
  }
}

extern "C" void kernel_launch(void* const* d_in, const int* in_sizes, int n_in,
                              void* d_out, int out_size, void* d_ws, size_t ws_size,
                              hipStream_t stream) {
  const float* X = (const float*)d_in[0];
  const float* Wq = (const float*)d_in[1];
  const float* Wk = (const float*)d_in[2];
  const float* Wv = (const float*)d_in[3];
  const float* Wg = (const float*)d_in[4];
  const float* Wo = (const float*)d_in[5];
  const float* W1 = (const float*)d_in[6];
  const float* W2 = (const float*)d_in[7];
  const float* lns = (const float*)d_in[8];
  const float* lnb = (const float*)d_in[9];
  const float* gns = (const float*)d_in[10];
  const float* gnb = (const float*)d_in[11];
  float* out = (float*)d_out;

  char* W = (char*)d_ws;
  const size_t MB = 1u << 20;
  float* Abuf  = (float*)(W);             // 16 MB fp32
  short* Xnb   = (short*)(W + 16 * MB);   // 8 MB bf16
  short* QKVGb = (short*)(W + 24 * MB);   // 32 MB bf16 [4096][4096]; Hb aliases first 16 MB
  short* Vtb   = (short*)(W + 88 * MB);   // 8 MB bf16
  short* Gb    = (short*)(W + 96 * MB);   // 8 MB bf16
  short* Wqkvgt= (short*)(W + 104 * MB);  // 8 MB
  short* Wot   = (short*)(W + 112 * MB);  // 2 MB
  short* W1t   = (short*)(W + 114 * MB);  // 4 MB
  short* W2t   = (short*)(W + 118 * MB);  // 4 MB
  float* ct    = (float*)(W + 122 * MB);  // 256 KB
  float* st    = ct + Ss * 64;            // 256 KB
  short* Hb = QKVGb;  // FFN hidden 4096x2048 bf16 (16 MB)

  rope_table_kernel<<<(Ss * 64) / 256, 256, 0, stream>>>(ct, st);

  for (int l = 0; l < LAYERS; ++l) {
    const size_t DD = (size_t)Dd * Dd;
    const float* Acur = (l == 0) ? X : Abuf;  // residual stream input for this layer
    // merged: weight transposes + LN(Acur) in one dispatch
    wtrans_ln_kernel<<<13312, 256, 0, stream>>>(Wq + l * DD, Wk + l * DD, Wv + l * DD,
                                                Wg + l * DD, Wo + l * DD,
                                                W1 + (size_t)l * Dd * Ff,
                                                W2 + (size_t)l * Ff * Dd,
                                                Wqkvgt, Wot, W1t, W2t,
                                                Acur, Xnb, lns, lnb);
    // fused QKVG projection (8-phase 256x256) + direct V^T epilogue
    gemm10<0><<<dim3(16, 16), 512, 0, stream>>>(Xnb, Wqkvgt, nullptr, QKVGb,
                                                nullptr, Vtb, 4096, Dd, LDQ);
    // RoPE in-place on Q,K slices (V^T already produced by gemm10)
    rope_qk_kernel<<<8192, 256, 0, stream>>>(QKVGb, ct, st);
    // retention + fused GN/gate -> Gb (bf16)
    ret5_kernel<<<256, 256, 0, stream>>>(QKVGb, Vtb, Gb,
                                         gns + (size_t)l * Dd, gnb + (size_t)l * Dd);
    // A = (Gb @ Wo) + Acur
    gemm12<1><<<256, 512, 0, stream>>>(Gb, Wot, Abuf, nullptr, Acur,
                                       Dd, Dd, Dd, Dd, 8);
    // FFN
    ln_bf16_kernel<<<Mm, 256, 0, stream>>>(Abuf, Xnb, lns, lnb);
    gemm11<2><<<256, 512, 0, stream>>>(Xnb, W1t, nullptr, Hb, nullptr,
                                       Dd, Dd, Dd, Ff, 16);
    float* dst = (l == LAYERS - 1) ? out : Abuf;
    gemm12<1><<<256, 512, 0, stream>>>(Hb, W2t, dst, nullptr, Abuf,
                                       Ff, Ff, Ff, Dd, 8);
  }
}